// Round 2
// baseline (1923.486 us; speedup 1.0000x reference)
//
#include <hip/hip_runtime.h>
#include <hip/hip_bf16.h>

#define IN_C 8
#define HID 64
#define N_NODES 20000
#define WINDOW 8
#define N_BIG 160000
#define NE 1600000
#define E_DEC 500000
#define DHV 143
#define EPSV 1e-5f

__device__ __forceinline__ float sigf(float x) { return 1.f / (1.f + __expf(-x)); }
__device__ __forceinline__ float tanhfast(float x) {
    x = fminf(fmaxf(x, -15.f), 15.f);
    float e = __expf(2.f * x);
    return (e - 1.f) / (e + 1.f);
}

// ---------------------------------------------------------------- prep ------
// Builds transposed LSTM weight blocks + padded decoder weight, inits deg=1
// (self-loop), zeroes BN stat accumulators. Runs every call (ws re-poisoned).
__global__ void k_prep(const float* Wih1, const float* Whh1, const float* bih1, const float* bhh1,
                       const float* Wih2, const float* Whh2, const float* bih2, const float* bhh2,
                       const float* dWa,
                       float* deg, float* Bf1, float* Bf2, float* bc1, float* bc2,
                       float* Bpq, float* stats)
{
    int i0 = blockIdx.x * blockDim.x + threadIdx.x;
    int stride = gridDim.x * blockDim.x;
    for (int i = i0; i < N_BIG; i += stride) deg[i] = 1.0f;           // self-loop weight
    for (int i = i0; i < 192 * 256; i += stride) {                    // [Wih1;Whh1]^T
        int k = i >> 8, n = i & 255;
        Bf1[i] = (k < 128) ? Wih1[n * 128 + k] : Whh1[n * 64 + (k - 128)];
    }
    for (int i = i0; i < 128 * 256; i += stride) {                    // [Wih2;Whh2]^T
        int k = i >> 8, n = i & 255;
        Bf2[i] = (k < 64) ? Wih2[n * 64 + k] : Whh2[n * 64 + (k - 64)];
    }
    for (int i = i0; i < 256; i += stride) {
        bc1[i] = bih1[i] + bhh1[i];
        bc2[i] = bih2[i] + bhh2[i];
    }
    for (int i = i0; i < 144 * 288; i += stride) {                    // [dWa_top | dWa_bot], padded
        int k = i / 288, n = i % 288;
        float v = 0.f;
        if (k < DHV) {
            if (n < DHV) v = dWa[k * DHV + n];
            else if (n >= 144 && n < 144 + DHV) v = dWa[(DHV + k) * DHV + (n - 144)];
        }
        Bpq[i] = v;
    }
    for (int i = i0; i < 256; i += stride) stats[i] = 0.f;
}

// ------------------------------------------------------------- degree -------
__global__ void k_deg(const int* ei, const float* ea, float* deg) {
    int e = blockIdx.x * blockDim.x + threadIdx.x;
    if (e < NE) unsafeAtomicAdd(&deg[ei[NE + e]], ea[e]);
}

__global__ void k_dis(float* deg) {
    int i = blockIdx.x * blockDim.x + threadIdx.x;
    if (i < N_BIG) {
        float d = deg[i];
        deg[i] = (d > 0.f) ? rsqrtf(fmaxf(d, EPSV)) : 0.f;
    }
}

// ------------------------------------------------------------ x @ W1 --------
__global__ __launch_bounds__(256) void k_xw1(const float* x, const float* W1, float* hbuf) {
    __shared__ float Ws[IN_C * HID];
    __shared__ float xs[4][IN_C];
    int tid = threadIdx.x;
    Ws[tid] = W1[tid];
    Ws[tid + 256] = W1[tid + 256];
    int node0 = blockIdx.x * 4;
    if (tid < 32) xs[tid >> 3][tid & 7] = x[node0 * IN_C + tid];
    __syncthreads();
    int ch = tid & 63, ns = tid >> 6;
    float acc = 0.f;
#pragma unroll
    for (int c = 0; c < IN_C; c++) acc += xs[ns][c] * Ws[c * 64 + ch];
    hbuf[(node0 + ns) * 64 + ch] = acc;
}

// --------------------------------------------------- GCN aggregation --------
// agg = dis[i]^2 * h[i]  (self-loop term; also fully initializes the buffer)
__global__ void k_agg_init(const float* h, const float* dis, float* agg) {
    int stride = gridDim.x * blockDim.x;
    for (int idx = blockIdx.x * blockDim.x + threadIdx.x; idx < N_BIG * 64; idx += stride) {
        float d = dis[idx >> 6];
        agg[idx] = d * d * h[idx];
    }
}

// one wave per edge, lane = channel
__global__ void k_gcn_scatter(const int* ei, const float* ea, const float* dis,
                              const float* h, float* agg) {
    int wid = (blockIdx.x * blockDim.x + threadIdx.x) >> 6;
    int lane = threadIdx.x & 63;
    if (wid >= NE) return;
    int r = ei[wid], c = ei[NE + wid];
    float norm = dis[r] * ea[wid] * dis[c];
    unsafeAtomicAdd(&agg[c * 64 + lane], norm * h[r * 64 + lane]);
}

// ------------------------------------------------------------ BatchNorm -----
// pass 1: y = relu(x + b) in place, accumulate sum/sumsq per channel
__global__ void k_bnstats(float* buf, const float* bias, float* s_sum, float* s_sq) {
    int ch = threadIdx.x & 63, g = threadIdx.x >> 6;
    float b = bias[ch];
    float s = 0.f, q = 0.f;
    for (int r = blockIdx.x * 4 + g; r < N_BIG; r += gridDim.x * 4) {
        float v = buf[r * 64 + ch] + b;
        v = fmaxf(v, 0.f);
        buf[r * 64 + ch] = v;
        s += v;
        q += v * v;
    }
    unsafeAtomicAdd(&s_sum[ch], s);
    unsafeAtomicAdd(&s_sq[ch], q);
}

// pass 2: normalize in place with batch stats (biased var)
__global__ void k_bnapply(float* buf, const float* gamma, const float* beta,
                          const float* s_sum, const float* s_sq) {
    const float invn = 1.f / (float)N_BIG;
    int stride = gridDim.x * blockDim.x;
    for (int idx = blockIdx.x * blockDim.x + threadIdx.x; idx < N_BIG * 64; idx += stride) {
        int ch = idx & 63;
        float m = s_sum[ch] * invn;
        float var = s_sq[ch] * invn - m * m;
        buf[idx] = (buf[idx] - m) * rsqrtf(var + EPSV) * gamma[ch] + beta[ch];
    }
}

// ------------------------------------------------------ generic fp32 GEMM ---
// C[M,N] = A[M,K] @ B[K,N];  BM=BN=64, BK=16, 256 thr, 4x4/thread. K%16==0, N%4==0.
__global__ __launch_bounds__(256) void k_gemm(const float* A, int lda, const float* B, int ldb,
                                              float* C, int ldc, int M, int N, int K)
{
    __shared__ float As[16][64];   // transposed: As[k][row]
    __shared__ float Bs[16][64];
    int tid = threadIdx.x;
    int tx = tid & 15, ty = tid >> 4;
    int bm = blockIdx.y * 64, bn = blockIdx.x * 64;
    float acc[4][4] = {};
    for (int ks = 0; ks < K; ks += 16) {
        {
            int idx = tid * 4;
            int r = idx >> 4, k4 = idx & 15;
            int gr = bm + r;
            float4 v = make_float4(0.f, 0.f, 0.f, 0.f);
            if (gr < M) v = *(const float4*)&A[(size_t)gr * lda + ks + k4];
            As[k4 + 0][r] = v.x; As[k4 + 1][r] = v.y; As[k4 + 2][r] = v.z; As[k4 + 3][r] = v.w;
        }
        {
            int kb = tid >> 4, n4 = (tid & 15) * 4;
            int gc = bn + n4;
            float4 v = make_float4(0.f, 0.f, 0.f, 0.f);
            if (gc < N) v = *(const float4*)&B[(size_t)(ks + kb) * ldb + gc];
            *(float4*)&Bs[kb][n4] = v;
        }
        __syncthreads();
#pragma unroll
        for (int kk = 0; kk < 16; kk++) {
            float4 a = *(const float4*)&As[kk][ty * 4];
            float4 b = *(const float4*)&Bs[kk][tx * 4];
            float av[4] = {a.x, a.y, a.z, a.w};
            float bv[4] = {b.x, b.y, b.z, b.w};
#pragma unroll
            for (int i = 0; i < 4; i++)
#pragma unroll
                for (int j = 0; j < 4; j++) acc[i][j] = fmaf(av[i], bv[j], acc[i][j]);
        }
        __syncthreads();
    }
#pragma unroll
    for (int i = 0; i < 4; i++) {
        int row = bm + ty * 4 + i, col = bn + tx * 4;
        if (row < M && col < N)
            *(float4*)&C[(size_t)row * ldc + col] = make_float4(acc[i][0], acc[i][1], acc[i][2], acc[i][3]);
    }
}

// --------------------------------------------------------- fused LSTM step --
// gates[20000,256] = [seg0|seg1|seg2] @ B + bias, then cell update in epilogue.
// Each block: 32 rows x 256 gates, K = nseg*64. Grid = 625.
__global__ __launch_bounds__(256) void k_lstm(const float* s0, const float* s1, const float* s2,
                                              const float* B, const float* bias,
                                              float* hstate, float* cstate, float* yout,
                                              int nseg, int first)
{
    __shared__ float As[16][32];
    __shared__ float Bs[16][256];
    __shared__ float Cs[32 * 256];
    int tid = threadIdx.x;
    int tx = tid & 31, ty = tid >> 5;
    int row0 = blockIdx.x * 32;
    float acc[4][8] = {};
    int nk = nseg * 4;
    for (int ks = 0; ks < nk; ks++) {
        int seg = ks >> 2;
        const float* Sp = (seg == 0) ? s0 : (seg == 1) ? s1 : s2;
        int k0 = (ks & 3) * 16;
        {   // A: 32 rows x 16 k
            int idx = tid * 2;
            int r = idx >> 4, kk = idx & 15;
            const float* p = Sp + (size_t)(row0 + r) * 64 + k0 + kk;
            As[kk][r] = p[0];
            As[kk + 1][r] = p[1];
        }
        {   // B: 16 k x 256 n
            int n4 = (tid & 63) * 4;
            int kb0 = (tid >> 6) * 4;
#pragma unroll
            for (int j = 0; j < 4; j++)
                *(float4*)&Bs[kb0 + j][n4] = *(const float4*)&B[(size_t)(ks * 16 + kb0 + j) * 256 + n4];
        }
        __syncthreads();
#pragma unroll
        for (int kk = 0; kk < 16; kk++) {
            float4 a = *(const float4*)&As[kk][ty * 4];
            float4 b0 = *(const float4*)&Bs[kk][tx * 8];
            float4 b1 = *(const float4*)&Bs[kk][tx * 8 + 4];
            float av[4] = {a.x, a.y, a.z, a.w};
            float bv[8] = {b0.x, b0.y, b0.z, b0.w, b1.x, b1.y, b1.z, b1.w};
#pragma unroll
            for (int i = 0; i < 4; i++)
#pragma unroll
                for (int j = 0; j < 8; j++) acc[i][j] = fmaf(av[i], bv[j], acc[i][j]);
        }
        __syncthreads();
    }
#pragma unroll
    for (int i = 0; i < 4; i++)
#pragma unroll
        for (int j = 0; j < 8; j++)
            Cs[(ty * 4 + i) * 256 + tx * 8 + j] = acc[i][j] + bias[tx * 8 + j];
    __syncthreads();
#pragma unroll
    for (int it = 0; it < 8; it++) {
        int idx = it * 256 + tid;
        int r = idx >> 6, u = idx & 63;
        int node = row0 + r;
        float gi = Cs[r * 256 + u];
        float gf = Cs[r * 256 + 64 + u];
        float gg = Cs[r * 256 + 128 + u];
        float go = Cs[r * 256 + 192 + u];
        float co = first ? 0.f : cstate[node * 64 + u];
        float cn = sigf(gf) * co + sigf(gi) * tanhfast(gg);
        float hn = sigf(go) * tanhfast(cn);
        cstate[node * 64 + u] = cn;
        hstate[node * 64 + u] = hn;
        if (yout) yout[node * 64 + u] = hn;
    }
}

// ----------------------------------------------------------- small utils ----
__global__ void k_copy(float* dst, const float* src, int n) {
    int i = blockIdx.x * blockDim.x + threadIdx.x;
    if (i < n) dst[i] = src[i];
}

// node_emb[20000,160] = [H1 | H2 | S | 0-pad]
__global__ void k_nodeemb(const float* H1, const float* H2, const float* x, float* ne) {
    int stride = gridDim.x * blockDim.x;
    for (int idx = blockIdx.x * blockDim.x + threadIdx.x; idx < N_NODES * 160; idx += stride) {
        int n = idx / 160, j = idx % 160;
        float v;
        if (j < 64) v = H1[n * 64 + j];
        else if (j < 128) v = H2[n * 64 + (j - 64)];
        else if (j < DHV) {
            int s = j - 128;
            v = (s < 8) ? x[n * IN_C + s] : x[(size_t)((s - 7) * N_NODES + n) * IN_C + 7];
        } else v = 0.f;
        ne[idx] = v;
    }
}

// decoder: out[e] = relu(P[src]+Q[trg]+ba) . dWb + bb ; one wave per edge
__global__ void k_edge(const int* ewi, const float* PQ, const float* dba,
                       const float* dWb, const float* dbb, float* out) {
    int wid = (blockIdx.x * blockDim.x + threadIdx.x) >> 6;
    int lane = threadIdx.x & 63;
    if (wid >= E_DEC) return;
    int src = ewi[wid], trg = ewi[E_DEC + wid];
    const float* Pr = PQ + (size_t)src * 288;
    const float* Qr = PQ + (size_t)trg * 288 + 144;
    float acc = 0.f;
    for (int u = lane; u < DHV; u += 64) {
        float v = Pr[u] + Qr[u] + dba[u];
        v = fmaxf(v, 0.f);
        acc += v * dWb[u];
    }
#pragma unroll
    for (int off = 32; off > 0; off >>= 1) acc += __shfl_down(acc, off);
    if (lane == 0) out[wid] = acc + dbb[0];
}

// ---------------------------------------------------------------------------
extern "C" void kernel_launch(void* const* d_in, const int* in_sizes, int n_in,
                              void* d_out, int out_size, void* d_ws, size_t ws_size,
                              hipStream_t stream) {
    (void)in_sizes; (void)n_in; (void)out_size; (void)ws_size;
    const float* x    = (const float*)d_in[0];
    const float* ea   = (const float*)d_in[1];
    const int*   ei   = (const int*)d_in[2];
    const int*   ewi  = (const int*)d_in[3];
    const float* W1   = (const float*)d_in[4];
    const float* b1   = (const float*)d_in[5];
    const float* g1   = (const float*)d_in[6];
    const float* be1  = (const float*)d_in[7];
    const float* W2   = (const float*)d_in[8];
    const float* b2   = (const float*)d_in[9];
    const float* g2   = (const float*)d_in[10];
    const float* be2  = (const float*)d_in[11];
    const float* Wih1 = (const float*)d_in[12];
    const float* Whh1 = (const float*)d_in[13];
    const float* bih1 = (const float*)d_in[14];
    const float* bhh1 = (const float*)d_in[15];
    const float* Wih2 = (const float*)d_in[16];
    const float* Whh2 = (const float*)d_in[17];
    const float* bih2 = (const float*)d_in[18];
    const float* bhh2 = (const float*)d_in[19];
    const float* dWa  = (const float*)d_in[20];
    const float* dba  = (const float*)d_in[21];
    const float* dWb  = (const float*)d_in[22];
    const float* dbb  = (const float*)d_in[23];
    float* out = (float*)d_out;

    float* ws = (float*)d_ws;
    size_t o = 0;
    float* dis    = ws + o; o += N_BIG;                 // deg -> dis
    float* hbuf   = ws + o; o += (size_t)N_BIG * 64;    // x@W1 / h1@W2; later y1
    float* h1     = ws + o; o += (size_t)N_BIG * 64;    // later node_emb
    float* h2     = ws + o; o += (size_t)N_BIG * 64;    // later PQ
    float* hstate = ws + o; o += (size_t)N_NODES * 64;
    float* cstate = ws + o; o += (size_t)N_NODES * 64;
    float* H1     = ws + o; o += (size_t)N_NODES * 64;
    float* Bf1    = ws + o; o += 192 * 256;
    float* Bf2    = ws + o; o += 128 * 256;
    float* bc1    = ws + o; o += 256;
    float* bc2    = ws + o; o += 256;
    float* Bpq    = ws + o; o += 144 * 288;
    float* stats  = ws + o; o += 256;
    float* y1 = hbuf;
    float* ne = h1;
    float* PQ = h2;
    const int NS = N_NODES * 64;

    k_prep<<<512, 256, 0, stream>>>(Wih1, Whh1, bih1, bhh1, Wih2, Whh2, bih2, bhh2,
                                    dWa, dis, Bf1, Bf2, bc1, bc2, Bpq, stats);
    k_deg<<<(NE + 255) / 256, 256, 0, stream>>>(ei, ea, dis);
    k_dis<<<(N_BIG + 255) / 256, 256, 0, stream>>>(dis);

    // ---- GCN layer 1 ----
    k_xw1<<<N_BIG / 4, 256, 0, stream>>>(x, W1, hbuf);
    k_agg_init<<<4096, 256, 0, stream>>>(hbuf, dis, h1);
    k_gcn_scatter<<<NE / 4, 256, 0, stream>>>(ei, ea, dis, hbuf, h1);
    k_bnstats<<<256, 256, 0, stream>>>(h1, b1, stats, stats + 64);
    k_bnapply<<<4096, 256, 0, stream>>>(h1, g1, be1, stats, stats + 64);

    // ---- GCN layer 2 ----
    {
        dim3 g(1, 2500);
        k_gemm<<<g, 256, 0, stream>>>(h1, 64, W2, 64, hbuf, 64, N_BIG, 64, 64);
    }
    k_agg_init<<<4096, 256, 0, stream>>>(hbuf, dis, h2);
    k_gcn_scatter<<<NE / 4, 256, 0, stream>>>(ei, ea, dis, hbuf, h2);
    k_bnstats<<<256, 256, 0, stream>>>(h2, b2, stats + 128, stats + 192);
    k_bnapply<<<4096, 256, 0, stream>>>(h2, g2, be2, stats + 128, stats + 192);

    // ---- LSTM 1 (input = [h1_t | h2_t], recur = hstate) ----
    for (int t = 0; t < WINDOW; t++) {
        k_lstm<<<625, 256, 0, stream>>>(h1 + (size_t)t * NS, h2 + (size_t)t * NS, hstate,
                                        Bf1, bc1, hstate, cstate, y1 + (size_t)t * NS,
                                        (t == 0) ? 2 : 3, (t == 0) ? 1 : 0);
    }
    k_copy<<<(NS + 255) / 256, 256, 0, stream>>>(H1, hstate, NS);

    // ---- LSTM 2 (input = y1_t, recur = hstate) ----
    for (int t = 0; t < WINDOW; t++) {
        k_lstm<<<625, 256, 0, stream>>>(y1 + (size_t)t * NS, hstate, nullptr,
                                        Bf2, bc2, hstate, cstate, nullptr,
                                        (t == 0) ? 1 : 2, (t == 0) ? 1 : 0);
    }

    // ---- node embeddings + decoder ----
    k_nodeemb<<<12500, 256, 0, stream>>>(H1, hstate, x, ne);
    {
        dim3 g(5, 313);
        k_gemm<<<g, 256, 0, stream>>>(ne, 160, Bpq, 288, PQ, 288, N_NODES, 288, 144);
    }
    k_edge<<<E_DEC / 4, 256, 0, stream>>>(ewi, PQ, dba, dWb, dbb, out);
}

// Round 3
// 1670.773 us; speedup vs baseline: 1.1513x; 1.1513x over previous
//
#include <hip/hip_runtime.h>
#include <hip/hip_bf16.h>

#define IN_C 8
#define HID 64
#define N_NODES 20000
#define WINDOW 8
#define N_BIG 160000
#define NE 1600000
#define E_DEC 500000
#define DHV 143
#define EPSV 1e-5f

__device__ __forceinline__ float sigf(float x) { return 1.f / (1.f + __expf(-x)); }
__device__ __forceinline__ float tanhfast(float x) {
    x = fminf(fmaxf(x, -15.f), 15.f);
    float e = __expf(2.f * x);
    return (e - 1.f) / (e + 1.f);
}

// ---------------------------------------------------------------- prep ------
__global__ void k_prep(const float* Wih1, const float* Whh1, const float* bih1, const float* bhh1,
                       const float* Wih2, const float* Whh2, const float* bih2, const float* bhh2,
                       const float* dWa,
                       float* deg, int* cnt, float* Bf1, float* Bf2, float* bc1, float* bc2,
                       float* Bpq, float* stats)
{
    int i0 = blockIdx.x * blockDim.x + threadIdx.x;
    int stride = gridDim.x * blockDim.x;
    for (int i = i0; i < N_BIG; i += stride) { deg[i] = 1.0f; cnt[i] = 0; }
    for (int i = i0; i < 192 * 256; i += stride) {                    // [Wih1;Whh1]^T
        int k = i >> 8, n = i & 255;
        Bf1[i] = (k < 128) ? Wih1[n * 128 + k] : Whh1[n * 64 + (k - 128)];
    }
    for (int i = i0; i < 128 * 256; i += stride) {                    // [Wih2;Whh2]^T
        int k = i >> 8, n = i & 255;
        Bf2[i] = (k < 64) ? Wih2[n * 64 + k] : Whh2[n * 64 + (k - 64)];
    }
    for (int i = i0; i < 256; i += stride) {
        bc1[i] = bih1[i] + bhh1[i];
        bc2[i] = bih2[i] + bhh2[i];
    }
    for (int i = i0; i < 144 * 288; i += stride) {                    // [dWa_top | dWa_bot], padded
        int k = i / 288, n = i % 288;
        float v = 0.f;
        if (k < DHV) {
            if (n < DHV) v = dWa[k * DHV + n];
            else if (n >= 144 && n < 144 + DHV) v = dWa[(DHV + k) * DHV + (n - 144)];
        }
        Bpq[i] = v;
    }
    for (int i = i0; i < 256; i += stride) stats[i] = 0.f;
}

// -------------------------------------------------- degree + edge count -----
__global__ void k_deg_count(const int* ei, const float* ea, float* deg, int* cnt) {
    int e = blockIdx.x * blockDim.x + threadIdx.x;
    if (e >= NE) return;
    int c = ei[NE + e];
    unsafeAtomicAdd(&deg[c], ea[e]);
    atomicAdd(&cnt[c], 1);
}

__global__ void k_dis(float* deg) {
    int i = blockIdx.x * blockDim.x + threadIdx.x;
    if (i < N_BIG) {
        float d = deg[i];
        deg[i] = (d > 0.f) ? rsqrtf(fmaxf(d, EPSV)) : 0.f;
    }
}

// ----------------------------------------------- exclusive scan (3-phase) ---
// 157 blocks x 256 thr x 4 elems = 160768 slots
__global__ __launch_bounds__(256) void k_scan1(const int* cnt, int* offs, int* part) {
    __shared__ int s[256];
    int tid = threadIdx.x;
    int base = blockIdx.x * 1024 + tid * 4;
    int c[4];
    int sum = 0;
#pragma unroll
    for (int j = 0; j < 4; j++) {
        c[j] = (base + j < N_BIG) ? cnt[base + j] : 0;
        sum += c[j];
    }
    s[tid] = sum;
    __syncthreads();
    for (int off = 1; off < 256; off <<= 1) {
        int v = (tid >= off) ? s[tid - off] : 0;
        __syncthreads();
        s[tid] += v;
        __syncthreads();
    }
    int run = s[tid] - sum;          // exclusive prefix within block
#pragma unroll
    for (int j = 0; j < 4; j++) {
        if (base + j < N_BIG) offs[base + j] = run;
        run += c[j];
    }
    if (tid == 255) part[blockIdx.x] = s[255];
}

__global__ __launch_bounds__(256) void k_scan2(int* part, int np) {
    __shared__ int s[256];
    int tid = threadIdx.x;
    int v = (tid < np) ? part[tid] : 0;
    s[tid] = v;
    __syncthreads();
    for (int off = 1; off < 256; off <<= 1) {
        int w = (tid >= off) ? s[tid - off] : 0;
        __syncthreads();
        s[tid] += w;
        __syncthreads();
    }
    if (tid < np) part[tid] = s[tid] - v;
}

__global__ __launch_bounds__(256) void k_scan3(int* offs, int* cur, const int* part) {
    int add = part[blockIdx.x];
    int base = blockIdx.x * 1024 + threadIdx.x * 4;
#pragma unroll
    for (int j = 0; j < 4; j++) {
        if (base + j < N_BIG) {
            int v = offs[base + j] + add;
            offs[base + j] = v;
            cur[base + j] = v;
        }
    }
}

// ------------------------------------------------------------ CSR fill ------
__global__ void k_fill(const int* ei, const float* ea, const float* dis, int* cur, float2* pairs) {
    int e = blockIdx.x * blockDim.x + threadIdx.x;
    if (e >= NE) return;
    int r = ei[e], c = ei[NE + e];
    float norm = dis[r] * ea[e] * dis[c];
    int p = atomicAdd(&cur[c], 1);
    pairs[p] = make_float2(__int_as_float(r), norm);
}

// ------------------------------------------------------------ x @ W1 --------
__global__ __launch_bounds__(256) void k_xw1(const float* x, const float* W1, float* hbuf) {
    __shared__ float Ws[IN_C * HID];
    __shared__ float xs[4][IN_C];
    int tid = threadIdx.x;
    Ws[tid] = W1[tid];
    Ws[tid + 256] = W1[tid + 256];
    int node0 = blockIdx.x * 4;
    if (tid < 32) xs[tid >> 3][tid & 7] = x[node0 * IN_C + tid];
    __syncthreads();
    int ch = tid & 63, ns = tid >> 6;
    float acc = 0.f;
#pragma unroll
    for (int c = 0; c < IN_C; c++) acc += xs[ns][c] * Ws[c * 64 + ch];
    hbuf[(node0 + ns) * 64 + ch] = acc;
}

// ------------------------------------------- GCN aggregation (CSR gather) ---
// wave per node: agg = d^2*h[c] + sum norm*h[src]; epilogue relu(agg + bias)
__global__ void k_gcn_gather(const float* h, const float* dis, const int* offs, const int* cnt,
                             const float2* pairs, const float* bias, float* outb) {
    int c = (blockIdx.x * blockDim.x + threadIdx.x) >> 6;
    int lane = threadIdx.x & 63;
    if (c >= N_BIG) return;
    float d = dis[c];
    float acc = d * d * h[(size_t)c * 64 + lane];
    int o = offs[c], n = cnt[c];
    for (int e = 0; e < n; e++) {
        float2 p = pairs[o + e];
        int r = __float_as_int(p.x);
        acc += p.y * h[(size_t)r * 64 + lane];
    }
    outb[(size_t)c * 64 + lane] = fmaxf(acc + bias[lane], 0.f);
}

// ------------------------------------------------------------ BatchNorm -----
// stats pass (read-only; buffer already has relu(x+b))
__global__ void k_bnstats(const float* buf, float* s_sum, float* s_sq) {
    int ch = threadIdx.x & 63, g = threadIdx.x >> 6;
    float s = 0.f, q = 0.f;
    for (int r = blockIdx.x * 4 + g; r < N_BIG; r += gridDim.x * 4) {
        float v = buf[(size_t)r * 64 + ch];
        s += v;
        q += v * v;
    }
    unsafeAtomicAdd(&s_sum[ch], s);
    unsafeAtomicAdd(&s_sq[ch], q);
}

__global__ void k_bnapply(float* buf, const float* gamma, const float* beta,
                          const float* s_sum, const float* s_sq) {
    const float invn = 1.f / (float)N_BIG;
    int stride = gridDim.x * blockDim.x;
    for (int idx = blockIdx.x * blockDim.x + threadIdx.x; idx < N_BIG * 64; idx += stride) {
        int ch = idx & 63;
        float m = s_sum[ch] * invn;
        float var = s_sq[ch] * invn - m * m;
        buf[idx] = (buf[idx] - m) * rsqrtf(var + EPSV) * gamma[ch] + beta[ch];
    }
}

// ------------------------------------------------------ generic fp32 GEMM ---
__global__ __launch_bounds__(256) void k_gemm(const float* A, int lda, const float* B, int ldb,
                                              float* C, int ldc, int M, int N, int K)
{
    __shared__ float As[16][64];
    __shared__ float Bs[16][64];
    int tid = threadIdx.x;
    int tx = tid & 15, ty = tid >> 4;
    int bm = blockIdx.y * 64, bn = blockIdx.x * 64;
    float acc[4][4] = {};
    for (int ks = 0; ks < K; ks += 16) {
        {
            int idx = tid * 4;
            int r = idx >> 4, k4 = idx & 15;
            int gr = bm + r;
            float4 v = make_float4(0.f, 0.f, 0.f, 0.f);
            if (gr < M) v = *(const float4*)&A[(size_t)gr * lda + ks + k4];
            As[k4 + 0][r] = v.x; As[k4 + 1][r] = v.y; As[k4 + 2][r] = v.z; As[k4 + 3][r] = v.w;
        }
        {
            int kb = tid >> 4, n4 = (tid & 15) * 4;
            int gc = bn + n4;
            float4 v = make_float4(0.f, 0.f, 0.f, 0.f);
            if (gc < N) v = *(const float4*)&B[(size_t)(ks + kb) * ldb + gc];
            *(float4*)&Bs[kb][n4] = v;
        }
        __syncthreads();
#pragma unroll
        for (int kk = 0; kk < 16; kk++) {
            float4 a = *(const float4*)&As[kk][ty * 4];
            float4 b = *(const float4*)&Bs[kk][tx * 4];
            float av[4] = {a.x, a.y, a.z, a.w};
            float bv[4] = {b.x, b.y, b.z, b.w};
#pragma unroll
            for (int i = 0; i < 4; i++)
#pragma unroll
                for (int j = 0; j < 4; j++) acc[i][j] = fmaf(av[i], bv[j], acc[i][j]);
        }
        __syncthreads();
    }
#pragma unroll
    for (int i = 0; i < 4; i++) {
        int row = bm + ty * 4 + i, col = bn + tx * 4;
        if (row < M && col < N)
            *(float4*)&C[(size_t)row * ldc + col] = make_float4(acc[i][0], acc[i][1], acc[i][2], acc[i][3]);
    }
}

// --------------------------------------------------------- fused LSTM step --
__global__ __launch_bounds__(256) void k_lstm(const float* s0, const float* s1, const float* s2,
                                              const float* B, const float* bias,
                                              float* hstate, float* cstate, float* yout,
                                              int nseg, int first)
{
    __shared__ float As[16][32];
    __shared__ float Bs[16][256];
    __shared__ float Cs[32 * 256];
    int tid = threadIdx.x;
    int tx = tid & 31, ty = tid >> 5;
    int row0 = blockIdx.x * 32;
    float acc[4][8] = {};
    int nk = nseg * 4;
    for (int ks = 0; ks < nk; ks++) {
        int seg = ks >> 2;
        const float* Sp = (seg == 0) ? s0 : (seg == 1) ? s1 : s2;
        int k0 = (ks & 3) * 16;
        {
            int idx = tid * 2;
            int r = idx >> 4, kk = idx & 15;
            const float* p = Sp + (size_t)(row0 + r) * 64 + k0 + kk;
            As[kk][r] = p[0];
            As[kk + 1][r] = p[1];
        }
        {
            int n4 = (tid & 63) * 4;
            int kb0 = (tid >> 6) * 4;
#pragma unroll
            for (int j = 0; j < 4; j++)
                *(float4*)&Bs[kb0 + j][n4] = *(const float4*)&B[(size_t)(ks * 16 + kb0 + j) * 256 + n4];
        }
        __syncthreads();
#pragma unroll
        for (int kk = 0; kk < 16; kk++) {
            float4 a = *(const float4*)&As[kk][ty * 4];
            float4 b0 = *(const float4*)&Bs[kk][tx * 8];
            float4 b1 = *(const float4*)&Bs[kk][tx * 8 + 4];
            float av[4] = {a.x, a.y, a.z, a.w};
            float bv[8] = {b0.x, b0.y, b0.z, b0.w, b1.x, b1.y, b1.z, b1.w};
#pragma unroll
            for (int i = 0; i < 4; i++)
#pragma unroll
                for (int j = 0; j < 8; j++) acc[i][j] = fmaf(av[i], bv[j], acc[i][j]);
        }
        __syncthreads();
    }
#pragma unroll
    for (int i = 0; i < 4; i++)
#pragma unroll
        for (int j = 0; j < 8; j++)
            Cs[(ty * 4 + i) * 256 + tx * 8 + j] = acc[i][j] + bias[tx * 8 + j];
    __syncthreads();
#pragma unroll
    for (int it = 0; it < 8; it++) {
        int idx = it * 256 + tid;
        int r = idx >> 6, u = idx & 63;
        int node = row0 + r;
        float gi = Cs[r * 256 + u];
        float gf = Cs[r * 256 + 64 + u];
        float gg = Cs[r * 256 + 128 + u];
        float go = Cs[r * 256 + 192 + u];
        float co = first ? 0.f : cstate[node * 64 + u];
        float cn = sigf(gf) * co + sigf(gi) * tanhfast(gg);
        float hn = sigf(go) * tanhfast(cn);
        cstate[node * 64 + u] = cn;
        hstate[node * 64 + u] = hn;
        if (yout) yout[node * 64 + u] = hn;
    }
}

// ----------------------------------------------------------- small utils ----
__global__ void k_copy(float* dst, const float* src, int n) {
    int i = blockIdx.x * blockDim.x + threadIdx.x;
    if (i < n) dst[i] = src[i];
}

__global__ void k_nodeemb(const float* H1, const float* H2, const float* x, float* ne) {
    int stride = gridDim.x * blockDim.x;
    for (int idx = blockIdx.x * blockDim.x + threadIdx.x; idx < N_NODES * 160; idx += stride) {
        int n = idx / 160, j = idx % 160;
        float v;
        if (j < 64) v = H1[n * 64 + j];
        else if (j < 128) v = H2[n * 64 + (j - 64)];
        else if (j < DHV) {
            int s = j - 128;
            v = (s < 8) ? x[n * IN_C + s] : x[(size_t)((s - 7) * N_NODES + n) * IN_C + 7];
        } else v = 0.f;
        ne[idx] = v;
    }
}

__global__ void k_edge(const int* ewi, const float* PQ, const float* dba,
                       const float* dWb, const float* dbb, float* out) {
    int wid = (blockIdx.x * blockDim.x + threadIdx.x) >> 6;
    int lane = threadIdx.x & 63;
    if (wid >= E_DEC) return;
    int src = ewi[wid], trg = ewi[E_DEC + wid];
    const float* Pr = PQ + (size_t)src * 288;
    const float* Qr = PQ + (size_t)trg * 288 + 144;
    float acc = 0.f;
    for (int u = lane; u < DHV; u += 64) {
        float v = Pr[u] + Qr[u] + dba[u];
        v = fmaxf(v, 0.f);
        acc += v * dWb[u];
    }
#pragma unroll
    for (int off = 32; off > 0; off >>= 1) acc += __shfl_down(acc, off);
    if (lane == 0) out[wid] = acc + dbb[0];
}

// ---------------------------------------------------------------------------
extern "C" void kernel_launch(void* const* d_in, const int* in_sizes, int n_in,
                              void* d_out, int out_size, void* d_ws, size_t ws_size,
                              hipStream_t stream) {
    (void)in_sizes; (void)n_in; (void)out_size; (void)ws_size;
    const float* x    = (const float*)d_in[0];
    const float* ea   = (const float*)d_in[1];
    const int*   ei   = (const int*)d_in[2];
    const int*   ewi  = (const int*)d_in[3];
    const float* W1   = (const float*)d_in[4];
    const float* b1   = (const float*)d_in[5];
    const float* g1   = (const float*)d_in[6];
    const float* be1  = (const float*)d_in[7];
    const float* W2   = (const float*)d_in[8];
    const float* b2   = (const float*)d_in[9];
    const float* g2   = (const float*)d_in[10];
    const float* be2  = (const float*)d_in[11];
    const float* Wih1 = (const float*)d_in[12];
    const float* Whh1 = (const float*)d_in[13];
    const float* bih1 = (const float*)d_in[14];
    const float* bhh1 = (const float*)d_in[15];
    const float* Wih2 = (const float*)d_in[16];
    const float* Whh2 = (const float*)d_in[17];
    const float* bih2 = (const float*)d_in[18];
    const float* bhh2 = (const float*)d_in[19];
    const float* dWa  = (const float*)d_in[20];
    const float* dba  = (const float*)d_in[21];
    const float* dWb  = (const float*)d_in[22];
    const float* dbb  = (const float*)d_in[23];
    float* out = (float*)d_out;

    const int NS = N_NODES * 64;
    float* ws = (float*)d_ws;
    size_t o = 0;
    float* dis    = ws + o; o += N_BIG;                 // deg -> dis
    float* hbuf   = ws + o; o += (size_t)N_BIG * 64;    // x@W1 / h1@W2; later y1
    float* h1     = ws + o; o += (size_t)N_BIG * 64;    // later node_emb
    float* h2     = ws + o; o += (size_t)N_BIG * 64;    // later PQ
    float* lstmbuf = ws + o; o += (size_t)3 * NS;       // CSR (early) / hstate|cstate|H1 (late)
    float* Bf1    = ws + o; o += 192 * 256;
    float* Bf2    = ws + o; o += 128 * 256;
    float* bc1    = ws + o; o += 256;
    float* bc2    = ws + o; o += 256;
    float* Bpq    = ws + o; o += 144 * 288;
    float* stats  = ws + o; o += 256;
    float* y1 = hbuf;
    float* ne = h1;
    float* PQ = h2;
    // temporal aliasing: CSR structures live in lstmbuf, dead before first k_lstm
    float2* pairs = (float2*)lstmbuf;                   // 1.6M float2 = 3.2M floats
    int* offs = (int*)(lstmbuf + 3200000);              // 160k
    int* cnt  = offs + N_BIG;                           // 160k
    int* cur  = cnt + N_BIG;                            // 160k
    int* part = cur + N_BIG;                            // 157  (total 3.68M < 3.84M)
    float* hstate = lstmbuf;
    float* cstate = lstmbuf + NS;
    float* H1     = lstmbuf + 2 * NS;

    // ---- prep + CSR build ----
    k_prep<<<512, 256, 0, stream>>>(Wih1, Whh1, bih1, bhh1, Wih2, Whh2, bih2, bhh2,
                                    dWa, dis, cnt, Bf1, Bf2, bc1, bc2, Bpq, stats);
    k_deg_count<<<(NE + 255) / 256, 256, 0, stream>>>(ei, ea, dis, cnt);
    k_dis<<<(N_BIG + 255) / 256, 256, 0, stream>>>(dis);
    k_scan1<<<157, 256, 0, stream>>>(cnt, offs, part);
    k_scan2<<<1, 256, 0, stream>>>(part, 157);
    k_scan3<<<157, 256, 0, stream>>>(offs, cur, part);
    k_fill<<<(NE + 255) / 256, 256, 0, stream>>>(ei, ea, dis, cur, pairs);

    // ---- GCN layer 1 ----
    k_xw1<<<N_BIG / 4, 256, 0, stream>>>(x, W1, hbuf);
    k_gcn_gather<<<N_BIG / 4, 256, 0, stream>>>(hbuf, dis, offs, cnt, pairs, b1, h1);
    k_bnstats<<<256, 256, 0, stream>>>(h1, stats, stats + 64);
    k_bnapply<<<4096, 256, 0, stream>>>(h1, g1, be1, stats, stats + 64);

    // ---- GCN layer 2 ----
    {
        dim3 g(1, 2500);
        k_gemm<<<g, 256, 0, stream>>>(h1, 64, W2, 64, hbuf, 64, N_BIG, 64, 64);
    }
    k_gcn_gather<<<N_BIG / 4, 256, 0, stream>>>(hbuf, dis, offs, cnt, pairs, b2, h2);
    k_bnstats<<<256, 256, 0, stream>>>(h2, stats + 128, stats + 192);
    k_bnapply<<<4096, 256, 0, stream>>>(h2, g2, be2, stats + 128, stats + 192);

    // ---- LSTM 1 (input = [h1_t | h2_t], recur = hstate) ----
    for (int t = 0; t < WINDOW; t++) {
        k_lstm<<<625, 256, 0, stream>>>(h1 + (size_t)t * NS, h2 + (size_t)t * NS, hstate,
                                        Bf1, bc1, hstate, cstate, y1 + (size_t)t * NS,
                                        (t == 0) ? 2 : 3, (t == 0) ? 1 : 0);
    }
    k_copy<<<(NS + 255) / 256, 256, 0, stream>>>(H1, hstate, NS);

    // ---- LSTM 2 (input = y1_t, recur = hstate) ----
    for (int t = 0; t < WINDOW; t++) {
        k_lstm<<<625, 256, 0, stream>>>(y1 + (size_t)t * NS, hstate, nullptr,
                                        Bf2, bc2, hstate, cstate, nullptr,
                                        (t == 0) ? 1 : 2, (t == 0) ? 1 : 0);
    }

    // ---- node embeddings + decoder ----
    k_nodeemb<<<12500, 256, 0, stream>>>(H1, hstate, x, ne);
    {
        dim3 g(5, 313);
        k_gemm<<<g, 256, 0, stream>>>(ne, 160, Bpq, 288, PQ, 288, N_NODES, 288, 144);
    }
    k_edge<<<E_DEC / 4, 256, 0, stream>>>(ewi, PQ, dba, dWb, dbb, out);
}

// Round 4
// 1439.564 us; speedup vs baseline: 1.3362x; 1.1606x over previous
//
#include <hip/hip_runtime.h>
#include <hip/hip_bf16.h>

#define IN_C 8
#define HID 64
#define N_NODES 20000
#define WINDOW 8
#define N_BIG 160000
#define NE 1600000
#define E_DEC 500000
#define DHV 143
#define EPSV 1e-5f

typedef __hip_bfloat16 bf;
typedef __attribute__((ext_vector_type(8))) short short8;
typedef __attribute__((ext_vector_type(4))) float float4_;

__device__ __forceinline__ float b2f(bf v) { return __bfloat162float(v); }
__device__ __forceinline__ bf f2b(float v) { return __float2bfloat16(v); }
__device__ __forceinline__ float sigf(float x) { return 1.f / (1.f + __expf(-x)); }
__device__ __forceinline__ float tanhfast(float x) {
    x = fminf(fmaxf(x, -15.f), 15.f);
    float e = __expf(2.f * x);
    return (e - 1.f) / (e + 1.f);
}

// ---------------------------------------------------------------- prep ------
// Weight conversion to bf16 (LSTM B-operands in native [N=256][K] layout,
// W2 transposed), padded decoder weight (fp32), deg=1, cnt=0, stats=0.
__global__ void k_prep(const float* Wih1, const float* Whh1, const float* bih1, const float* bhh1,
                       const float* Wih2, const float* Whh2, const float* bih2, const float* bhh2,
                       const float* dWa, const float* W2,
                       float* deg, int* cnt, bf* Bcat1, bf* Bcat2, bf* W2t,
                       float* bc1, float* bc2, float* Bpq, float* stats)
{
    int i0 = blockIdx.x * blockDim.x + threadIdx.x;
    int stride = gridDim.x * blockDim.x;
    for (int i = i0; i < N_BIG; i += stride) { deg[i] = 1.0f; cnt[i] = 0; }
    for (int i = i0; i < 256 * 192; i += stride) {        // [Wih1|Whh1] row-major [256][192]
        int n = i / 192, k = i % 192;
        Bcat1[i] = f2b((k < 128) ? Wih1[n * 128 + k] : Whh1[n * 64 + (k - 128)]);
    }
    for (int i = i0; i < 256 * 128; i += stride) {        // [Wih2|Whh2] row-major [256][128]
        int n = i >> 7, k = i & 127;
        Bcat2[i] = f2b((k < 64) ? Wih2[n * 64 + k] : Whh2[n * 64 + (k - 64)]);
    }
    for (int i = i0; i < 64 * 64; i += stride) {          // W2^T [n][k]
        int n = i >> 6, k = i & 63;
        W2t[i] = f2b(W2[k * 64 + n]);
    }
    for (int i = i0; i < 256; i += stride) {
        bc1[i] = bih1[i] + bhh1[i];
        bc2[i] = bih2[i] + bhh2[i];
    }
    for (int i = i0; i < 144 * 288; i += stride) {        // [dWa_top | dWa_bot], padded fp32
        int k = i / 288, n = i % 288;
        float v = 0.f;
        if (k < DHV) {
            if (n < DHV) v = dWa[k * DHV + n];
            else if (n >= 144 && n < 144 + DHV) v = dWa[(DHV + k) * DHV + (n - 144)];
        }
        Bpq[i] = v;
    }
    for (int i = i0; i < 256; i += stride) stats[i] = 0.f;
}

// -------------------------------------------------- degree + edge count -----
__global__ void k_deg_count(const int* ei, const float* ea, float* deg, int* cnt) {
    int e = blockIdx.x * blockDim.x + threadIdx.x;
    if (e >= NE) return;
    int c = ei[NE + e];
    unsafeAtomicAdd(&deg[c], ea[e]);
    atomicAdd(&cnt[c], 1);
}

__global__ void k_dis(float* deg) {
    int i = blockIdx.x * blockDim.x + threadIdx.x;
    if (i < N_BIG) {
        float d = deg[i];
        deg[i] = (d > 0.f) ? rsqrtf(fmaxf(d, EPSV)) : 0.f;
    }
}

// ----------------------------------------------- exclusive scan (3-phase) ---
__global__ __launch_bounds__(256) void k_scan1(const int* cnt, int* offs, int* part) {
    __shared__ int s[256];
    int tid = threadIdx.x;
    int base = blockIdx.x * 1024 + tid * 4;
    int c[4];
    int sum = 0;
#pragma unroll
    for (int j = 0; j < 4; j++) {
        c[j] = (base + j < N_BIG) ? cnt[base + j] : 0;
        sum += c[j];
    }
    s[tid] = sum;
    __syncthreads();
    for (int off = 1; off < 256; off <<= 1) {
        int v = (tid >= off) ? s[tid - off] : 0;
        __syncthreads();
        s[tid] += v;
        __syncthreads();
    }
    int run = s[tid] - sum;
#pragma unroll
    for (int j = 0; j < 4; j++) {
        if (base + j < N_BIG) offs[base + j] = run;
        run += c[j];
    }
    if (tid == 255) part[blockIdx.x] = s[255];
}

__global__ __launch_bounds__(256) void k_scan2(int* part, int np) {
    __shared__ int s[256];
    int tid = threadIdx.x;
    int v = (tid < np) ? part[tid] : 0;
    s[tid] = v;
    __syncthreads();
    for (int off = 1; off < 256; off <<= 1) {
        int w = (tid >= off) ? s[tid - off] : 0;
        __syncthreads();
        s[tid] += w;
        __syncthreads();
    }
    if (tid < np) part[tid] = s[tid] - v;
}

__global__ __launch_bounds__(256) void k_scan3(int* offs, int* cur, const int* part) {
    int add = part[blockIdx.x];
    int base = blockIdx.x * 1024 + threadIdx.x * 4;
#pragma unroll
    for (int j = 0; j < 4; j++) {
        if (base + j < N_BIG) {
            int v = offs[base + j] + add;
            offs[base + j] = v;
            cur[base + j] = v;
        }
    }
}

// ------------------------------------------------------------ CSR fill ------
__global__ void k_fill(const int* ei, const float* ea, const float* dis, int* cur, float2* pairs) {
    int e = blockIdx.x * blockDim.x + threadIdx.x;
    if (e >= NE) return;
    int r = ei[e], c = ei[NE + e];
    float norm = dis[r] * ea[e] * dis[c];
    int p = atomicAdd(&cur[c], 1);
    pairs[p] = make_float2(__int_as_float(r), norm);
}

// ------------------------------------------------------------ x @ W1 --------
__global__ __launch_bounds__(256) void k_xw1(const float* x, const float* W1, bf* hbufb) {
    __shared__ float Ws[IN_C * HID];
    __shared__ float xs[4][IN_C];
    int tid = threadIdx.x;
    Ws[tid] = W1[tid];
    Ws[tid + 256] = W1[tid + 256];
    int node0 = blockIdx.x * 4;
    if (tid < 32) xs[tid >> 3][tid & 7] = x[node0 * IN_C + tid];
    __syncthreads();
    int ch = tid & 63, ns = tid >> 6;
    float acc = 0.f;
#pragma unroll
    for (int c = 0; c < IN_C; c++) acc += xs[ns][c] * Ws[c * 64 + ch];
    hbufb[(size_t)(node0 + ns) * 64 + ch] = f2b(acc);
}

// ------------------------------------------- GCN aggregation (CSR gather) ---
// wave per node, bf16 rows; epilogue relu(agg + bias) -> fp32 out
__global__ void k_gcn_gather(const bf* h, const float* dis, const int* offs, const int* cnt,
                             const float2* pairs, const float* bias, float* outf) {
    int c = (blockIdx.x * blockDim.x + threadIdx.x) >> 6;
    int lane = threadIdx.x & 63;
    if (c >= N_BIG) return;
    float d = dis[c];
    float acc = d * d * b2f(h[(size_t)c * 64 + lane]);
    int o = offs[c], n = cnt[c];
    for (int e = 0; e < n; e++) {
        float2 p = pairs[o + e];
        int r = __float_as_int(p.x);
        acc += p.y * b2f(h[(size_t)r * 64 + lane]);
    }
    outf[(size_t)c * 64 + lane] = fmaxf(acc + bias[lane], 0.f);
}

// ------------------------------------------------------------ BatchNorm -----
__global__ void k_bnstats(const float* buf, float* s_sum, float* s_sq) {
    int ch = threadIdx.x & 63, g = threadIdx.x >> 6;
    float s = 0.f, q = 0.f;
    for (int r = blockIdx.x * 4 + g; r < N_BIG; r += gridDim.x * 4) {
        float v = buf[(size_t)r * 64 + ch];
        s += v;
        q += v * v;
    }
    unsafeAtomicAdd(&s_sum[ch], s);
    unsafeAtomicAdd(&s_sq[ch], q);
}

// normalize, write bf16
__global__ void k_bnapply(const float* buf, const float* gamma, const float* beta,
                          const float* s_sum, const float* s_sq, bf* outb) {
    const float invn = 1.f / (float)N_BIG;
    int stride = gridDim.x * blockDim.x;
    for (int idx = blockIdx.x * blockDim.x + threadIdx.x; idx < N_BIG * 64; idx += stride) {
        int ch = idx & 63;
        float m = s_sum[ch] * invn;
        float var = s_sq[ch] * invn - m * m;
        outb[idx] = f2b((buf[idx] - m) * rsqrtf(var + EPSV) * gamma[ch] + beta[ch]);
    }
}

// ------------------------------------------------- h1 @ W2 (bf16 MFMA) ------
// wave: 16 rows x 64 cols, K=64. grid 2500 (exact).
__global__ __launch_bounds__(256) void k_h1w2(const bf* h1b, const bf* W2t, bf* outb) {
    int tid = threadIdx.x, w = tid >> 6, lane = tid & 63;
    int q = lane >> 4, l15 = lane & 15;
    size_t r0 = (size_t)blockIdx.x * 64 + w * 16;
    float4_ acc[4];
#pragma unroll
    for (int ct = 0; ct < 4; ct++) acc[ct] = (float4_){0.f, 0.f, 0.f, 0.f};
#pragma unroll
    for (int c = 0; c < 2; c++) {
        int koff = c * 32 + q * 8;
        short8 a = *(const short8*)(h1b + (r0 + l15) * 64 + koff);
#pragma unroll
        for (int ct = 0; ct < 4; ct++) {
            short8 b = *(const short8*)(W2t + (size_t)(ct * 16 + l15) * 64 + koff);
            acc[ct] = __builtin_amdgcn_mfma_f32_16x16x32_bf16(a, b, acc[ct], 0, 0, 0);
        }
    }
    size_t node0 = r0 + q * 4;
#pragma unroll
    for (int reg = 0; reg < 4; reg++)
#pragma unroll
        for (int ct = 0; ct < 4; ct++)
            outb[(node0 + reg) * 64 + ct * 16 + l15] = f2b(acc[ct][reg]);
}

// ------------------------------------------------- fused LSTM step (MFMA) ---
// Block 256thr/4 waves; wave = 16 nodes x 256 gate cols (16 tiles 16x16).
// K = nchunk*32 from segs {s0,s1,s2} (chunk c -> seg c>>1, k_in_seg (c&1)*32).
// Bt = [Wih|Whh] row-major [256][ldb] bf16. Bias folded into acc init.
// i/f/g/o of unit u live in tiles ct,ct+4,ct+8,ct+12 of the same lane ->
// cell update fully in-register. Each wave reads/writes only its own rows.
__global__ __launch_bounds__(256) void k_lstm_mfma(
    const bf* s0, const bf* s1, const bf* s2,
    const bf* Bt, int ldb, const float* bias,
    bf* hstate, float* cstate, bf* yout, int nchunk, int first)
{
    int tid = threadIdx.x, w = tid >> 6, lane = tid & 63;
    int q = lane >> 4, l15 = lane & 15;
    int r0 = blockIdx.x * 64 + w * 16;
    float4_ acc[16];
#pragma unroll
    for (int ct = 0; ct < 16; ct++) {
        float bcv = bias[ct * 16 + l15];
        acc[ct] = (float4_){bcv, bcv, bcv, bcv};
    }
    for (int c = 0; c < nchunk; c++) {
        const bf* sp = (c < 2) ? s0 : (c < 4) ? s1 : s2;
        int koff = (c & 1) * 32 + q * 8;
        short8 a = *(const short8*)(sp + (size_t)(r0 + l15) * 64 + koff);
        int kb = c * 32 + q * 8;
#pragma unroll
        for (int ct = 0; ct < 16; ct++) {
            short8 b = *(const short8*)(Bt + (size_t)(ct * 16 + l15) * ldb + kb);
            acc[ct] = __builtin_amdgcn_mfma_f32_16x16x32_bf16(a, b, acc[ct], 0, 0, 0);
        }
    }
    int node0 = r0 + q * 4;
#pragma unroll
    for (int reg = 0; reg < 4; reg++) {
        int node = node0 + reg;
        if (node < N_NODES) {
#pragma unroll
            for (int ui = 0; ui < 4; ui++) {
                int u = ui * 16 + l15;
                float gi = acc[ui][reg];
                float gf = acc[ui + 4][reg];
                float gg = acc[ui + 8][reg];
                float go = acc[ui + 12][reg];
                float co = first ? 0.f : cstate[(size_t)node * 64 + u];
                float cn = sigf(gf) * co + sigf(gi) * tanhfast(gg);
                float hn = sigf(go) * tanhfast(cn);
                cstate[(size_t)node * 64 + u] = cn;
                hstate[(size_t)node * 64 + u] = f2b(hn);
                if (yout) yout[(size_t)node * 64 + u] = f2b(hn);
            }
        }
    }
}

// ------------------------------------------------------ generic fp32 GEMM ---
__global__ __launch_bounds__(256) void k_gemm(const float* A, int lda, const float* B, int ldb,
                                              float* C, int ldc, int M, int N, int K)
{
    __shared__ float As[16][64];
    __shared__ float Bs[16][64];
    int tid = threadIdx.x;
    int tx = tid & 15, ty = tid >> 4;
    int bm = blockIdx.y * 64, bn = blockIdx.x * 64;
    float acc[4][4] = {};
    for (int ks = 0; ks < K; ks += 16) {
        {
            int idx = tid * 4;
            int r = idx >> 4, k4 = idx & 15;
            int gr = bm + r;
            float4 v = make_float4(0.f, 0.f, 0.f, 0.f);
            if (gr < M) v = *(const float4*)&A[(size_t)gr * lda + ks + k4];
            As[k4 + 0][r] = v.x; As[k4 + 1][r] = v.y; As[k4 + 2][r] = v.z; As[k4 + 3][r] = v.w;
        }
        {
            int kb = tid >> 4, n4 = (tid & 15) * 4;
            int gc = bn + n4;
            float4 v = make_float4(0.f, 0.f, 0.f, 0.f);
            if (gc < N) v = *(const float4*)&B[(size_t)(ks + kb) * ldb + gc];
            *(float4*)&Bs[kb][n4] = v;
        }
        __syncthreads();
#pragma unroll
        for (int kk = 0; kk < 16; kk++) {
            float4 a = *(const float4*)&As[kk][ty * 4];
            float4 b = *(const float4*)&Bs[kk][tx * 4];
            float av[4] = {a.x, a.y, a.z, a.w};
            float bv[4] = {b.x, b.y, b.z, b.w};
#pragma unroll
            for (int i = 0; i < 4; i++)
#pragma unroll
                for (int j = 0; j < 4; j++) acc[i][j] = fmaf(av[i], bv[j], acc[i][j]);
        }
        __syncthreads();
    }
#pragma unroll
    for (int i = 0; i < 4; i++) {
        int row = bm + ty * 4 + i, col = bn + tx * 4;
        if (row < M && col < N)
            *(float4*)&C[(size_t)row * ldc + col] = make_float4(acc[i][0], acc[i][1], acc[i][2], acc[i][3]);
    }
}

// ----------------------------------------------------------- small utils ----
__global__ void k_nodeemb(const bf* H1, const bf* H2, const float* x, float* ne) {
    int stride = gridDim.x * blockDim.x;
    for (int idx = blockIdx.x * blockDim.x + threadIdx.x; idx < N_NODES * 160; idx += stride) {
        int n = idx / 160, j = idx % 160;
        float v;
        if (j < 64) v = b2f(H1[(size_t)n * 64 + j]);
        else if (j < 128) v = b2f(H2[(size_t)n * 64 + (j - 64)]);
        else if (j < DHV) {
            int s = j - 128;
            v = (s < 8) ? x[n * IN_C + s] : x[(size_t)((s - 7) * N_NODES + n) * IN_C + 7];
        } else v = 0.f;
        ne[idx] = v;
    }
}

__global__ void k_edge(const int* ewi, const float* PQ, const float* dba,
                       const float* dWb, const float* dbb, float* out) {
    int wid = (blockIdx.x * blockDim.x + threadIdx.x) >> 6;
    int lane = threadIdx.x & 63;
    if (wid >= E_DEC) return;
    int src = ewi[wid], trg = ewi[E_DEC + wid];
    const float* Pr = PQ + (size_t)src * 288;
    const float* Qr = PQ + (size_t)trg * 288 + 144;
    float acc = 0.f;
    for (int u = lane; u < DHV; u += 64) {
        float v = Pr[u] + Qr[u] + dba[u];
        v = fmaxf(v, 0.f);
        acc += v * dWb[u];
    }
#pragma unroll
    for (int off = 32; off > 0; off >>= 1) acc += __shfl_down(acc, off);
    if (lane == 0) out[wid] = acc + dbb[0];
}

// ---------------------------------------------------------------------------
extern "C" void kernel_launch(void* const* d_in, const int* in_sizes, int n_in,
                              void* d_out, int out_size, void* d_ws, size_t ws_size,
                              hipStream_t stream) {
    (void)in_sizes; (void)n_in; (void)out_size; (void)ws_size;
    const float* x    = (const float*)d_in[0];
    const float* ea   = (const float*)d_in[1];
    const int*   ei   = (const int*)d_in[2];
    const int*   ewi  = (const int*)d_in[3];
    const float* W1   = (const float*)d_in[4];
    const float* b1   = (const float*)d_in[5];
    const float* g1   = (const float*)d_in[6];
    const float* be1  = (const float*)d_in[7];
    const float* W2   = (const float*)d_in[8];
    const float* b2   = (const float*)d_in[9];
    const float* g2   = (const float*)d_in[10];
    const float* be2  = (const float*)d_in[11];
    const float* Wih1 = (const float*)d_in[12];
    const float* Whh1 = (const float*)d_in[13];
    const float* bih1 = (const float*)d_in[14];
    const float* bhh1 = (const float*)d_in[15];
    const float* Wih2 = (const float*)d_in[16];
    const float* Whh2 = (const float*)d_in[17];
    const float* bih2 = (const float*)d_in[18];
    const float* bhh2 = (const float*)d_in[19];
    const float* dWa  = (const float*)d_in[20];
    const float* dba  = (const float*)d_in[21];
    const float* dWb  = (const float*)d_in[22];
    const float* dbb  = (const float*)d_in[23];
    float* out = (float*)d_out;

    const size_t NSB = (size_t)N_BIG * 64;   // 10.24M
    const size_t NS  = (size_t)N_NODES * 64; // 1.28M
    char* base = (char*)d_ws;
    size_t o = 0;
    float* dis  = (float*)(base + o); o += (size_t)N_BIG * 4;      // 0.64 MB
    float* aggf = (float*)(base + o); o += NSB * 4;                // 41 MB (gather out / BN in)
    bf* hbufb   = (bf*)(base + o);    o += NSB * 2;                // 20.5 MB (xW1 out / h1W2 out)
    bf* h1b     = (bf*)(base + o);    o += NSB * 2;
    bf* h2b     = (bf*)(base + o);    o += NSB * 2;
    bf* y1b     = (bf*)(base + o);    o += NSB * 2;                // CSR aliases here (dead by LSTM1)
    bf* hs1     = (bf*)(base + o);    o += NS * 2;
    float* cs1  = (float*)(base + o); o += NS * 4;
    bf* hs2     = (bf*)(base + o);    o += NS * 2;
    float* cs2  = (float*)(base + o); o += NS * 4;
    bf* Bcat1   = (bf*)(base + o);    o += 256 * 192 * 2;
    bf* Bcat2   = (bf*)(base + o);    o += 256 * 128 * 2;
    bf* W2t     = (bf*)(base + o);    o += 64 * 64 * 2;
    float* bc1  = (float*)(base + o); o += 256 * 4;
    float* bc2  = (float*)(base + o); o += 256 * 4;
    float* Bpq  = (float*)(base + o); o += 144 * 288 * 4;
    float* stats= (float*)(base + o); o += 256 * 4;
    // temporal aliases
    float2* pairs = (float2*)y1b;                    // 1.6M float2 = 12.8 MB
    int* offs = (int*)y1b + 3200000;                 // +160k
    int* cnt  = offs + N_BIG;
    int* cur  = cnt + N_BIG;
    int* part = cur + N_BIG;                         // total 14.72 MB <= 20.48 MB
    float* ne = aggf;                                // 20000x160 f32 (after aggf last use)
    float* PQ = aggf + 3200000;                      // 20000x288 f32

    // ---- prep + CSR build ----
    k_prep<<<512, 256, 0, stream>>>(Wih1, Whh1, bih1, bhh1, Wih2, Whh2, bih2, bhh2,
                                    dWa, W2, dis, cnt, Bcat1, Bcat2, W2t, bc1, bc2, Bpq, stats);
    k_deg_count<<<(NE + 255) / 256, 256, 0, stream>>>(ei, ea, dis, cnt);
    k_dis<<<(N_BIG + 255) / 256, 256, 0, stream>>>(dis);
    k_scan1<<<157, 256, 0, stream>>>(cnt, offs, part);
    k_scan2<<<1, 256, 0, stream>>>(part, 157);
    k_scan3<<<157, 256, 0, stream>>>(offs, cur, part);
    k_fill<<<(NE + 255) / 256, 256, 0, stream>>>(ei, ea, dis, cur, pairs);

    // ---- GCN layer 1 ----
    k_xw1<<<N_BIG / 4, 256, 0, stream>>>(x, W1, hbufb);
    k_gcn_gather<<<N_BIG / 4, 256, 0, stream>>>(hbufb, dis, offs, cnt, pairs, b1, aggf);
    k_bnstats<<<256, 256, 0, stream>>>(aggf, stats, stats + 64);
    k_bnapply<<<4096, 256, 0, stream>>>(aggf, g1, be1, stats, stats + 64, h1b);

    // ---- GCN layer 2 ----
    k_h1w2<<<2500, 256, 0, stream>>>(h1b, W2t, hbufb);
    k_gcn_gather<<<N_BIG / 4, 256, 0, stream>>>(hbufb, dis, offs, cnt, pairs, b2, aggf);
    k_bnstats<<<256, 256, 0, stream>>>(aggf, stats + 128, stats + 192);
    k_bnapply<<<4096, 256, 0, stream>>>(aggf, g2, be2, stats + 128, stats + 192, h2b);

    // ---- LSTM 1: K=[h1_t | h2_t | h_{t-1}] (192) ----
    for (int t = 0; t < WINDOW; t++) {
        k_lstm_mfma<<<313, 256, 0, stream>>>(h1b + (size_t)t * NS, h2b + (size_t)t * NS, hs1,
                                             Bcat1, 192, bc1, hs1, cs1, y1b + (size_t)t * NS,
                                             (t == 0) ? 4 : 6, (t == 0) ? 1 : 0);
    }
    // ---- LSTM 2: K=[y1_t | h_{t-1}] (128) ----
    for (int t = 0; t < WINDOW; t++) {
        k_lstm_mfma<<<313, 256, 0, stream>>>(y1b + (size_t)t * NS, hs2, nullptr,
                                             Bcat2, 128, bc2, hs2, cs2, nullptr,
                                             (t == 0) ? 2 : 4, (t == 0) ? 1 : 0);
    }

    // ---- node embeddings + decoder (fp32) ----
    k_nodeemb<<<12500, 256, 0, stream>>>(hs1, hs2, x, ne);
    {
        dim3 g(5, 313);
        k_gemm<<<g, 256, 0, stream>>>(ne, 160, Bpq, 288, PQ, 288, N_NODES, 288, 144);
    }
    k_edge<<<E_DEC / 4, 256, 0, stream>>>(ewi, PQ, dba, dWb, dbb, out);
}

// Round 5
// 1234.635 us; speedup vs baseline: 1.5579x; 1.1660x over previous
//
#include <hip/hip_runtime.h>
#include <hip/hip_bf16.h>

#define IN_C 8
#define HID 64
#define N_NODES 20000
#define WINDOW 8
#define N_BIG 160000
#define NE 1600000
#define E_DEC 500000
#define DHV 143
#define EPSV 1e-5f

typedef __hip_bfloat16 bf;
typedef __attribute__((ext_vector_type(8))) short short8;
typedef __attribute__((ext_vector_type(4))) float float4_;

__device__ __forceinline__ float b2f(bf v) { return __bfloat162float(v); }
__device__ __forceinline__ bf f2b(float v) { return __float2bfloat16(v); }
__device__ __forceinline__ float sigf(float x) { return 1.f / (1.f + __expf(-x)); }
__device__ __forceinline__ float tanhfast(float x) {
    x = fminf(fmaxf(x, -15.f), 15.f);
    float e = __expf(2.f * x);
    return (e - 1.f) / (e + 1.f);
}

// ---------------------------------------------------------------- prep ------
__global__ void k_prep(const float* Wih1, const float* Whh1, const float* bih1, const float* bhh1,
                       const float* Wih2, const float* Whh2, const float* bih2, const float* bhh2,
                       const float* dWa, const float* W2,
                       float* deg, int* cnt, bf* Bcat1, bf* Bcat2, bf* W2t,
                       float* bc1, float* bc2, float* Bpq, float* stats)
{
    int i0 = blockIdx.x * blockDim.x + threadIdx.x;
    int stride = gridDim.x * blockDim.x;
    for (int i = i0; i < N_BIG; i += stride) { deg[i] = 1.0f; cnt[i] = 0; }
    for (int i = i0; i < 256 * 192; i += stride) {        // [Wih1|Whh1] row-major [256][192]
        int n = i / 192, k = i % 192;
        Bcat1[i] = f2b((k < 128) ? Wih1[n * 128 + k] : Whh1[n * 64 + (k - 128)]);
    }
    for (int i = i0; i < 256 * 128; i += stride) {        // [Wih2|Whh2] row-major [256][128]
        int n = i >> 7, k = i & 127;
        Bcat2[i] = f2b((k < 64) ? Wih2[n * 64 + k] : Whh2[n * 64 + (k - 64)]);
    }
    for (int i = i0; i < 64 * 64; i += stride) {          // W2^T [n][k]
        int n = i >> 6, k = i & 63;
        W2t[i] = f2b(W2[k * 64 + n]);
    }
    for (int i = i0; i < 256; i += stride) {
        bc1[i] = bih1[i] + bhh1[i];
        bc2[i] = bih2[i] + bhh2[i];
    }
    for (int i = i0; i < 144 * 288; i += stride) {        // [dWa_top | dWa_bot], padded fp32
        int k = i / 288, n = i % 288;
        float v = 0.f;
        if (k < DHV) {
            if (n < DHV) v = dWa[k * DHV + n];
            else if (n >= 144 && n < 144 + DHV) v = dWa[(DHV + k) * DHV + (n - 144)];
        }
        Bpq[i] = v;
    }
    for (int i = i0; i < 256; i += stride) stats[i] = 0.f;
}

// -------------------------------------------------- degree + edge count -----
__global__ void k_deg_count(const int* ei, const float* ea, float* deg, int* cnt) {
    int e = blockIdx.x * blockDim.x + threadIdx.x;
    if (e >= NE) return;
    int c = ei[NE + e];
    unsafeAtomicAdd(&deg[c], ea[e]);
    atomicAdd(&cnt[c], 1);
}

__global__ void k_dis(float* deg) {
    int i = blockIdx.x * blockDim.x + threadIdx.x;
    if (i < N_BIG) {
        float d = deg[i];
        deg[i] = (d > 0.f) ? rsqrtf(fmaxf(d, EPSV)) : 0.f;
    }
}

// ----------------------------------------------- exclusive scan (3-phase) ---
__global__ __launch_bounds__(256) void k_scan1(const int* cnt, int* offs, int* part) {
    __shared__ int s[256];
    int tid = threadIdx.x;
    int base = blockIdx.x * 1024 + tid * 4;
    int c[4];
    int sum = 0;
#pragma unroll
    for (int j = 0; j < 4; j++) {
        c[j] = (base + j < N_BIG) ? cnt[base + j] : 0;
        sum += c[j];
    }
    s[tid] = sum;
    __syncthreads();
    for (int off = 1; off < 256; off <<= 1) {
        int v = (tid >= off) ? s[tid - off] : 0;
        __syncthreads();
        s[tid] += v;
        __syncthreads();
    }
    int run = s[tid] - sum;
#pragma unroll
    for (int j = 0; j < 4; j++) {
        if (base + j < N_BIG) offs[base + j] = run;
        run += c[j];
    }
    if (tid == 255) part[blockIdx.x] = s[255];
}

__global__ __launch_bounds__(256) void k_scan2(int* part, int np) {
    __shared__ int s[256];
    int tid = threadIdx.x;
    int v = (tid < np) ? part[tid] : 0;
    s[tid] = v;
    __syncthreads();
    for (int off = 1; off < 256; off <<= 1) {
        int w = (tid >= off) ? s[tid - off] : 0;
        __syncthreads();
        s[tid] += w;
        __syncthreads();
    }
    if (tid < np) part[tid] = s[tid] - v;
}

__global__ __launch_bounds__(256) void k_scan3(int* offs, int* cur, const int* part) {
    int add = part[blockIdx.x];
    int base = blockIdx.x * 1024 + threadIdx.x * 4;
#pragma unroll
    for (int j = 0; j < 4; j++) {
        if (base + j < N_BIG) {
            int v = offs[base + j] + add;
            offs[base + j] = v;
            cur[base + j] = v;
        }
    }
}

// ------------------------------------------------------------ CSR fill ------
__global__ void k_fill(const int* ei, const float* ea, const float* dis, int* cur, float2* pairs) {
    int e = blockIdx.x * blockDim.x + threadIdx.x;
    if (e >= NE) return;
    int r = ei[e], c = ei[NE + e];
    float norm = dis[r] * ea[e] * dis[c];
    int p = atomicAdd(&cur[c], 1);
    pairs[p] = make_float2(__int_as_float(r), norm);
}

// ------------------------------------------------------------ x @ W1 --------
__global__ __launch_bounds__(256) void k_xw1(const float* x, const float* W1, bf* hbufb) {
    __shared__ float Ws[IN_C * HID];
    __shared__ float xs[4][IN_C];
    int tid = threadIdx.x;
    Ws[tid] = W1[tid];
    Ws[tid + 256] = W1[tid + 256];
    int node0 = blockIdx.x * 4;
    if (tid < 32) xs[tid >> 3][tid & 7] = x[node0 * IN_C + tid];
    __syncthreads();
    int ch = tid & 63, ns = tid >> 6;
    float acc = 0.f;
#pragma unroll
    for (int c = 0; c < IN_C; c++) acc += xs[ns][c] * Ws[c * 64 + ch];
    hbufb[(size_t)(node0 + ns) * 64 + ch] = f2b(acc);
}

// ------------------------------------------- GCN aggregation (CSR gather) ---
// wave per node, 4-wide unrolled for memory-level parallelism
__global__ void k_gcn_gather(const bf* h, const float* dis, const int* offs, const int* cnt,
                             const float2* pairs, const float* bias, float* outf) {
    int c = (blockIdx.x * blockDim.x + threadIdx.x) >> 6;
    int lane = threadIdx.x & 63;
    if (c >= N_BIG) return;
    float d = dis[c];
    float acc = d * d * b2f(h[(size_t)c * 64 + lane]);
    int o = offs[c], n = cnt[c];
    int e = 0;
    for (; e + 4 <= n; e += 4) {
        float2 p0 = pairs[o + e + 0];
        float2 p1 = pairs[o + e + 1];
        float2 p2 = pairs[o + e + 2];
        float2 p3 = pairs[o + e + 3];
        float v0 = b2f(h[(size_t)__float_as_int(p0.x) * 64 + lane]);
        float v1 = b2f(h[(size_t)__float_as_int(p1.x) * 64 + lane]);
        float v2 = b2f(h[(size_t)__float_as_int(p2.x) * 64 + lane]);
        float v3 = b2f(h[(size_t)__float_as_int(p3.x) * 64 + lane]);
        acc += p0.y * v0 + p1.y * v1 + p2.y * v2 + p3.y * v3;
    }
    for (; e < n; e++) {
        float2 p = pairs[o + e];
        acc += p.y * b2f(h[(size_t)__float_as_int(p.x) * 64 + lane]);
    }
    outf[(size_t)c * 64 + lane] = fmaxf(acc + bias[lane], 0.f);
}

// ------------------------------------------------------------ BatchNorm -----
__global__ void k_bnstats(const float* buf, float* s_sum, float* s_sq) {
    int ch = threadIdx.x & 63, g = threadIdx.x >> 6;
    float s = 0.f, q = 0.f;
    for (int r = blockIdx.x * 4 + g; r < N_BIG; r += gridDim.x * 4) {
        float v = buf[(size_t)r * 64 + ch];
        s += v;
        q += v * v;
    }
    unsafeAtomicAdd(&s_sum[ch], s);
    unsafeAtomicAdd(&s_sq[ch], q);
}

__global__ void k_bnapply(const float* buf, const float* gamma, const float* beta,
                          const float* s_sum, const float* s_sq, bf* outb) {
    const float invn = 1.f / (float)N_BIG;
    int stride = gridDim.x * blockDim.x;
    for (int idx = blockIdx.x * blockDim.x + threadIdx.x; idx < N_BIG * 64; idx += stride) {
        int ch = idx & 63;
        float m = s_sum[ch] * invn;
        float var = s_sq[ch] * invn - m * m;
        outb[idx] = f2b((buf[idx] - m) * rsqrtf(var + EPSV) * gamma[ch] + beta[ch]);
    }
}

// ------------------------------------------------- h1 @ W2 (bf16 MFMA) ------
__global__ __launch_bounds__(256) void k_h1w2(const bf* h1b, const bf* W2t, bf* outb) {
    int tid = threadIdx.x, w = tid >> 6, lane = tid & 63;
    int q = lane >> 4, l15 = lane & 15;
    size_t r0 = (size_t)blockIdx.x * 64 + w * 16;
    float4_ acc[4];
#pragma unroll
    for (int ct = 0; ct < 4; ct++) acc[ct] = (float4_){0.f, 0.f, 0.f, 0.f};
#pragma unroll
    for (int c = 0; c < 2; c++) {
        int koff = c * 32 + q * 8;
        short8 a = *(const short8*)(h1b + (r0 + l15) * 64 + koff);
#pragma unroll
        for (int ct = 0; ct < 4; ct++) {
            short8 b = *(const short8*)(W2t + (size_t)(ct * 16 + l15) * 64 + koff);
            acc[ct] = __builtin_amdgcn_mfma_f32_16x16x32_bf16(a, b, acc[ct], 0, 0, 0);
        }
    }
    size_t node0 = r0 + q * 4;
#pragma unroll
    for (int reg = 0; reg < 4; reg++)
#pragma unroll
        for (int ct = 0; ct < 4; ct++)
            outb[(node0 + reg) * 64 + ct * 16 + l15] = f2b(acc[ct][reg]);
}

// ----------------------------------------- fully fused double LSTM (MFMA) ---
// Block = 128 thr = 2 waves; wave owns 16 nodes for ALL 8 steps of BOTH LSTMs.
// h/c state never leaves the CU: c in regs, h via LDS (doubles as the
// C-layout -> A-layout transpose). Grid 625 x 32 nodes = 20000 exact.
// LDS rows padded to 72 shorts (stride 4 banks -> <=2-way conflict on b128).
__global__ __launch_bounds__(128) void k_lstm_fused(
    const bf* h1b, const bf* h2b, const bf* B1, const bf* B2,
    const float* bc1, const float* bc2, bf* H1out, bf* H2out)
{
    __shared__ bf h1s[32][72];
    __shared__ bf h2s[32][72];
    int tid = threadIdx.x, w = tid >> 6, lane = tid & 63;
    int q = lane >> 4, l15 = lane & 15;
    int nloc0 = w * 16;
    int gnode0 = blockIdx.x * 32 + nloc0;
    float c1[16] = {}, c2[16] = {};
    float bv1[16], bv2[16];
#pragma unroll
    for (int ct = 0; ct < 16; ct++) {
        bv1[ct] = bc1[ct * 16 + l15];
        bv2[ct] = bc2[ct * 16 + l15];
    }
    for (int t = 0; t < WINDOW; t++) {
        const size_t toff = (size_t)t * N_NODES * 64;
        // ======== LSTM 1: gates = [h1b_t | h2b_t | h1_{t-1}] @ B1 ========
        float4_ acc[16];
#pragma unroll
        for (int ct = 0; ct < 16; ct++) acc[ct] = (float4_){bv1[ct], bv1[ct], bv1[ct], bv1[ct]};
#pragma unroll
        for (int c = 0; c < 4; c++) {   // global input chunks
            const bf* sp = (c < 2) ? h1b + toff : h2b + toff;
            int koff = (c & 1) * 32 + q * 8;
            short8 a = *(const short8*)(sp + (size_t)(gnode0 + l15) * 64 + koff);
            int kb = c * 32 + q * 8;
#pragma unroll
            for (int ct = 0; ct < 16; ct++) {
                short8 b = *(const short8*)(B1 + (size_t)(ct * 16 + l15) * 192 + kb);
                acc[ct] = __builtin_amdgcn_mfma_f32_16x16x32_bf16(a, b, acc[ct], 0, 0, 0);
            }
        }
        if (t > 0) {
#pragma unroll
            for (int c = 4; c < 6; c++) {   // recurrent chunks from LDS
                int koff = (c & 1) * 32 + q * 8;
                short8 a = *(const short8*)&h1s[nloc0 + l15][koff];
                int kb = c * 32 + q * 8;
#pragma unroll
                for (int ct = 0; ct < 16; ct++) {
                    short8 b = *(const short8*)(B1 + (size_t)(ct * 16 + l15) * 192 + kb);
                    acc[ct] = __builtin_amdgcn_mfma_f32_16x16x32_bf16(a, b, acc[ct], 0, 0, 0);
                }
            }
        }
#pragma unroll
        for (int ui = 0; ui < 4; ui++)
#pragma unroll
            for (int reg = 0; reg < 4; reg++) {
                float gi = acc[ui][reg], gf = acc[ui + 4][reg];
                float gg = acc[ui + 8][reg], go = acc[ui + 12][reg];
                float co = (t == 0) ? 0.f : c1[ui * 4 + reg];
                float cn = sigf(gf) * co + sigf(gi) * tanhfast(gg);
                float hn = sigf(go) * tanhfast(cn);
                c1[ui * 4 + reg] = cn;
                int nl = nloc0 + q * 4 + reg;
                h1s[nl][ui * 16 + l15] = f2b(hn);
                if (t == WINDOW - 1)
                    H1out[(size_t)(blockIdx.x * 32 + nl) * 64 + ui * 16 + l15] = f2b(hn);
            }
        __syncthreads();
        // ======== LSTM 2: gates = [h1_t | h2_{t-1}] @ B2 ========
#pragma unroll
        for (int ct = 0; ct < 16; ct++) acc[ct] = (float4_){bv2[ct], bv2[ct], bv2[ct], bv2[ct]};
#pragma unroll
        for (int c = 0; c < 2; c++) {   // y1_t = h1_t from LDS
            int koff = (c & 1) * 32 + q * 8;
            short8 a = *(const short8*)&h1s[nloc0 + l15][koff];
            int kb = c * 32 + q * 8;
#pragma unroll
            for (int ct = 0; ct < 16; ct++) {
                short8 b = *(const short8*)(B2 + (size_t)(ct * 16 + l15) * 128 + kb);
                acc[ct] = __builtin_amdgcn_mfma_f32_16x16x32_bf16(a, b, acc[ct], 0, 0, 0);
            }
        }
        if (t > 0) {
#pragma unroll
            for (int c = 2; c < 4; c++) {   // recurrent from LDS
                int koff = (c & 1) * 32 + q * 8;
                short8 a = *(const short8*)&h2s[nloc0 + l15][koff];
                int kb = c * 32 + q * 8;
#pragma unroll
                for (int ct = 0; ct < 16; ct++) {
                    short8 b = *(const short8*)(B2 + (size_t)(ct * 16 + l15) * 128 + kb);
                    acc[ct] = __builtin_amdgcn_mfma_f32_16x16x32_bf16(a, b, acc[ct], 0, 0, 0);
                }
            }
        }
#pragma unroll
        for (int ui = 0; ui < 4; ui++)
#pragma unroll
            for (int reg = 0; reg < 4; reg++) {
                float gi = acc[ui][reg], gf = acc[ui + 4][reg];
                float gg = acc[ui + 8][reg], go = acc[ui + 12][reg];
                float co = (t == 0) ? 0.f : c2[ui * 4 + reg];
                float cn = sigf(gf) * co + sigf(gi) * tanhfast(gg);
                float hn = sigf(go) * tanhfast(cn);
                c2[ui * 4 + reg] = cn;
                int nl = nloc0 + q * 4 + reg;
                h2s[nl][ui * 16 + l15] = f2b(hn);
                if (t == WINDOW - 1)
                    H2out[(size_t)(blockIdx.x * 32 + nl) * 64 + ui * 16 + l15] = f2b(hn);
            }
        __syncthreads();
    }
}

// ------------------------------------------------------ generic fp32 GEMM ---
__global__ __launch_bounds__(256) void k_gemm(const float* A, int lda, const float* B, int ldb,
                                              float* C, int ldc, int M, int N, int K)
{
    __shared__ float As[16][64];
    __shared__ float Bs[16][64];
    int tid = threadIdx.x;
    int tx = tid & 15, ty = tid >> 4;
    int bm = blockIdx.y * 64, bn = blockIdx.x * 64;
    float acc[4][4] = {};
    for (int ks = 0; ks < K; ks += 16) {
        {
            int idx = tid * 4;
            int r = idx >> 4, k4 = idx & 15;
            int gr = bm + r;
            float4 v = make_float4(0.f, 0.f, 0.f, 0.f);
            if (gr < M) v = *(const float4*)&A[(size_t)gr * lda + ks + k4];
            As[k4 + 0][r] = v.x; As[k4 + 1][r] = v.y; As[k4 + 2][r] = v.z; As[k4 + 3][r] = v.w;
        }
        {
            int kb = tid >> 4, n4 = (tid & 15) * 4;
            int gc = bn + n4;
            float4 v = make_float4(0.f, 0.f, 0.f, 0.f);
            if (gc < N) v = *(const float4*)&B[(size_t)(ks + kb) * ldb + gc];
            *(float4*)&Bs[kb][n4] = v;
        }
        __syncthreads();
#pragma unroll
        for (int kk = 0; kk < 16; kk++) {
            float4 a = *(const float4*)&As[kk][ty * 4];
            float4 b = *(const float4*)&Bs[kk][tx * 4];
            float av[4] = {a.x, a.y, a.z, a.w};
            float bv[4] = {b.x, b.y, b.z, b.w};
#pragma unroll
            for (int i = 0; i < 4; i++)
#pragma unroll
                for (int j = 0; j < 4; j++) acc[i][j] = fmaf(av[i], bv[j], acc[i][j]);
        }
        __syncthreads();
    }
#pragma unroll
    for (int i = 0; i < 4; i++) {
        int row = bm + ty * 4 + i, col = bn + tx * 4;
        if (row < M && col < N)
            *(float4*)&C[(size_t)row * ldc + col] = make_float4(acc[i][0], acc[i][1], acc[i][2], acc[i][3]);
    }
}

// ----------------------------------------------------------- small utils ----
__global__ void k_nodeemb(const bf* H1, const bf* H2, const float* x, float* ne) {
    int stride = gridDim.x * blockDim.x;
    for (int idx = blockIdx.x * blockDim.x + threadIdx.x; idx < N_NODES * 160; idx += stride) {
        int n = idx / 160, j = idx % 160;
        float v;
        if (j < 64) v = b2f(H1[(size_t)n * 64 + j]);
        else if (j < 128) v = b2f(H2[(size_t)n * 64 + (j - 64)]);
        else if (j < DHV) {
            int s = j - 128;
            v = (s < 8) ? x[n * IN_C + s] : x[(size_t)((s - 7) * N_NODES + n) * IN_C + 7];
        } else v = 0.f;
        ne[idx] = v;
    }
}

__global__ void k_edge(const int* ewi, const float* PQ, const float* dba,
                       const float* dWb, const float* dbb, float* out) {
    int wid = (blockIdx.x * blockDim.x + threadIdx.x) >> 6;
    int lane = threadIdx.x & 63;
    if (wid >= E_DEC) return;
    int src = ewi[wid], trg = ewi[E_DEC + wid];
    const float* Pr = PQ + (size_t)src * 288;
    const float* Qr = PQ + (size_t)trg * 288 + 144;
    float acc = 0.f;
    for (int u = lane; u < DHV; u += 64) {
        float v = Pr[u] + Qr[u] + dba[u];
        v = fmaxf(v, 0.f);
        acc += v * dWb[u];
    }
#pragma unroll
    for (int off = 32; off > 0; off >>= 1) acc += __shfl_down(acc, off);
    if (lane == 0) out[wid] = acc + dbb[0];
}

// ---------------------------------------------------------------------------
extern "C" void kernel_launch(void* const* d_in, const int* in_sizes, int n_in,
                              void* d_out, int out_size, void* d_ws, size_t ws_size,
                              hipStream_t stream) {
    (void)in_sizes; (void)n_in; (void)out_size; (void)ws_size;
    const float* x    = (const float*)d_in[0];
    const float* ea   = (const float*)d_in[1];
    const int*   ei   = (const int*)d_in[2];
    const int*   ewi  = (const int*)d_in[3];
    const float* W1   = (const float*)d_in[4];
    const float* b1   = (const float*)d_in[5];
    const float* g1   = (const float*)d_in[6];
    const float* be1  = (const float*)d_in[7];
    const float* W2   = (const float*)d_in[8];
    const float* b2   = (const float*)d_in[9];
    const float* g2   = (const float*)d_in[10];
    const float* be2  = (const float*)d_in[11];
    const float* Wih1 = (const float*)d_in[12];
    const float* Whh1 = (const float*)d_in[13];
    const float* bih1 = (const float*)d_in[14];
    const float* bhh1 = (const float*)d_in[15];
    const float* Wih2 = (const float*)d_in[16];
    const float* Whh2 = (const float*)d_in[17];
    const float* bih2 = (const float*)d_in[18];
    const float* bhh2 = (const float*)d_in[19];
    const float* dWa  = (const float*)d_in[20];
    const float* dba  = (const float*)d_in[21];
    const float* dWb  = (const float*)d_in[22];
    const float* dbb  = (const float*)d_in[23];
    float* out = (float*)d_out;

    const size_t NSB = (size_t)N_BIG * 64;   // 10.24M
    const size_t NS  = (size_t)N_NODES * 64; // 1.28M
    char* base = (char*)d_ws;
    size_t o = 0;
    float* dis  = (float*)(base + o); o += (size_t)N_BIG * 4;      // 0.64 MB
    float* aggf = (float*)(base + o); o += NSB * 4;                // 41 MB (gather out / ne,PQ later)
    bf* hbufb   = (bf*)(base + o);    o += NSB * 2;                // 20.5 MB
    bf* h1b     = (bf*)(base + o);    o += NSB * 2;
    bf* h2b     = (bf*)(base + o);    o += NSB * 2;
    bf* hs1     = (bf*)(base + o);    o += NS * 2;
    bf* hs2     = (bf*)(base + o);    o += NS * 2;
    bf* Bcat1   = (bf*)(base + o);    o += 256 * 192 * 2;
    bf* Bcat2   = (bf*)(base + o);    o += 256 * 128 * 2;
    bf* W2t     = (bf*)(base + o);    o += 64 * 64 * 2;
    float* bc1  = (float*)(base + o); o += 256 * 4;
    float* bc2  = (float*)(base + o); o += 256 * 4;
    float* Bpq  = (float*)(base + o); o += 144 * 288 * 4;
    float* stats= (float*)(base + o); o += 256 * 4;
    float2* pairs = (float2*)(base + o); o += (size_t)NE * 8;      // 12.8 MB
    int* offs = (int*)(base + o); o += (size_t)N_BIG * 4;
    int* cnt  = (int*)(base + o); o += (size_t)N_BIG * 4;
    int* cur  = (int*)(base + o); o += (size_t)N_BIG * 4;
    int* part = (int*)(base + o); o += 256 * 4;
    float* ne = aggf;                                // 20000x160 f32 (aggf dead by then)
    float* PQ = aggf + 3200000;                      // 20000x288 f32

    // ---- prep + CSR build ----
    k_prep<<<512, 256, 0, stream>>>(Wih1, Whh1, bih1, bhh1, Wih2, Whh2, bih2, bhh2,
                                    dWa, W2, dis, cnt, Bcat1, Bcat2, W2t, bc1, bc2, Bpq, stats);
    k_deg_count<<<(NE + 255) / 256, 256, 0, stream>>>(ei, ea, dis, cnt);
    k_dis<<<(N_BIG + 255) / 256, 256, 0, stream>>>(dis);
    k_scan1<<<157, 256, 0, stream>>>(cnt, offs, part);
    k_scan2<<<1, 256, 0, stream>>>(part, 157);
    k_scan3<<<157, 256, 0, stream>>>(offs, cur, part);
    k_fill<<<(NE + 255) / 256, 256, 0, stream>>>(ei, ea, dis, cur, pairs);

    // ---- GCN layer 1 ----
    k_xw1<<<N_BIG / 4, 256, 0, stream>>>(x, W1, hbufb);
    k_gcn_gather<<<N_BIG / 4, 256, 0, stream>>>(hbufb, dis, offs, cnt, pairs, b1, aggf);
    k_bnstats<<<256, 256, 0, stream>>>(aggf, stats, stats + 64);
    k_bnapply<<<4096, 256, 0, stream>>>(aggf, g1, be1, stats, stats + 64, h1b);

    // ---- GCN layer 2 ----
    k_h1w2<<<2500, 256, 0, stream>>>(h1b, W2t, hbufb);
    k_gcn_gather<<<N_BIG / 4, 256, 0, stream>>>(hbufb, dis, offs, cnt, pairs, b2, aggf);
    k_bnstats<<<256, 256, 0, stream>>>(aggf, stats + 128, stats + 192);
    k_bnapply<<<4096, 256, 0, stream>>>(aggf, g2, be2, stats + 128, stats + 192, h2b);

    // ---- both LSTMs, all 8 steps, one launch ----
    k_lstm_fused<<<625, 128, 0, stream>>>(h1b, h2b, Bcat1, Bcat2, bc1, bc2, hs1, hs2);

    // ---- node embeddings + decoder (fp32) ----
    k_nodeemb<<<12500, 256, 0, stream>>>(hs1, hs2, x, ne);
    {
        dim3 g(5, 313);
        k_gemm<<<g, 256, 0, stream>>>(ne, 160, Bpq, 288, PQ, 288, N_NODES, 288, 144);
    }
    k_edge<<<E_DEC / 4, 256, 0, stream>>>(ewi, PQ, dba, dWb, dbb, out);
}

// Round 6
// 1085.661 us; speedup vs baseline: 1.7717x; 1.1372x over previous
//
#include <hip/hip_runtime.h>
#include <hip/hip_bf16.h>

#define IN_C 8
#define HID 64
#define N_NODES 20000
#define WINDOW 8
#define N_BIG 160000
#define NE 1600000
#define E_DEC 500000
#define DHV 143
#define EPSV 1e-5f

typedef __hip_bfloat16 bf;
typedef __attribute__((ext_vector_type(8))) short short8;
typedef __attribute__((ext_vector_type(4))) float float4_;

__device__ __forceinline__ float b2f(bf v) { return __bfloat162float(v); }
__device__ __forceinline__ bf f2b(float v) { return __float2bfloat16(v); }
// v_rcp_f32-based activations (rel err ~1e-6, way below bf16 noise)
__device__ __forceinline__ float sigf(float x) {
    return __builtin_amdgcn_rcpf(1.f + __expf(-x));
}
__device__ __forceinline__ float tanhfast(float x) {
    x = fminf(fmaxf(x, -15.f), 15.f);
    float e = __expf(2.f * x);
    return (e - 1.f) * __builtin_amdgcn_rcpf(e + 1.f);
}

// ---------------------------------------------------------------- prep ------
__global__ void k_prep(const float* Wih1, const float* Whh1, const float* bih1, const float* bhh1,
                       const float* Wih2, const float* Whh2, const float* bih2, const float* bhh2,
                       const float* dWa, const float* W2,
                       float* deg, int* cnt, bf* Bcat1, bf* Bcat2, bf* W2t,
                       float* bc1, float* bc2, float* Bpq, float* stats)
{
    int i0 = blockIdx.x * blockDim.x + threadIdx.x;
    int stride = gridDim.x * blockDim.x;
    for (int i = i0; i < N_BIG; i += stride) { deg[i] = 1.0f; cnt[i] = 0; }
    for (int i = i0; i < 256 * 192; i += stride) {        // [Wih1|Whh1] row-major [256][192]
        int n = i / 192, k = i % 192;
        Bcat1[i] = f2b((k < 128) ? Wih1[n * 128 + k] : Whh1[n * 64 + (k - 128)]);
    }
    for (int i = i0; i < 256 * 128; i += stride) {        // [Wih2|Whh2] row-major [256][128]
        int n = i >> 7, k = i & 127;
        Bcat2[i] = f2b((k < 64) ? Wih2[n * 64 + k] : Whh2[n * 64 + (k - 64)]);
    }
    for (int i = i0; i < 64 * 64; i += stride) {          // W2^T [n][k]
        int n = i >> 6, k = i & 63;
        W2t[i] = f2b(W2[k * 64 + n]);
    }
    for (int i = i0; i < 256; i += stride) {
        bc1[i] = bih1[i] + bhh1[i];
        bc2[i] = bih2[i] + bhh2[i];
    }
    for (int i = i0; i < 144 * 288; i += stride) {        // [dWa_top | dWa_bot], padded fp32
        int k = i / 288, n = i % 288;
        float v = 0.f;
        if (k < DHV) {
            if (n < DHV) v = dWa[k * DHV + n];
            else if (n >= 144 && n < 144 + DHV) v = dWa[(DHV + k) * DHV + (n - 144)];
        }
        Bpq[i] = v;
    }
    for (int i = i0; i < 256; i += stride) stats[i] = 0.f;
}

// -------------------------------------------------- degree + edge count -----
__global__ void k_deg_count(const int* ei, const float* ea, float* deg, int* cnt) {
    int e = blockIdx.x * blockDim.x + threadIdx.x;
    if (e >= NE) return;
    int c = ei[NE + e];
    unsafeAtomicAdd(&deg[c], ea[e]);
    atomicAdd(&cnt[c], 1);
}

__global__ void k_dis(float* deg) {
    int i = blockIdx.x * blockDim.x + threadIdx.x;
    if (i < N_BIG) {
        float d = deg[i];
        deg[i] = (d > 0.f) ? rsqrtf(fmaxf(d, EPSV)) : 0.f;
    }
}

// ----------------------------------------------- exclusive scan (3-phase) ---
__global__ __launch_bounds__(256) void k_scan1(const int* cnt, int* offs, int* part) {
    __shared__ int s[256];
    int tid = threadIdx.x;
    int base = blockIdx.x * 1024 + tid * 4;
    int c[4];
    int sum = 0;
#pragma unroll
    for (int j = 0; j < 4; j++) {
        c[j] = (base + j < N_BIG) ? cnt[base + j] : 0;
        sum += c[j];
    }
    s[tid] = sum;
    __syncthreads();
    for (int off = 1; off < 256; off <<= 1) {
        int v = (tid >= off) ? s[tid - off] : 0;
        __syncthreads();
        s[tid] += v;
        __syncthreads();
    }
    int run = s[tid] - sum;
#pragma unroll
    for (int j = 0; j < 4; j++) {
        if (base + j < N_BIG) offs[base + j] = run;
        run += c[j];
    }
    if (tid == 255) part[blockIdx.x] = s[255];
}

__global__ __launch_bounds__(256) void k_scan2(int* part, int np) {
    __shared__ int s[256];
    int tid = threadIdx.x;
    int v = (tid < np) ? part[tid] : 0;
    s[tid] = v;
    __syncthreads();
    for (int off = 1; off < 256; off <<= 1) {
        int w = (tid >= off) ? s[tid - off] : 0;
        __syncthreads();
        s[tid] += w;
        __syncthreads();
    }
    if (tid < np) part[tid] = s[tid] - v;
}

__global__ __launch_bounds__(256) void k_scan3(int* offs, int* cur, const int* part) {
    int add = part[blockIdx.x];
    int base = blockIdx.x * 1024 + threadIdx.x * 4;
#pragma unroll
    for (int j = 0; j < 4; j++) {
        if (base + j < N_BIG) {
            int v = offs[base + j] + add;
            offs[base + j] = v;
            cur[base + j] = v;
        }
    }
}

// ------------------------------------------------------------ CSR fill ------
__global__ void k_fill(const int* ei, const float* ea, const float* dis, int* cur, float2* pairs) {
    int e = blockIdx.x * blockDim.x + threadIdx.x;
    if (e >= NE) return;
    int r = ei[e], c = ei[NE + e];
    float norm = dis[r] * ea[e] * dis[c];
    int p = atomicAdd(&cur[c], 1);
    pairs[p] = make_float2(__int_as_float(r), norm);
}

// ------------------------------------------------------------ x @ W1 --------
__global__ __launch_bounds__(256) void k_xw1(const float* x, const float* W1, bf* hbufb) {
    __shared__ float Ws[IN_C * HID];
    __shared__ float xs[4][IN_C];
    int tid = threadIdx.x;
    Ws[tid] = W1[tid];
    Ws[tid + 256] = W1[tid + 256];
    int node0 = blockIdx.x * 4;
    if (tid < 32) xs[tid >> 3][tid & 7] = x[node0 * IN_C + tid];
    __syncthreads();
    int ch = tid & 63, ns = tid >> 6;
    float acc = 0.f;
#pragma unroll
    for (int c = 0; c < IN_C; c++) acc += xs[ns][c] * Ws[c * 64 + ch];
    hbufb[(size_t)(node0 + ns) * 64 + ch] = f2b(acc);
}

// ------------------------------------------- GCN aggregation (CSR gather) ---
// wave per node, 4-wide unrolled for memory-level parallelism
__global__ void k_gcn_gather(const bf* h, const float* dis, const int* offs, const int* cnt,
                             const float2* pairs, const float* bias, float* outf) {
    int c = (blockIdx.x * blockDim.x + threadIdx.x) >> 6;
    int lane = threadIdx.x & 63;
    if (c >= N_BIG) return;
    float d = dis[c];
    float acc = d * d * b2f(h[(size_t)c * 64 + lane]);
    int o = offs[c], n = cnt[c];
    int e = 0;
    for (; e + 4 <= n; e += 4) {
        float2 p0 = pairs[o + e + 0];
        float2 p1 = pairs[o + e + 1];
        float2 p2 = pairs[o + e + 2];
        float2 p3 = pairs[o + e + 3];
        float v0 = b2f(h[(size_t)__float_as_int(p0.x) * 64 + lane]);
        float v1 = b2f(h[(size_t)__float_as_int(p1.x) * 64 + lane]);
        float v2 = b2f(h[(size_t)__float_as_int(p2.x) * 64 + lane]);
        float v3 = b2f(h[(size_t)__float_as_int(p3.x) * 64 + lane]);
        acc += p0.y * v0 + p1.y * v1 + p2.y * v2 + p3.y * v3;
    }
    for (; e < n; e++) {
        float2 p = pairs[o + e];
        acc += p.y * b2f(h[(size_t)__float_as_int(p.x) * 64 + lane]);
    }
    outf[(size_t)c * 64 + lane] = fmaxf(acc + bias[lane], 0.f);
}

// ------------------------------------------------------------ BatchNorm -----
__global__ void k_bnstats(const float* buf, float* s_sum, float* s_sq) {
    int ch = threadIdx.x & 63, g = threadIdx.x >> 6;
    float s = 0.f, q = 0.f;
    for (int r = blockIdx.x * 4 + g; r < N_BIG; r += gridDim.x * 4) {
        float v = buf[(size_t)r * 64 + ch];
        s += v;
        q += v * v;
    }
    unsafeAtomicAdd(&s_sum[ch], s);
    unsafeAtomicAdd(&s_sq[ch], q);
}

__global__ void k_bnapply(const float* buf, const float* gamma, const float* beta,
                          const float* s_sum, const float* s_sq, bf* outb) {
    const float invn = 1.f / (float)N_BIG;
    int stride = gridDim.x * blockDim.x;
    for (int idx = blockIdx.x * blockDim.x + threadIdx.x; idx < N_BIG * 64; idx += stride) {
        int ch = idx & 63;
        float m = s_sum[ch] * invn;
        float var = s_sq[ch] * invn - m * m;
        outb[idx] = f2b((buf[idx] - m) * rsqrtf(var + EPSV) * gamma[ch] + beta[ch]);
    }
}

// ------------------------------------------------- h1 @ W2 (bf16 MFMA) ------
__global__ __launch_bounds__(256) void k_h1w2(const bf* h1b, const bf* W2t, bf* outb) {
    int tid = threadIdx.x, w = tid >> 6, lane = tid & 63;
    int q = lane >> 4, l15 = lane & 15;
    size_t r0 = (size_t)blockIdx.x * 64 + w * 16;
    float4_ acc[4];
#pragma unroll
    for (int ct = 0; ct < 4; ct++) acc[ct] = (float4_){0.f, 0.f, 0.f, 0.f};
#pragma unroll
    for (int c = 0; c < 2; c++) {
        int koff = c * 32 + q * 8;
        short8 a = *(const short8*)(h1b + (r0 + l15) * 64 + koff);
#pragma unroll
        for (int ct = 0; ct < 4; ct++) {
            short8 b = *(const short8*)(W2t + (size_t)(ct * 16 + l15) * 64 + koff);
            acc[ct] = __builtin_amdgcn_mfma_f32_16x16x32_bf16(a, b, acc[ct], 0, 0, 0);
        }
    }
    size_t node0 = r0 + q * 4;
#pragma unroll
    for (int reg = 0; reg < 4; reg++)
#pragma unroll
        for (int ct = 0; ct < 4; ct++)
            outb[(node0 + reg) * 64 + ct * 16 + l15] = f2b(acc[ct][reg]);
}

// ----------------------------------------- fully fused double LSTM (MFMA) ---
// Block = 256 thr = 4 waves; BLOCK owns 16 nodes for all 8 steps of both
// LSTMs. Wave w computes tiles {w, w+4, w+8, w+12} = gates i/f/g/o of units
// [16w,16w+16) -> in-register cell update for those units (acc = 4 tiles =
// 16 VGPRs, vs 64 in the old 16-tile-per-wave layout). h state exchanged via
// LDS (padded stride 72 shorts -> only free 2-way conflicts); c state in regs.
// Grid 1250 x 16 nodes = 20000 exact -> ~4.9 blocks/CU (vs 7% occupancy before).
__global__ __launch_bounds__(256) void k_lstm_fused(
    const bf* h1b, const bf* h2b, const bf* B1, const bf* B2,
    const float* bc1, const float* bc2, bf* H1out, bf* H2out)
{
    __shared__ bf h1s[16][72];
    __shared__ bf h2s[16][72];
    int tid = threadIdx.x, w = tid >> 6, lane = tid & 63;
    int q = lane >> 4, l15 = lane & 15;
    int gnode0 = blockIdx.x * 16;
    float c1[4] = {}, c2[4] = {};
    float bv1[4], bv2[4];
#pragma unroll
    for (int g = 0; g < 4; g++) {
        bv1[g] = bc1[(w + 4 * g) * 16 + l15];
        bv2[g] = bc2[(w + 4 * g) * 16 + l15];
    }
    for (int t = 0; t < WINDOW; t++) {
        const size_t toff = (size_t)t * N_NODES * 64;
        // ======== LSTM 1: gates = [h1b_t | h2b_t | h1_{t-1}] @ B1 ========
        float4_ acc[4];
#pragma unroll
        for (int g = 0; g < 4; g++) acc[g] = (float4_){bv1[g], bv1[g], bv1[g], bv1[g]};
#pragma unroll
        for (int c = 0; c < 4; c++) {   // global input chunks
            const bf* sp = (c < 2) ? h1b + toff : h2b + toff;
            int koff = (c & 1) * 32 + q * 8;
            short8 a = *(const short8*)(sp + (size_t)(gnode0 + l15) * 64 + koff);
            int kb = c * 32 + q * 8;
#pragma unroll
            for (int g = 0; g < 4; g++) {
                short8 b = *(const short8*)(B1 + (size_t)((w + 4 * g) * 16 + l15) * 192 + kb);
                acc[g] = __builtin_amdgcn_mfma_f32_16x16x32_bf16(a, b, acc[g], 0, 0, 0);
            }
        }
        if (t > 0) {
#pragma unroll
            for (int c = 4; c < 6; c++) {   // recurrent chunks from LDS
                int koff = (c & 1) * 32 + q * 8;
                short8 a = *(const short8*)&h1s[l15][koff];
                int kb = c * 32 + q * 8;
#pragma unroll
                for (int g = 0; g < 4; g++) {
                    short8 b = *(const short8*)(B1 + (size_t)((w + 4 * g) * 16 + l15) * 192 + kb);
                    acc[g] = __builtin_amdgcn_mfma_f32_16x16x32_bf16(a, b, acc[g], 0, 0, 0);
                }
            }
        }
        __syncthreads();   // all h1s(t-1) reads done before overwrite
#pragma unroll
        for (int reg = 0; reg < 4; reg++) {
            float gi = acc[0][reg], gf = acc[1][reg];
            float gg = acc[2][reg], go = acc[3][reg];
            float co = (t == 0) ? 0.f : c1[reg];
            float cn = sigf(gf) * co + sigf(gi) * tanhfast(gg);
            float hn = sigf(go) * tanhfast(cn);
            c1[reg] = cn;
            int nl = q * 4 + reg;
            h1s[nl][w * 16 + l15] = f2b(hn);
            if (t == WINDOW - 1)
                H1out[(size_t)(gnode0 + nl) * 64 + w * 16 + l15] = f2b(hn);
        }
        __syncthreads();   // h1s(t) visible
        // ======== LSTM 2: gates = [h1_t | h2_{t-1}] @ B2 ========
#pragma unroll
        for (int g = 0; g < 4; g++) acc[g] = (float4_){bv2[g], bv2[g], bv2[g], bv2[g]};
#pragma unroll
        for (int c = 0; c < 2; c++) {   // y1_t = h1_t from LDS
            int koff = (c & 1) * 32 + q * 8;
            short8 a = *(const short8*)&h1s[l15][koff];
            int kb = c * 32 + q * 8;
#pragma unroll
            for (int g = 0; g < 4; g++) {
                short8 b = *(const short8*)(B2 + (size_t)((w + 4 * g) * 16 + l15) * 128 + kb);
                acc[g] = __builtin_amdgcn_mfma_f32_16x16x32_bf16(a, b, acc[g], 0, 0, 0);
            }
        }
        if (t > 0) {
#pragma unroll
            for (int c = 2; c < 4; c++) {   // recurrent from LDS
                int koff = (c & 1) * 32 + q * 8;
                short8 a = *(const short8*)&h2s[l15][koff];
                int kb = c * 32 + q * 8;
#pragma unroll
                for (int g = 0; g < 4; g++) {
                    short8 b = *(const short8*)(B2 + (size_t)((w + 4 * g) * 16 + l15) * 128 + kb);
                    acc[g] = __builtin_amdgcn_mfma_f32_16x16x32_bf16(a, b, acc[g], 0, 0, 0);
                }
            }
        }
        __syncthreads();   // all h2s(t-1) reads done
#pragma unroll
        for (int reg = 0; reg < 4; reg++) {
            float gi = acc[0][reg], gf = acc[1][reg];
            float gg = acc[2][reg], go = acc[3][reg];
            float co = (t == 0) ? 0.f : c2[reg];
            float cn = sigf(gf) * co + sigf(gi) * tanhfast(gg);
            float hn = sigf(go) * tanhfast(cn);
            c2[reg] = cn;
            int nl = q * 4 + reg;
            h2s[nl][w * 16 + l15] = f2b(hn);
            if (t == WINDOW - 1)
                H2out[(size_t)(gnode0 + nl) * 64 + w * 16 + l15] = f2b(hn);
        }
        __syncthreads();   // h2s(t) visible
    }
}

// ------------------------------------------------------ generic fp32 GEMM ---
__global__ __launch_bounds__(256) void k_gemm(const float* A, int lda, const float* B, int ldb,
                                              float* C, int ldc, int M, int N, int K)
{
    __shared__ float As[16][64];
    __shared__ float Bs[16][64];
    int tid = threadIdx.x;
    int tx = tid & 15, ty = tid >> 4;
    int bm = blockIdx.y * 64, bn = blockIdx.x * 64;
    float acc[4][4] = {};
    for (int ks = 0; ks < K; ks += 16) {
        {
            int idx = tid * 4;
            int r = idx >> 4, k4 = idx & 15;
            int gr = bm + r;
            float4 v = make_float4(0.f, 0.f, 0.f, 0.f);
            if (gr < M) v = *(const float4*)&A[(size_t)gr * lda + ks + k4];
            As[k4 + 0][r] = v.x; As[k4 + 1][r] = v.y; As[k4 + 2][r] = v.z; As[k4 + 3][r] = v.w;
        }
        {
            int kb = tid >> 4, n4 = (tid & 15) * 4;
            int gc = bn + n4;
            float4 v = make_float4(0.f, 0.f, 0.f, 0.f);
            if (gc < N) v = *(const float4*)&B[(size_t)(ks + kb) * ldb + gc];
            *(float4*)&Bs[kb][n4] = v;
        }
        __syncthreads();
#pragma unroll
        for (int kk = 0; kk < 16; kk++) {
            float4 a = *(const float4*)&As[kk][ty * 4];
            float4 b = *(const float4*)&Bs[kk][tx * 4];
            float av[4] = {a.x, a.y, a.z, a.w};
            float bv[4] = {b.x, b.y, b.z, b.w};
#pragma unroll
            for (int i = 0; i < 4; i++)
#pragma unroll
                for (int j = 0; j < 4; j++) acc[i][j] = fmaf(av[i], bv[j], acc[i][j]);
        }
        __syncthreads();
    }
#pragma unroll
    for (int i = 0; i < 4; i++) {
        int row = bm + ty * 4 + i, col = bn + tx * 4;
        if (row < M && col < N)
            *(float4*)&C[(size_t)row * ldc + col] = make_float4(acc[i][0], acc[i][1], acc[i][2], acc[i][3]);
    }
}

// ----------------------------------------------------------- small utils ----
__global__ void k_nodeemb(const bf* H1, const bf* H2, const float* x, float* ne) {
    int stride = gridDim.x * blockDim.x;
    for (int idx = blockIdx.x * blockDim.x + threadIdx.x; idx < N_NODES * 160; idx += stride) {
        int n = idx / 160, j = idx % 160;
        float v;
        if (j < 64) v = b2f(H1[(size_t)n * 64 + j]);
        else if (j < 128) v = b2f(H2[(size_t)n * 64 + (j - 64)]);
        else if (j < DHV) {
            int s = j - 128;
            v = (s < 8) ? x[n * IN_C + s] : x[(size_t)((s - 7) * N_NODES + n) * IN_C + 7];
        } else v = 0.f;
        ne[idx] = v;
    }
}

__global__ void k_edge(const int* ewi, const float* PQ, const float* dba,
                       const float* dWb, const float* dbb, float* out) {
    int wid = (blockIdx.x * blockDim.x + threadIdx.x) >> 6;
    int lane = threadIdx.x & 63;
    if (wid >= E_DEC) return;
    int src = ewi[wid], trg = ewi[E_DEC + wid];
    const float* Pr = PQ + (size_t)src * 288;
    const float* Qr = PQ + (size_t)trg * 288 + 144;
    float acc = 0.f;
    for (int u = lane; u < DHV; u += 64) {
        float v = Pr[u] + Qr[u] + dba[u];
        v = fmaxf(v, 0.f);
        acc += v * dWb[u];
    }
#pragma unroll
    for (int off = 32; off > 0; off >>= 1) acc += __shfl_down(acc, off);
    if (lane == 0) out[wid] = acc + dbb[0];
}

// ---------------------------------------------------------------------------
extern "C" void kernel_launch(void* const* d_in, const int* in_sizes, int n_in,
                              void* d_out, int out_size, void* d_ws, size_t ws_size,
                              hipStream_t stream) {
    (void)in_sizes; (void)n_in; (void)out_size; (void)ws_size;
    const float* x    = (const float*)d_in[0];
    const float* ea   = (const float*)d_in[1];
    const int*   ei   = (const int*)d_in[2];
    const int*   ewi  = (const int*)d_in[3];
    const float* W1   = (const float*)d_in[4];
    const float* b1   = (const float*)d_in[5];
    const float* g1   = (const float*)d_in[6];
    const float* be1  = (const float*)d_in[7];
    const float* W2   = (const float*)d_in[8];
    const float* b2   = (const float*)d_in[9];
    const float* g2   = (const float*)d_in[10];
    const float* be2  = (const float*)d_in[11];
    const float* Wih1 = (const float*)d_in[12];
    const float* Whh1 = (const float*)d_in[13];
    const float* bih1 = (const float*)d_in[14];
    const float* bhh1 = (const float*)d_in[15];
    const float* Wih2 = (const float*)d_in[16];
    const float* Whh2 = (const float*)d_in[17];
    const float* bih2 = (const float*)d_in[18];
    const float* bhh2 = (const float*)d_in[19];
    const float* dWa  = (const float*)d_in[20];
    const float* dba  = (const float*)d_in[21];
    const float* dWb  = (const float*)d_in[22];
    const float* dbb  = (const float*)d_in[23];
    float* out = (float*)d_out;

    const size_t NSB = (size_t)N_BIG * 64;   // 10.24M
    const size_t NS  = (size_t)N_NODES * 64; // 1.28M
    char* base = (char*)d_ws;
    size_t o = 0;
    float* dis  = (float*)(base + o); o += (size_t)N_BIG * 4;      // 0.64 MB
    float* aggf = (float*)(base + o); o += NSB * 4;                // 41 MB (gather out / ne,PQ later)
    bf* hbufb   = (bf*)(base + o);    o += NSB * 2;                // 20.5 MB
    bf* h1b     = (bf*)(base + o);    o += NSB * 2;
    bf* h2b     = (bf*)(base + o);    o += NSB * 2;
    bf* hs1     = (bf*)(base + o);    o += NS * 2;
    bf* hs2     = (bf*)(base + o);    o += NS * 2;
    bf* Bcat1   = (bf*)(base + o);    o += 256 * 192 * 2;
    bf* Bcat2   = (bf*)(base + o);    o += 256 * 128 * 2;
    bf* W2t     = (bf*)(base + o);    o += 64 * 64 * 2;
    float* bc1  = (float*)(base + o); o += 256 * 4;
    float* bc2  = (float*)(base + o); o += 256 * 4;
    float* Bpq  = (float*)(base + o); o += 144 * 288 * 4;
    float* stats= (float*)(base + o); o += 256 * 4;
    float2* pairs = (float2*)(base + o); o += (size_t)NE * 8;      // 12.8 MB
    int* offs = (int*)(base + o); o += (size_t)N_BIG * 4;
    int* cnt  = (int*)(base + o); o += (size_t)N_BIG * 4;
    int* cur  = (int*)(base + o); o += (size_t)N_BIG * 4;
    int* part = (int*)(base + o); o += 256 * 4;
    float* ne = aggf;                                // 20000x160 f32 (aggf dead by then)
    float* PQ = aggf + 3200000;                      // 20000x288 f32

    // ---- prep + CSR build ----
    k_prep<<<512, 256, 0, stream>>>(Wih1, Whh1, bih1, bhh1, Wih2, Whh2, bih2, bhh2,
                                    dWa, W2, dis, cnt, Bcat1, Bcat2, W2t, bc1, bc2, Bpq, stats);
    k_deg_count<<<(NE + 255) / 256, 256, 0, stream>>>(ei, ea, dis, cnt);
    k_dis<<<(N_BIG + 255) / 256, 256, 0, stream>>>(dis);
    k_scan1<<<157, 256, 0, stream>>>(cnt, offs, part);
    k_scan2<<<1, 256, 0, stream>>>(part, 157);
    k_scan3<<<157, 256, 0, stream>>>(offs, cur, part);
    k_fill<<<(NE + 255) / 256, 256, 0, stream>>>(ei, ea, dis, cur, pairs);

    // ---- GCN layer 1 ----
    k_xw1<<<N_BIG / 4, 256, 0, stream>>>(x, W1, hbufb);
    k_gcn_gather<<<N_BIG / 4, 256, 0, stream>>>(hbufb, dis, offs, cnt, pairs, b1, aggf);
    k_bnstats<<<256, 256, 0, stream>>>(aggf, stats, stats + 64);
    k_bnapply<<<4096, 256, 0, stream>>>(aggf, g1, be1, stats, stats + 64, h1b);

    // ---- GCN layer 2 ----
    k_h1w2<<<2500, 256, 0, stream>>>(h1b, W2t, hbufb);
    k_gcn_gather<<<N_BIG / 4, 256, 0, stream>>>(hbufb, dis, offs, cnt, pairs, b2, aggf);
    k_bnstats<<<256, 256, 0, stream>>>(aggf, stats + 128, stats + 192);
    k_bnapply<<<4096, 256, 0, stream>>>(aggf, g2, be2, stats + 128, stats + 192, h2b);

    // ---- both LSTMs, all 8 steps, one launch (block = 16 nodes, 4 waves) ----
    k_lstm_fused<<<1250, 256, 0, stream>>>(h1b, h2b, Bcat1, Bcat2, bc1, bc2, hs1, hs2);

    // ---- node embeddings + decoder (fp32) ----
    k_nodeemb<<<12500, 256, 0, stream>>>(hs1, hs2, x, ne);
    {
        dim3 g(5, 313);
        k_gemm<<<g, 256, 0, stream>>>(ne, 160, Bpq, 288, PQ, 288, N_NODES, 288, 144);
    }
    k_edge<<<E_DEC / 4, 256, 0, stream>>>(ewi, PQ, dba, dWb, dbb, out);
}

// Round 7
// 939.415 us; speedup vs baseline: 2.0475x; 1.1557x over previous
//
#include <hip/hip_runtime.h>
#include <hip/hip_bf16.h>

#define IN_C 8
#define HID 64
#define N_NODES 20000
#define WINDOW 8
#define N_BIG 160000
#define NE 1600000
#define E_DEC 500000
#define DHV 143
#define EPSV 1e-5f

typedef __hip_bfloat16 bf;
typedef __attribute__((ext_vector_type(8))) short short8;
typedef __attribute__((ext_vector_type(4))) float float4_;

__device__ __forceinline__ float b2f(bf v) { return __bfloat162float(v); }
__device__ __forceinline__ bf f2b(float v) { return __float2bfloat16(v); }
// v_rcp_f32-based activations (rel err ~1e-6, way below bf16 noise)
__device__ __forceinline__ float sigf(float x) {
    return __builtin_amdgcn_rcpf(1.f + __expf(-x));
}
__device__ __forceinline__ float tanhfast(float x) {
    x = fminf(fmaxf(x, -15.f), 15.f);
    float e = __expf(2.f * x);
    return (e - 1.f) * __builtin_amdgcn_rcpf(e + 1.f);
}

// ---------------------------------------------------------------- prep ------
// B1f/B2f: LSTM weights pre-swizzled into MFMA fragment order
// [tile ct][chunk c][lane][j] so a wave's B-fragment load is one coalesced
// 1KB burst. ct in 0..15 (gate-quarter*4 + ...), lane = q*16+l15 ->
// element [n=ct*16+l15][k=c*32+q*8+j].
__global__ void k_prep(const float* Wih1, const float* Whh1, const float* bih1, const float* bhh1,
                       const float* Wih2, const float* Whh2, const float* bih2, const float* bhh2,
                       const float* dWa, const float* W2,
                       float* deg, int* cnt, bf* B1f, bf* B2f, bf* W2t,
                       float* bc1, float* bc2, float* Bpq, float* stats)
{
    int i0 = blockIdx.x * blockDim.x + threadIdx.x;
    int stride = gridDim.x * blockDim.x;
    for (int i = i0; i < N_BIG; i += stride) { deg[i] = 1.0f; cnt[i] = 0; }
    for (int i = i0; i < 16 * 6 * 64 * 8; i += stride) {   // B1 fragments (K=192)
        int j = i & 7, lane = (i >> 3) & 63, r = i >> 9;
        int c = r % 6, ct = r / 6;
        int q = lane >> 4, l15 = lane & 15;
        int n = ct * 16 + l15, k = c * 32 + q * 8 + j;
        B1f[i] = f2b((k < 128) ? Wih1[n * 128 + k] : Whh1[n * 64 + (k - 128)]);
    }
    for (int i = i0; i < 16 * 4 * 64 * 8; i += stride) {   // B2 fragments (K=128)
        int j = i & 7, lane = (i >> 3) & 63, r = i >> 9;
        int c = r & 3, ct = r >> 2;
        int q = lane >> 4, l15 = lane & 15;
        int n = ct * 16 + l15, k = c * 32 + q * 8 + j;
        B2f[i] = f2b((k < 64) ? Wih2[n * 64 + k] : Whh2[n * 64 + (k - 64)]);
    }
    for (int i = i0; i < 64 * 64; i += stride) {          // W2^T [n][k]
        int n = i >> 6, k = i & 63;
        W2t[i] = f2b(W2[k * 64 + n]);
    }
    for (int i = i0; i < 256; i += stride) {
        bc1[i] = bih1[i] + bhh1[i];
        bc2[i] = bih2[i] + bhh2[i];
    }
    for (int i = i0; i < 144 * 288; i += stride) {        // [dWa_top | dWa_bot], padded fp32
        int k = i / 288, n = i % 288;
        float v = 0.f;
        if (k < DHV) {
            if (n < DHV) v = dWa[k * DHV + n];
            else if (n >= 144 && n < 144 + DHV) v = dWa[(DHV + k) * DHV + (n - 144)];
        }
        Bpq[i] = v;
    }
    for (int i = i0; i < 256; i += stride) stats[i] = 0.f;
}

// -------------------------------------------------- degree + edge count -----
__global__ void k_deg_count(const int* ei, const float* ea, float* deg, int* cnt) {
    int e = blockIdx.x * blockDim.x + threadIdx.x;
    if (e >= NE) return;
    int c = ei[NE + e];
    unsafeAtomicAdd(&deg[c], ea[e]);
    atomicAdd(&cnt[c], 1);
}

__global__ void k_dis(float* deg) {
    int i = blockIdx.x * blockDim.x + threadIdx.x;
    if (i < N_BIG) {
        float d = deg[i];
        deg[i] = (d > 0.f) ? rsqrtf(fmaxf(d, EPSV)) : 0.f;
    }
}

// ----------------------------------------------- exclusive scan (3-phase) ---
__global__ __launch_bounds__(256) void k_scan1(const int* cnt, int* offs, int* part) {
    __shared__ int s[256];
    int tid = threadIdx.x;
    int base = blockIdx.x * 1024 + tid * 4;
    int c[4];
    int sum = 0;
#pragma unroll
    for (int j = 0; j < 4; j++) {
        c[j] = (base + j < N_BIG) ? cnt[base + j] : 0;
        sum += c[j];
    }
    s[tid] = sum;
    __syncthreads();
    for (int off = 1; off < 256; off <<= 1) {
        int v = (tid >= off) ? s[tid - off] : 0;
        __syncthreads();
        s[tid] += v;
        __syncthreads();
    }
    int run = s[tid] - sum;
#pragma unroll
    for (int j = 0; j < 4; j++) {
        if (base + j < N_BIG) offs[base + j] = run;
        run += c[j];
    }
    if (tid == 255) part[blockIdx.x] = s[255];
}

__global__ __launch_bounds__(256) void k_scan2(int* part, int np) {
    __shared__ int s[256];
    int tid = threadIdx.x;
    int v = (tid < np) ? part[tid] : 0;
    s[tid] = v;
    __syncthreads();
    for (int off = 1; off < 256; off <<= 1) {
        int w = (tid >= off) ? s[tid - off] : 0;
        __syncthreads();
        s[tid] += w;
        __syncthreads();
    }
    if (tid < np) part[tid] = s[tid] - v;
}

__global__ __launch_bounds__(256) void k_scan3(int* offs, int* cur, const int* part) {
    int add = part[blockIdx.x];
    int base = blockIdx.x * 1024 + threadIdx.x * 4;
#pragma unroll
    for (int j = 0; j < 4; j++) {
        if (base + j < N_BIG) {
            int v = offs[base + j] + add;
            offs[base + j] = v;
            cur[base + j] = v;
        }
    }
}

// ------------------------------------------------------------ CSR fill ------
__global__ void k_fill(const int* ei, const float* ea, const float* dis, int* cur, float2* pairs) {
    int e = blockIdx.x * blockDim.x + threadIdx.x;
    if (e >= NE) return;
    int r = ei[e], c = ei[NE + e];
    float norm = dis[r] * ea[e] * dis[c];
    int p = atomicAdd(&cur[c], 1);
    pairs[p] = make_float2(__int_as_float(r), norm);
}

// ------------------------------------------------------------ x @ W1 --------
__global__ __launch_bounds__(256) void k_xw1(const float* x, const float* W1, bf* hbufb) {
    __shared__ float Ws[IN_C * HID];
    __shared__ float xs[4][IN_C];
    int tid = threadIdx.x;
    Ws[tid] = W1[tid];
    Ws[tid + 256] = W1[tid + 256];
    int node0 = blockIdx.x * 4;
    if (tid < 32) xs[tid >> 3][tid & 7] = x[node0 * IN_C + tid];
    __syncthreads();
    int ch = tid & 63, ns = tid >> 6;
    float acc = 0.f;
#pragma unroll
    for (int c = 0; c < IN_C; c++) acc += xs[ns][c] * Ws[c * 64 + ch];
    hbufb[(size_t)(node0 + ns) * 64 + ch] = f2b(acc);
}

// ------------------------------------------- GCN aggregation (CSR gather) ---
// wave per node, 4-wide unrolled for memory-level parallelism
__global__ void k_gcn_gather(const bf* h, const float* dis, const int* offs, const int* cnt,
                             const float2* pairs, const float* bias, float* outf) {
    int c = (blockIdx.x * blockDim.x + threadIdx.x) >> 6;
    int lane = threadIdx.x & 63;
    if (c >= N_BIG) return;
    float d = dis[c];
    float acc = d * d * b2f(h[(size_t)c * 64 + lane]);
    int o = offs[c], n = cnt[c];
    int e = 0;
    for (; e + 4 <= n; e += 4) {
        float2 p0 = pairs[o + e + 0];
        float2 p1 = pairs[o + e + 1];
        float2 p2 = pairs[o + e + 2];
        float2 p3 = pairs[o + e + 3];
        float v0 = b2f(h[(size_t)__float_as_int(p0.x) * 64 + lane]);
        float v1 = b2f(h[(size_t)__float_as_int(p1.x) * 64 + lane]);
        float v2 = b2f(h[(size_t)__float_as_int(p2.x) * 64 + lane]);
        float v3 = b2f(h[(size_t)__float_as_int(p3.x) * 64 + lane]);
        acc += p0.y * v0 + p1.y * v1 + p2.y * v2 + p3.y * v3;
    }
    for (; e < n; e++) {
        float2 p = pairs[o + e];
        acc += p.y * b2f(h[(size_t)__float_as_int(p.x) * 64 + lane]);
    }
    outf[(size_t)c * 64 + lane] = fmaxf(acc + bias[lane], 0.f);
}

// ------------------------------------------------------------ BatchNorm -----
__global__ void k_bnstats(const float* buf, float* s_sum, float* s_sq) {
    int ch = threadIdx.x & 63, g = threadIdx.x >> 6;
    float s = 0.f, q = 0.f;
    for (int r = blockIdx.x * 4 + g; r < N_BIG; r += gridDim.x * 4) {
        float v = buf[(size_t)r * 64 + ch];
        s += v;
        q += v * v;
    }
    unsafeAtomicAdd(&s_sum[ch], s);
    unsafeAtomicAdd(&s_sq[ch], q);
}

__global__ void k_bnapply(const float* buf, const float* gamma, const float* beta,
                          const float* s_sum, const float* s_sq, bf* outb) {
    const float invn = 1.f / (float)N_BIG;
    int stride = gridDim.x * blockDim.x;
    for (int idx = blockIdx.x * blockDim.x + threadIdx.x; idx < N_BIG * 64; idx += stride) {
        int ch = idx & 63;
        float m = s_sum[ch] * invn;
        float var = s_sq[ch] * invn - m * m;
        outb[idx] = f2b((buf[idx] - m) * rsqrtf(var + EPSV) * gamma[ch] + beta[ch]);
    }
}

// ------------------------------------------------- h1 @ W2 (bf16 MFMA) ------
__global__ __launch_bounds__(256) void k_h1w2(const bf* h1b, const bf* W2t, bf* outb) {
    int tid = threadIdx.x, w = tid >> 6, lane = tid & 63;
    int q = lane >> 4, l15 = lane & 15;
    size_t r0 = (size_t)blockIdx.x * 64 + w * 16;
    float4_ acc[4];
#pragma unroll
    for (int ct = 0; ct < 4; ct++) acc[ct] = (float4_){0.f, 0.f, 0.f, 0.f};
#pragma unroll
    for (int c = 0; c < 2; c++) {
        int koff = c * 32 + q * 8;
        short8 a = *(const short8*)(h1b + (r0 + l15) * 64 + koff);
#pragma unroll
        for (int ct = 0; ct < 4; ct++) {
            short8 b = *(const short8*)(W2t + (size_t)(ct * 16 + l15) * 64 + koff);
            acc[ct] = __builtin_amdgcn_mfma_f32_16x16x32_bf16(a, b, acc[ct], 0, 0, 0);
        }
    }
    size_t node0 = r0 + q * 4;
#pragma unroll
    for (int reg = 0; reg < 4; reg++)
#pragma unroll
        for (int ct = 0; ct < 4; ct++)
            outb[(node0 + reg) * 64 + ct * 16 + l15] = f2b(acc[ct][reg]);
}

// ----------------------------------------- fully fused double LSTM (MFMA) ---
// Block = 256 thr = 4 waves; block owns 32 nodes (2 groups of 16) for all 8
// steps of both LSTMs. Wave w computes gate tiles {w,w+4,w+8,w+12} = i/f/g/o
// of units [16w,16w+16) -> in-register cell update. ALL B fragments preloaded
// into registers from fragment-ordered B1f/B2f (coalesced 1KB bursts; 160
// VGPRs persistent) -> zero B traffic inside the t-loop. h state via LDS
// (stride-72 rows: free 2-way conflicts), c state in regs. Grid 625.
__global__ __launch_bounds__(256, 1) void k_lstm_fused(
    const bf* h1b, const bf* h2b, const bf* B1f, const bf* B2f,
    const float* bc1, const float* bc2, bf* H1out, bf* H2out)
{
    __shared__ bf h1s[32][72];
    __shared__ bf h2s[32][72];
    int tid = threadIdx.x, w = tid >> 6, lane = tid & 63;
    int q = lane >> 4, l15 = lane & 15;
    int gnode0 = blockIdx.x * 32;
    // ---- preload B fragments (per-wave tile set, coalesced) ----
    short8 B1r[6][4];
    short8 B2r[4][4];
#pragma unroll
    for (int c = 0; c < 6; c++)
#pragma unroll
        for (int g = 0; g < 4; g++)
            B1r[c][g] = *(const short8*)(B1f + (size_t)(((w + 4 * g) * 6 + c) * 64 + lane) * 8);
#pragma unroll
    for (int c = 0; c < 4; c++)
#pragma unroll
        for (int g = 0; g < 4; g++)
            B2r[c][g] = *(const short8*)(B2f + (size_t)(((w + 4 * g) * 4 + c) * 64 + lane) * 8);
    float c1[2][4] = {}, c2[2][4] = {};
    float bv1[4], bv2[4];
#pragma unroll
    for (int g = 0; g < 4; g++) {
        bv1[g] = bc1[(w + 4 * g) * 16 + l15];
        bv2[g] = bc2[(w + 4 * g) * 16 + l15];
    }
    for (int t = 0; t < WINDOW; t++) {
        const size_t toff = (size_t)t * N_NODES * 64;
        // ======== LSTM 1: gates = [h1b_t | h2b_t | h1_{t-1}] @ B1 ========
        float4_ acc[2][4];
#pragma unroll
        for (int m = 0; m < 2; m++)
#pragma unroll
            for (int g = 0; g < 4; g++) acc[m][g] = (float4_){bv1[g], bv1[g], bv1[g], bv1[g]};
#pragma unroll
        for (int c = 0; c < 4; c++) {   // global input chunks
            const bf* sp = (c < 2) ? h1b + toff : h2b + toff;
            int koff = (c & 1) * 32 + q * 8;
#pragma unroll
            for (int m = 0; m < 2; m++) {
                short8 a = *(const short8*)(sp + (size_t)(gnode0 + m * 16 + l15) * 64 + koff);
#pragma unroll
                for (int g = 0; g < 4; g++)
                    acc[m][g] = __builtin_amdgcn_mfma_f32_16x16x32_bf16(a, B1r[c][g], acc[m][g], 0, 0, 0);
            }
        }
        if (t > 0) {
#pragma unroll
            for (int c = 4; c < 6; c++) {   // recurrent chunks from LDS
                int koff = (c & 1) * 32 + q * 8;
#pragma unroll
                for (int m = 0; m < 2; m++) {
                    short8 a = *(const short8*)&h1s[m * 16 + l15][koff];
#pragma unroll
                    for (int g = 0; g < 4; g++)
                        acc[m][g] = __builtin_amdgcn_mfma_f32_16x16x32_bf16(a, B1r[c][g], acc[m][g], 0, 0, 0);
                }
            }
        }
        __syncthreads();   // all h1s(t-1) reads done before overwrite
#pragma unroll
        for (int m = 0; m < 2; m++)
#pragma unroll
            for (int reg = 0; reg < 4; reg++) {
                float gi = acc[m][0][reg], gf = acc[m][1][reg];
                float gg = acc[m][2][reg], go = acc[m][3][reg];
                float co = (t == 0) ? 0.f : c1[m][reg];
                float cn = sigf(gf) * co + sigf(gi) * tanhfast(gg);
                float hn = sigf(go) * tanhfast(cn);
                c1[m][reg] = cn;
                int nl = m * 16 + q * 4 + reg;
                h1s[nl][w * 16 + l15] = f2b(hn);
                if (t == WINDOW - 1)
                    H1out[(size_t)(gnode0 + nl) * 64 + w * 16 + l15] = f2b(hn);
            }
        __syncthreads();   // h1s(t) visible
        // ======== LSTM 2: gates = [h1_t | h2_{t-1}] @ B2 ========
#pragma unroll
        for (int m = 0; m < 2; m++)
#pragma unroll
            for (int g = 0; g < 4; g++) acc[m][g] = (float4_){bv2[g], bv2[g], bv2[g], bv2[g]};
#pragma unroll
        for (int c = 0; c < 2; c++) {   // y1_t = h1_t from LDS
            int koff = (c & 1) * 32 + q * 8;
#pragma unroll
            for (int m = 0; m < 2; m++) {
                short8 a = *(const short8*)&h1s[m * 16 + l15][koff];
#pragma unroll
                for (int g = 0; g < 4; g++)
                    acc[m][g] = __builtin_amdgcn_mfma_f32_16x16x32_bf16(a, B2r[c][g], acc[m][g], 0, 0, 0);
            }
        }
        if (t > 0) {
#pragma unroll
            for (int c = 2; c < 4; c++) {   // recurrent from LDS
                int koff = (c & 1) * 32 + q * 8;
#pragma unroll
                for (int m = 0; m < 2; m++) {
                    short8 a = *(const short8*)&h2s[m * 16 + l15][koff];
#pragma unroll
                    for (int g = 0; g < 4; g++)
                        acc[m][g] = __builtin_amdgcn_mfma_f32_16x16x32_bf16(a, B2r[c][g], acc[m][g], 0, 0, 0);
                }
            }
        }
        __syncthreads();   // all h2s(t-1) reads done
#pragma unroll
        for (int m = 0; m < 2; m++)
#pragma unroll
            for (int reg = 0; reg < 4; reg++) {
                float gi = acc[m][0][reg], gf = acc[m][1][reg];
                float gg = acc[m][2][reg], go = acc[m][3][reg];
                float co = (t == 0) ? 0.f : c2[m][reg];
                float cn = sigf(gf) * co + sigf(gi) * tanhfast(gg);
                float hn = sigf(go) * tanhfast(cn);
                c2[m][reg] = cn;
                int nl = m * 16 + q * 4 + reg;
                h2s[nl][w * 16 + l15] = f2b(hn);
                if (t == WINDOW - 1)
                    H2out[(size_t)(gnode0 + nl) * 64 + w * 16 + l15] = f2b(hn);
            }
        __syncthreads();   // h2s(t) visible
    }
}

// ------------------------------------------------------ generic fp32 GEMM ---
__global__ __launch_bounds__(256) void k_gemm(const float* A, int lda, const float* B, int ldb,
                                              float* C, int ldc, int M, int N, int K)
{
    __shared__ float As[16][64];
    __shared__ float Bs[16][64];
    int tid = threadIdx.x;
    int tx = tid & 15, ty = tid >> 4;
    int bm = blockIdx.y * 64, bn = blockIdx.x * 64;
    float acc[4][4] = {};
    for (int ks = 0; ks < K; ks += 16) {
        {
            int idx = tid * 4;
            int r = idx >> 4, k4 = idx & 15;
            int gr = bm + r;
            float4 v = make_float4(0.f, 0.f, 0.f, 0.f);
            if (gr < M) v = *(const float4*)&A[(size_t)gr * lda + ks + k4];
            As[k4 + 0][r] = v.x; As[k4 + 1][r] = v.y; As[k4 + 2][r] = v.z; As[k4 + 3][r] = v.w;
        }
        {
            int kb = tid >> 4, n4 = (tid & 15) * 4;
            int gc = bn + n4;
            float4 v = make_float4(0.f, 0.f, 0.f, 0.f);
            if (gc < N) v = *(const float4*)&B[(size_t)(ks + kb) * ldb + gc];
            *(float4*)&Bs[kb][n4] = v;
        }
        __syncthreads();
#pragma unroll
        for (int kk = 0; kk < 16; kk++) {
            float4 a = *(const float4*)&As[kk][ty * 4];
            float4 b = *(const float4*)&Bs[kk][tx * 4];
            float av[4] = {a.x, a.y, a.z, a.w};
            float bv[4] = {b.x, b.y, b.z, b.w};
#pragma unroll
            for (int i = 0; i < 4; i++)
#pragma unroll
                for (int j = 0; j < 4; j++) acc[i][j] = fmaf(av[i], bv[j], acc[i][j]);
        }
        __syncthreads();
    }
#pragma unroll
    for (int i = 0; i < 4; i++) {
        int row = bm + ty * 4 + i, col = bn + tx * 4;
        if (row < M && col < N)
            *(float4*)&C[(size_t)row * ldc + col] = make_float4(acc[i][0], acc[i][1], acc[i][2], acc[i][3]);
    }
}

// ----------------------------------------------------------- small utils ----
__global__ void k_nodeemb(const bf* H1, const bf* H2, const float* x, float* ne) {
    int stride = gridDim.x * blockDim.x;
    for (int idx = blockIdx.x * blockDim.x + threadIdx.x; idx < N_NODES * 160; idx += stride) {
        int n = idx / 160, j = idx % 160;
        float v;
        if (j < 64) v = b2f(H1[(size_t)n * 64 + j]);
        else if (j < 128) v = b2f(H2[(size_t)n * 64 + (j - 64)]);
        else if (j < DHV) {
            int s = j - 128;
            v = (s < 8) ? x[n * IN_C + s] : x[(size_t)((s - 7) * N_NODES + n) * IN_C + 7];
        } else v = 0.f;
        ne[idx] = v;
    }
}

__global__ void k_edge(const int* ewi, const float* PQ, const float* dba,
                       const float* dWb, const float* dbb, float* out) {
    int wid = (blockIdx.x * blockDim.x + threadIdx.x) >> 6;
    int lane = threadIdx.x & 63;
    if (wid >= E_DEC) return;
    int src = ewi[wid], trg = ewi[E_DEC + wid];
    const float* Pr = PQ + (size_t)src * 288;
    const float* Qr = PQ + (size_t)trg * 288 + 144;
    float acc = 0.f;
    for (int u = lane; u < DHV; u += 64) {
        float v = Pr[u] + Qr[u] + dba[u];
        v = fmaxf(v, 0.f);
        acc += v * dWb[u];
    }
#pragma unroll
    for (int off = 32; off > 0; off >>= 1) acc += __shfl_down(acc, off);
    if (lane == 0) out[wid] = acc + dbb[0];
}

// ---------------------------------------------------------------------------
extern "C" void kernel_launch(void* const* d_in, const int* in_sizes, int n_in,
                              void* d_out, int out_size, void* d_ws, size_t ws_size,
                              hipStream_t stream) {
    (void)in_sizes; (void)n_in; (void)out_size; (void)ws_size;
    const float* x    = (const float*)d_in[0];
    const float* ea   = (const float*)d_in[1];
    const int*   ei   = (const int*)d_in[2];
    const int*   ewi  = (const int*)d_in[3];
    const float* W1   = (const float*)d_in[4];
    const float* b1   = (const float*)d_in[5];
    const float* g1   = (const float*)d_in[6];
    const float* be1  = (const float*)d_in[7];
    const float* W2   = (const float*)d_in[8];
    const float* b2   = (const float*)d_in[9];
    const float* g2   = (const float*)d_in[10];
    const float* be2  = (const float*)d_in[11];
    const float* Wih1 = (const float*)d_in[12];
    const float* Whh1 = (const float*)d_in[13];
    const float* bih1 = (const float*)d_in[14];
    const float* bhh1 = (const float*)d_in[15];
    const float* Wih2 = (const float*)d_in[16];
    const float* Whh2 = (const float*)d_in[17];
    const float* bih2 = (const float*)d_in[18];
    const float* bhh2 = (const float*)d_in[19];
    const float* dWa  = (const float*)d_in[20];
    const float* dba  = (const float*)d_in[21];
    const float* dWb  = (const float*)d_in[22];
    const float* dbb  = (const float*)d_in[23];
    float* out = (float*)d_out;

    const size_t NSB = (size_t)N_BIG * 64;   // 10.24M
    const size_t NS  = (size_t)N_NODES * 64; // 1.28M
    char* base = (char*)d_ws;
    size_t o = 0;
    float* dis  = (float*)(base + o); o += (size_t)N_BIG * 4;      // 0.64 MB
    float* aggf = (float*)(base + o); o += NSB * 4;                // 41 MB (gather out / ne,PQ later)
    bf* hbufb   = (bf*)(base + o);    o += NSB * 2;                // 20.5 MB
    bf* h1b     = (bf*)(base + o);    o += NSB * 2;
    bf* h2b     = (bf*)(base + o);    o += NSB * 2;
    bf* hs1     = (bf*)(base + o);    o += NS * 2;
    bf* hs2     = (bf*)(base + o);    o += NS * 2;
    bf* B1f     = (bf*)(base + o);    o += (size_t)16 * 6 * 64 * 8 * 2;   // 96 KB
    bf* B2f     = (bf*)(base + o);    o += (size_t)16 * 4 * 64 * 8 * 2;   // 64 KB
    bf* W2t     = (bf*)(base + o);    o += 64 * 64 * 2;
    float* bc1  = (float*)(base + o); o += 256 * 4;
    float* bc2  = (float*)(base + o); o += 256 * 4;
    float* Bpq  = (float*)(base + o); o += 144 * 288 * 4;
    float* stats= (float*)(base + o); o += 256 * 4;
    float2* pairs = (float2*)(base + o); o += (size_t)NE * 8;      // 12.8 MB
    int* offs = (int*)(base + o); o += (size_t)N_BIG * 4;
    int* cnt  = (int*)(base + o); o += (size_t)N_BIG * 4;
    int* cur  = (int*)(base + o); o += (size_t)N_BIG * 4;
    int* part = (int*)(base + o); o += 256 * 4;
    float* ne = aggf;                                // 20000x160 f32 (aggf dead by then)
    float* PQ = aggf + 3200000;                      // 20000x288 f32

    // ---- prep + CSR build ----
    k_prep<<<512, 256, 0, stream>>>(Wih1, Whh1, bih1, bhh1, Wih2, Whh2, bih2, bhh2,
                                    dWa, W2, dis, cnt, B1f, B2f, W2t, bc1, bc2, Bpq, stats);
    k_deg_count<<<(NE + 255) / 256, 256, 0, stream>>>(ei, ea, dis, cnt);
    k_dis<<<(N_BIG + 255) / 256, 256, 0, stream>>>(dis);
    k_scan1<<<157, 256, 0, stream>>>(cnt, offs, part);
    k_scan2<<<1, 256, 0, stream>>>(part, 157);
    k_scan3<<<157, 256, 0, stream>>>(offs, cur, part);
    k_fill<<<(NE + 255) / 256, 256, 0, stream>>>(ei, ea, dis, cur, pairs);

    // ---- GCN layer 1 ----
    k_xw1<<<N_BIG / 4, 256, 0, stream>>>(x, W1, hbufb);
    k_gcn_gather<<<N_BIG / 4, 256, 0, stream>>>(hbufb, dis, offs, cnt, pairs, b1, aggf);
    k_bnstats<<<256, 256, 0, stream>>>(aggf, stats, stats + 64);
    k_bnapply<<<4096, 256, 0, stream>>>(aggf, g1, be1, stats, stats + 64, h1b);

    // ---- GCN layer 2 ----
    k_h1w2<<<2500, 256, 0, stream>>>(h1b, W2t, hbufb);
    k_gcn_gather<<<N_BIG / 4, 256, 0, stream>>>(hbufb, dis, offs, cnt, pairs, b2, aggf);
    k_bnstats<<<256, 256, 0, stream>>>(aggf, stats + 128, stats + 192);
    k_bnapply<<<4096, 256, 0, stream>>>(aggf, g2, be2, stats + 128, stats + 192, h2b);

    // ---- both LSTMs, all 8 steps, one launch (block = 32 nodes, 4 waves) ----
    k_lstm_fused<<<625, 256, 0, stream>>>(h1b, h2b, B1f, B2f, bc1, bc2, hs1, hs2);

    // ---- node embeddings + decoder (fp32) ----
    k_nodeemb<<<12500, 256, 0, stream>>>(hs1, hs2, x, ne);
    {
        dim3 g(5, 313);
        k_gemm<<<g, 256, 0, stream>>>(ne, 160, Bpq, 288, PQ, 288, N_NODES, 288, 144);
    }
    k_edge<<<E_DEC / 4, 256, 0, stream>>>(ewi, PQ, dba, dWb, dbb, out);
}

// Round 8
// 829.917 us; speedup vs baseline: 2.3177x; 1.1319x over previous
//
#include <hip/hip_runtime.h>
#include <hip/hip_bf16.h>

#define IN_C 8
#define HID 64
#define N_NODES 20000
#define WINDOW 8
#define N_BIG 160000
#define NE 1600000
#define E_DEC 500000
#define DHV 143
#define EPSV 1e-5f

typedef __hip_bfloat16 bf;
typedef unsigned long long ull;
typedef __attribute__((ext_vector_type(8))) short short8;
typedef __attribute__((ext_vector_type(4))) float float4_;

__device__ __forceinline__ float b2f(bf v) { return __bfloat162float(v); }
__device__ __forceinline__ bf f2b(float v) { return __float2bfloat16(v); }
__device__ __forceinline__ float sigf(float x) {
    return __builtin_amdgcn_rcpf(1.f + __expf(-x));
}
__device__ __forceinline__ float tanhfast(float x) {
    x = fminf(fmaxf(x, -15.f), 15.f);
    float e = __expf(2.f * x);
    return (e - 1.f) * __builtin_amdgcn_rcpf(e + 1.f);
}

// ---------------------------------------------------------------- prep ------
// B1f/B2f/Bpqf: weights pre-swizzled into MFMA fragment order
// [tile][chunk][lane][8] -> a wave's B-fragment load is one coalesced 1KB burst.
__global__ void k_prep(const float* Wih1, const float* Whh1, const float* bih1, const float* bhh1,
                       const float* Wih2, const float* Whh2, const float* bih2, const float* bhh2,
                       const float* dWa,  const float* W2,
                       ull* deg64, bf* B1f, bf* B2f, bf* W2t,
                       float* bc1, float* bc2, bf* Bpqf, float* stats)
{
    int i0 = blockIdx.x * blockDim.x + threadIdx.x;
    int stride = gridDim.x * blockDim.x;
    for (int i = i0; i < N_BIG; i += stride) deg64[i] = 0ull;
    for (int i = i0; i < 16 * 6 * 64 * 8; i += stride) {   // B1 fragments (K=192)
        int j = i & 7, lane = (i >> 3) & 63, r = i >> 9;
        int c = r % 6, ct = r / 6;
        int q = lane >> 4, l15 = lane & 15;
        int n = ct * 16 + l15, k = c * 32 + q * 8 + j;
        B1f[i] = f2b((k < 128) ? Wih1[n * 128 + k] : Whh1[n * 64 + (k - 128)]);
    }
    for (int i = i0; i < 16 * 4 * 64 * 8; i += stride) {   // B2 fragments (K=128)
        int j = i & 7, lane = (i >> 3) & 63, r = i >> 9;
        int c = r & 3, ct = r >> 2;
        int q = lane >> 4, l15 = lane & 15;
        int n = ct * 16 + l15, k = c * 32 + q * 8 + j;
        B2f[i] = f2b((k < 64) ? Wih2[n * 64 + k] : Whh2[n * 64 + (k - 64)]);
    }
    for (int i = i0; i < 64 * 64; i += stride) {          // W2^T [n][k]
        int n = i >> 6, k = i & 63;
        W2t[i] = f2b(W2[k * 64 + n]);
    }
    for (int i = i0; i < 256; i += stride) {
        bc1[i] = bih1[i] + bhh1[i];
        bc2[i] = bih2[i] + bhh2[i];
    }
    // decoder weight fragments: N=288 (18 tiles: P cols 0..143, Q cols 144..287),
    // K=160 (5 chunks; k<143 real, else 0)
    for (int i = i0; i < 18 * 5 * 64 * 8; i += stride) {
        int j = i & 7, lane = (i >> 3) & 63, r = i >> 9;
        int c = r % 5, ct = r / 5;
        int q = lane >> 4, l15 = lane & 15;
        int n = ct * 16 + l15, k = c * 32 + q * 8 + j;
        float v = 0.f;
        if (k < DHV) {
            if (n < DHV) v = dWa[k * DHV + n];                       // P block
            else if (n >= 144 && n < 144 + DHV) v = dWa[(DHV + k) * DHV + (n - 144)]; // Q block
        }
        Bpqf[i] = f2b(v);
    }
    for (int i = i0; i < 256; i += stride) stats[i] = 0.f;
}

// ---------------------------------- degree + edge count (one packed atomic) --
// bits 40+: count; bits 0..39: sum(ea) in 2^-24 fixed point (max ~2^30, safe)
__global__ void k_deg_count(const int* ei, const float* ea, ull* deg64) {
    int e = blockIdx.x * blockDim.x + threadIdx.x;
    if (e >= NE) return;
    int c = ei[NE + e];
    unsigned int q = (unsigned int)(ea[e] * 16777216.f + 0.5f);
    atomicAdd(&deg64[c], (1ull << 40) | (ull)q);
}

__global__ void k_dis(const ull* deg64, float* dis, int* cnt) {
    int i = blockIdx.x * blockDim.x + threadIdx.x;
    if (i < N_BIG) {
        ull v = deg64[i];
        cnt[i] = (int)(v >> 40);
        float deg = 1.f + (float)(v & 0xFFFFFFFFFFull) * (1.f / 16777216.f);
        dis[i] = rsqrtf(fmaxf(deg, EPSV));
    }
}

// ----------------------------------------------- exclusive scan (3-phase) ---
__global__ __launch_bounds__(256) void k_scan1(const int* cnt, int* offs, int* part) {
    __shared__ int s[256];
    int tid = threadIdx.x;
    int base = blockIdx.x * 1024 + tid * 4;
    int c[4];
    int sum = 0;
#pragma unroll
    for (int j = 0; j < 4; j++) {
        c[j] = (base + j < N_BIG) ? cnt[base + j] : 0;
        sum += c[j];
    }
    s[tid] = sum;
    __syncthreads();
    for (int off = 1; off < 256; off <<= 1) {
        int v = (tid >= off) ? s[tid - off] : 0;
        __syncthreads();
        s[tid] += v;
        __syncthreads();
    }
    int run = s[tid] - sum;
#pragma unroll
    for (int j = 0; j < 4; j++) {
        if (base + j < N_BIG) offs[base + j] = run;
        run += c[j];
    }
    if (tid == 255) part[blockIdx.x] = s[255];
}

__global__ __launch_bounds__(256) void k_scan2(int* part, int np) {
    __shared__ int s[256];
    int tid = threadIdx.x;
    int v = (tid < np) ? part[tid] : 0;
    s[tid] = v;
    __syncthreads();
    for (int off = 1; off < 256; off <<= 1) {
        int w = (tid >= off) ? s[tid - off] : 0;
        __syncthreads();
        s[tid] += w;
        __syncthreads();
    }
    if (tid < np) part[tid] = s[tid] - v;
}

__global__ __launch_bounds__(256) void k_scan3(int* offs, int* cur, const int* part) {
    int add = part[blockIdx.x];
    int base = blockIdx.x * 1024 + threadIdx.x * 4;
#pragma unroll
    for (int j = 0; j < 4; j++) {
        if (base + j < N_BIG) {
            int v = offs[base + j] + add;
            offs[base + j] = v;
            cur[base + j] = v;
        }
    }
}

// ------------------------------------------------------------ CSR fill ------
__global__ void k_fill(const int* ei, const float* ea, const float* dis, int* cur, float2* pairs) {
    int e = blockIdx.x * blockDim.x + threadIdx.x;
    if (e >= NE) return;
    int r = ei[e], c = ei[NE + e];
    float norm = dis[r] * ea[e] * dis[c];
    int p = atomicAdd(&cur[c], 1);
    pairs[p] = make_float2(__int_as_float(r), norm);
}

// ------------------------------------------------------------ x @ W1 --------
__global__ __launch_bounds__(256) void k_xw1(const float* x, const float* W1, bf* hbufb) {
    __shared__ float Ws[IN_C * HID];
    __shared__ float xs[4][IN_C];
    int tid = threadIdx.x;
    Ws[tid] = W1[tid];
    Ws[tid + 256] = W1[tid + 256];
    int node0 = blockIdx.x * 4;
    if (tid < 32) xs[tid >> 3][tid & 7] = x[node0 * IN_C + tid];
    __syncthreads();
    int ch = tid & 63, ns = tid >> 6;
    float acc = 0.f;
#pragma unroll
    for (int c = 0; c < IN_C; c++) acc += xs[ns][c] * Ws[c * 64 + ch];
    hbufb[(size_t)(node0 + ns) * 64 + ch] = f2b(acc);
}

// ------------------------------------------- GCN aggregation (CSR gather) ---
// wave per node, 8-wide unrolled for memory-level parallelism; bf16 out
__global__ void k_gcn_gather(const bf* h, const float* dis, const int* offs, const int* cnt,
                             const float2* pairs, const float* bias, bf* outb) {
    int c = (blockIdx.x * blockDim.x + threadIdx.x) >> 6;
    int lane = threadIdx.x & 63;
    if (c >= N_BIG) return;
    float d = dis[c];
    float acc = d * d * b2f(h[(size_t)c * 64 + lane]);
    int o = offs[c], n = cnt[c];
    int e = 0;
    for (; e + 8 <= n; e += 8) {
        float2 p[8];
#pragma unroll
        for (int j = 0; j < 8; j++) p[j] = pairs[o + e + j];
        float v[8];
#pragma unroll
        for (int j = 0; j < 8; j++) v[j] = b2f(h[(size_t)__float_as_int(p[j].x) * 64 + lane]);
#pragma unroll
        for (int j = 0; j < 8; j++) acc += p[j].y * v[j];
    }
    for (; e + 4 <= n; e += 4) {
        float2 p0 = pairs[o + e + 0];
        float2 p1 = pairs[o + e + 1];
        float2 p2 = pairs[o + e + 2];
        float2 p3 = pairs[o + e + 3];
        float v0 = b2f(h[(size_t)__float_as_int(p0.x) * 64 + lane]);
        float v1 = b2f(h[(size_t)__float_as_int(p1.x) * 64 + lane]);
        float v2 = b2f(h[(size_t)__float_as_int(p2.x) * 64 + lane]);
        float v3 = b2f(h[(size_t)__float_as_int(p3.x) * 64 + lane]);
        acc += p0.y * v0 + p1.y * v1 + p2.y * v2 + p3.y * v3;
    }
    for (; e < n; e++) {
        float2 p = pairs[o + e];
        acc += p.y * b2f(h[(size_t)__float_as_int(p.x) * 64 + lane]);
    }
    outb[(size_t)c * 64 + lane] = f2b(fmaxf(acc + bias[lane], 0.f));
}

// ------------------------------------------------------------ BatchNorm -----
__global__ void k_bnstats(const bf* buf, float* s_sum, float* s_sq) {
    int ch = threadIdx.x & 63, g = threadIdx.x >> 6;
    float s = 0.f, q = 0.f;
    for (int r = blockIdx.x * 4 + g; r < N_BIG; r += gridDim.x * 4) {
        float v = b2f(buf[(size_t)r * 64 + ch]);
        s += v;
        q += v * v;
    }
    unsafeAtomicAdd(&s_sum[ch], s);
    unsafeAtomicAdd(&s_sq[ch], q);
}

__global__ void k_bnapply(const bf* buf, const float* gamma, const float* beta,
                          const float* s_sum, const float* s_sq, bf* outb) {
    const float invn = 1.f / (float)N_BIG;
    int stride = gridDim.x * blockDim.x;
    for (int idx = blockIdx.x * blockDim.x + threadIdx.x; idx < N_BIG * 64; idx += stride) {
        int ch = idx & 63;
        float m = s_sum[ch] * invn;
        float var = s_sq[ch] * invn - m * m;
        outb[idx] = f2b((b2f(buf[idx]) - m) * rsqrtf(var + EPSV) * gamma[ch] + beta[ch]);
    }
}

// ------------------------------------------------- h1 @ W2 (bf16 MFMA) ------
__global__ __launch_bounds__(256) void k_h1w2(const bf* h1b, const bf* W2t, bf* outb) {
    int tid = threadIdx.x, w = tid >> 6, lane = tid & 63;
    int q = lane >> 4, l15 = lane & 15;
    size_t r0 = (size_t)blockIdx.x * 64 + w * 16;
    float4_ acc[4];
#pragma unroll
    for (int ct = 0; ct < 4; ct++) acc[ct] = (float4_){0.f, 0.f, 0.f, 0.f};
#pragma unroll
    for (int c = 0; c < 2; c++) {
        int koff = c * 32 + q * 8;
        short8 a = *(const short8*)(h1b + (r0 + l15) * 64 + koff);
#pragma unroll
        for (int ct = 0; ct < 4; ct++) {
            short8 b = *(const short8*)(W2t + (size_t)(ct * 16 + l15) * 64 + koff);
            acc[ct] = __builtin_amdgcn_mfma_f32_16x16x32_bf16(a, b, acc[ct], 0, 0, 0);
        }
    }
    size_t node0 = r0 + q * 4;
#pragma unroll
    for (int reg = 0; reg < 4; reg++)
#pragma unroll
        for (int ct = 0; ct < 4; ct++)
            outb[(node0 + reg) * 64 + ct * 16 + l15] = f2b(acc[ct][reg]);
}

// ----------------------------------------- fully fused double LSTM (MFMA) ---
__global__ __launch_bounds__(256, 1) void k_lstm_fused(
    const bf* h1b, const bf* h2b, const bf* B1f, const bf* B2f,
    const float* bc1, const float* bc2, bf* H1out, bf* H2out)
{
    __shared__ bf h1s[32][72];
    __shared__ bf h2s[32][72];
    int tid = threadIdx.x, w = tid >> 6, lane = tid & 63;
    int q = lane >> 4, l15 = lane & 15;
    int gnode0 = blockIdx.x * 32;
    short8 B1r[6][4];
    short8 B2r[4][4];
#pragma unroll
    for (int c = 0; c < 6; c++)
#pragma unroll
        for (int g = 0; g < 4; g++)
            B1r[c][g] = *(const short8*)(B1f + (size_t)(((w + 4 * g) * 6 + c) * 64 + lane) * 8);
#pragma unroll
    for (int c = 0; c < 4; c++)
#pragma unroll
        for (int g = 0; g < 4; g++)
            B2r[c][g] = *(const short8*)(B2f + (size_t)(((w + 4 * g) * 4 + c) * 64 + lane) * 8);
    float c1[2][4] = {}, c2[2][4] = {};
    float bv1[4], bv2[4];
#pragma unroll
    for (int g = 0; g < 4; g++) {
        bv1[g] = bc1[(w + 4 * g) * 16 + l15];
        bv2[g] = bc2[(w + 4 * g) * 16 + l15];
    }
    for (int t = 0; t < WINDOW; t++) {
        const size_t toff = (size_t)t * N_NODES * 64;
        float4_ acc[2][4];
#pragma unroll
        for (int m = 0; m < 2; m++)
#pragma unroll
            for (int g = 0; g < 4; g++) acc[m][g] = (float4_){bv1[g], bv1[g], bv1[g], bv1[g]};
#pragma unroll
        for (int c = 0; c < 4; c++) {
            const bf* sp = (c < 2) ? h1b + toff : h2b + toff;
            int koff = (c & 1) * 32 + q * 8;
#pragma unroll
            for (int m = 0; m < 2; m++) {
                short8 a = *(const short8*)(sp + (size_t)(gnode0 + m * 16 + l15) * 64 + koff);
#pragma unroll
                for (int g = 0; g < 4; g++)
                    acc[m][g] = __builtin_amdgcn_mfma_f32_16x16x32_bf16(a, B1r[c][g], acc[m][g], 0, 0, 0);
            }
        }
        if (t > 0) {
#pragma unroll
            for (int c = 4; c < 6; c++) {
                int koff = (c & 1) * 32 + q * 8;
#pragma unroll
                for (int m = 0; m < 2; m++) {
                    short8 a = *(const short8*)&h1s[m * 16 + l15][koff];
#pragma unroll
                    for (int g = 0; g < 4; g++)
                        acc[m][g] = __builtin_amdgcn_mfma_f32_16x16x32_bf16(a, B1r[c][g], acc[m][g], 0, 0, 0);
                }
            }
        }
        __syncthreads();
#pragma unroll
        for (int m = 0; m < 2; m++)
#pragma unroll
            for (int reg = 0; reg < 4; reg++) {
                float gi = acc[m][0][reg], gf = acc[m][1][reg];
                float gg = acc[m][2][reg], go = acc[m][3][reg];
                float co = (t == 0) ? 0.f : c1[m][reg];
                float cn = sigf(gf) * co + sigf(gi) * tanhfast(gg);
                float hn = sigf(go) * tanhfast(cn);
                c1[m][reg] = cn;
                int nl = m * 16 + q * 4 + reg;
                h1s[nl][w * 16 + l15] = f2b(hn);
                if (t == WINDOW - 1)
                    H1out[(size_t)(gnode0 + nl) * 64 + w * 16 + l15] = f2b(hn);
            }
        __syncthreads();
#pragma unroll
        for (int m = 0; m < 2; m++)
#pragma unroll
            for (int g = 0; g < 4; g++) acc[m][g] = (float4_){bv2[g], bv2[g], bv2[g], bv2[g]};
#pragma unroll
        for (int c = 0; c < 2; c++) {
            int koff = (c & 1) * 32 + q * 8;
#pragma unroll
            for (int m = 0; m < 2; m++) {
                short8 a = *(const short8*)&h1s[m * 16 + l15][koff];
#pragma unroll
                for (int g = 0; g < 4; g++)
                    acc[m][g] = __builtin_amdgcn_mfma_f32_16x16x32_bf16(a, B2r[c][g], acc[m][g], 0, 0, 0);
            }
        }
        if (t > 0) {
#pragma unroll
            for (int c = 2; c < 4; c++) {
                int koff = (c & 1) * 32 + q * 8;
#pragma unroll
                for (int m = 0; m < 2; m++) {
                    short8 a = *(const short8*)&h2s[m * 16 + l15][koff];
#pragma unroll
                    for (int g = 0; g < 4; g++)
                        acc[m][g] = __builtin_amdgcn_mfma_f32_16x16x32_bf16(a, B2r[c][g], acc[m][g], 0, 0, 0);
                }
            }
        }
        __syncthreads();
#pragma unroll
        for (int m = 0; m < 2; m++)
#pragma unroll
            for (int reg = 0; reg < 4; reg++) {
                float gi = acc[m][0][reg], gf = acc[m][1][reg];
                float gg = acc[m][2][reg], go = acc[m][3][reg];
                float co = (t == 0) ? 0.f : c2[m][reg];
                float cn = sigf(gf) * co + sigf(gi) * tanhfast(gg);
                float hn = sigf(go) * tanhfast(cn);
                c2[m][reg] = cn;
                int nl = m * 16 + q * 4 + reg;
                h2s[nl][w * 16 + l15] = f2b(hn);
                if (t == WINDOW - 1)
                    H2out[(size_t)(gnode0 + nl) * 64 + w * 16 + l15] = f2b(hn);
            }
        __syncthreads();
    }
}

// ----------------------------------------------------------- small utils ----
// neb[20032][160] bf16, K-padded (cols 143..159 zero); rows >=20000 unwritten
__global__ void k_nodeemb(const bf* H1, const bf* H2, const float* x, bf* neb) {
    int stride = gridDim.x * blockDim.x;
    for (int idx = blockIdx.x * blockDim.x + threadIdx.x; idx < N_NODES * 160; idx += stride) {
        int n = idx / 160, j = idx % 160;
        float v;
        if (j < 64) v = b2f(H1[(size_t)n * 64 + j]);
        else if (j < 128) v = b2f(H2[(size_t)n * 64 + (j - 64)]);
        else if (j < DHV) {
            int s = j - 128;
            v = (s < 8) ? x[n * IN_C + s] : x[(size_t)((s - 7) * N_NODES + n) * IN_C + 7];
        } else v = 0.f;
        neb[idx] = f2b(v);
    }
}

// PQ = neb @ Bpq  (bf16 MFMA, M=20032, N=288, K=160) -> PQb bf16 [20000][288]
__global__ __launch_bounds__(256) void k_pq(const bf* neb, const bf* Bpqf, bf* PQb) {
    int tid = threadIdx.x, w = tid >> 6, lane = tid & 63;
    int q = lane >> 4, l15 = lane & 15;
    int r0 = blockIdx.x * 64 + w * 16;
    float4_ acc[18];
#pragma unroll
    for (int ct = 0; ct < 18; ct++) acc[ct] = (float4_){0.f, 0.f, 0.f, 0.f};
#pragma unroll
    for (int c = 0; c < 5; c++) {
        short8 a = *(const short8*)(neb + (size_t)(r0 + l15) * 160 + c * 32 + q * 8);
#pragma unroll
        for (int ct = 0; ct < 18; ct++) {
            short8 b = *(const short8*)(Bpqf + (size_t)((ct * 5 + c) * 64 + lane) * 8);
            acc[ct] = __builtin_amdgcn_mfma_f32_16x16x32_bf16(a, b, acc[ct], 0, 0, 0);
        }
    }
#pragma unroll
    for (int reg = 0; reg < 4; reg++) {
        int node = r0 + q * 4 + reg;
        if (node < N_NODES)
#pragma unroll
            for (int ct = 0; ct < 18; ct++)
                PQb[(size_t)node * 288 + ct * 16 + l15] = f2b(acc[ct][reg]);
    }
}

// decoder: out[e] = relu(P[src]+Q[trg]+ba) . dWb + bb ; one wave per edge
__global__ void k_edge(const int* ewi, const bf* PQb, const float* dba,
                       const float* dWb, const float* dbb, float* out) {
    int wid = (blockIdx.x * blockDim.x + threadIdx.x) >> 6;
    int lane = threadIdx.x & 63;
    if (wid >= E_DEC) return;
    int src = ewi[wid], trg = ewi[E_DEC + wid];
    const bf* Pr = PQb + (size_t)src * 288;
    const bf* Qr = PQb + (size_t)trg * 288 + 144;
    float acc = 0.f;
    for (int u = lane; u < DHV; u += 64) {
        float v = b2f(Pr[u]) + b2f(Qr[u]) + dba[u];
        v = fmaxf(v, 0.f);
        acc += v * dWb[u];
    }
#pragma unroll
    for (int off = 32; off > 0; off >>= 1) acc += __shfl_down(acc, off);
    if (lane == 0) out[wid] = acc + dbb[0];
}

// ---------------------------------------------------------------------------
extern "C" void kernel_launch(void* const* d_in, const int* in_sizes, int n_in,
                              void* d_out, int out_size, void* d_ws, size_t ws_size,
                              hipStream_t stream) {
    (void)in_sizes; (void)n_in; (void)out_size; (void)ws_size;
    const float* x    = (const float*)d_in[0];
    const float* ea   = (const float*)d_in[1];
    const int*   ei   = (const int*)d_in[2];
    const int*   ewi  = (const int*)d_in[3];
    const float* W1   = (const float*)d_in[4];
    const float* b1   = (const float*)d_in[5];
    const float* g1   = (const float*)d_in[6];
    const float* be1  = (const float*)d_in[7];
    const float* W2   = (const float*)d_in[8];
    const float* b2   = (const float*)d_in[9];
    const float* g2   = (const float*)d_in[10];
    const float* be2  = (const float*)d_in[11];
    const float* Wih1 = (const float*)d_in[12];
    const float* Whh1 = (const float*)d_in[13];
    const float* bih1 = (const float*)d_in[14];
    const float* bhh1 = (const float*)d_in[15];
    const float* Wih2 = (const float*)d_in[16];
    const float* Whh2 = (const float*)d_in[17];
    const float* bih2 = (const float*)d_in[18];
    const float* bhh2 = (const float*)d_in[19];
    const float* dWa  = (const float*)d_in[20];
    const float* dba  = (const float*)d_in[21];
    const float* dWb  = (const float*)d_in[22];
    const float* dbb  = (const float*)d_in[23];
    float* out = (float*)d_out;

    const size_t NSB = (size_t)N_BIG * 64;   // 10.24M
    const size_t NS  = (size_t)N_NODES * 64; // 1.28M
    char* base = (char*)d_ws;
    size_t o = 0;
    float* dis  = (float*)(base + o); o += (size_t)N_BIG * 4;      // 0.64 MB
    ull* deg64  = (ull*)(base + o);   o += (size_t)N_BIG * 8;      // 1.28 MB
    bf* aggb    = (bf*)(base + o);    o += NSB * 2;                // 20.5 MB (gather out; neb/PQb later)
    bf* hbufb   = (bf*)(base + o);    o += NSB * 2;                // 20.5 MB
    bf* h1b     = (bf*)(base + o);    o += NSB * 2;
    bf* h2b     = (bf*)(base + o);    o += NSB * 2;
    bf* hs1     = (bf*)(base + o);    o += NS * 2;
    bf* hs2     = (bf*)(base + o);    o += NS * 2;
    bf* B1f     = (bf*)(base + o);    o += (size_t)16 * 6 * 64 * 8 * 2;   // 96 KB
    bf* B2f     = (bf*)(base + o);    o += (size_t)16 * 4 * 64 * 8 * 2;   // 64 KB
    bf* W2t     = (bf*)(base + o);    o += 64 * 64 * 2;
    float* bc1  = (float*)(base + o); o += 256 * 4;
    float* bc2  = (float*)(base + o); o += 256 * 4;
    bf* Bpqf    = (bf*)(base + o);    o += (size_t)18 * 5 * 64 * 8 * 2;   // 92 KB
    float* stats= (float*)(base + o); o += 256 * 4;
    float2* pairs = (float2*)(base + o); o += (size_t)NE * 8;      // 12.8 MB
    int* offs = (int*)(base + o); o += (size_t)N_BIG * 4;
    int* cnt  = (int*)(base + o); o += (size_t)N_BIG * 4;
    int* cur  = (int*)(base + o); o += (size_t)N_BIG * 4;
    int* part = (int*)(base + o); o += 256 * 4;
    // temporal aliases on aggb (dead after bnapply layer 2):
    bf* neb = aggb;                          // 20032 x 160 bf16 = 6.41 MB
    bf* PQb = aggb + (size_t)20032 * 160;    // 20000 x 288 bf16 = 11.5 MB (17.9 < 20.5 OK)

    // ---- prep + CSR build ----
    k_prep<<<512, 256, 0, stream>>>(Wih1, Whh1, bih1, bhh1, Wih2, Whh2, bih2, bhh2,
                                    dWa, W2, deg64, B1f, B2f, W2t, bc1, bc2, Bpqf, stats);
    k_deg_count<<<(NE + 255) / 256, 256, 0, stream>>>(ei, ea, deg64);
    k_dis<<<(N_BIG + 255) / 256, 256, 0, stream>>>(deg64, dis, cnt);
    k_scan1<<<157, 256, 0, stream>>>(cnt, offs, part);
    k_scan2<<<1, 256, 0, stream>>>(part, 157);
    k_scan3<<<157, 256, 0, stream>>>(offs, cur, part);
    k_fill<<<(NE + 255) / 256, 256, 0, stream>>>(ei, ea, dis, cur, pairs);

    // ---- GCN layer 1 ----
    k_xw1<<<N_BIG / 4, 256, 0, stream>>>(x, W1, hbufb);
    k_gcn_gather<<<N_BIG / 4, 256, 0, stream>>>(hbufb, dis, offs, cnt, pairs, b1, aggb);
    k_bnstats<<<256, 256, 0, stream>>>(aggb, stats, stats + 64);
    k_bnapply<<<4096, 256, 0, stream>>>(aggb, g1, be1, stats, stats + 64, h1b);

    // ---- GCN layer 2 ----
    k_h1w2<<<2500, 256, 0, stream>>>(h1b, W2t, hbufb);
    k_gcn_gather<<<N_BIG / 4, 256, 0, stream>>>(hbufb, dis, offs, cnt, pairs, b2, aggb);
    k_bnstats<<<256, 256, 0, stream>>>(aggb, stats + 128, stats + 192);
    k_bnapply<<<4096, 256, 0, stream>>>(aggb, g2, be2, stats + 128, stats + 192, h2b);

    // ---- both LSTMs, all 8 steps, one launch ----
    k_lstm_fused<<<625, 256, 0, stream>>>(h1b, h2b, B1f, B2f, bc1, bc2, hs1, hs2);

    // ---- node embeddings + decoder ----
    k_nodeemb<<<12500, 256, 0, stream>>>(hs1, hs2, x, neb);
    k_pq<<<313, 256, 0, stream>>>(neb, Bpqf, PQb);
    k_edge<<<E_DEC / 4, 256, 0, stream>>>(ewi, PQb, dba, dWb, dbb, out);
}

// Round 10
// 735.757 us; speedup vs baseline: 2.6143x; 1.1280x over previous
//
#include <hip/hip_runtime.h>
#include <hip/hip_bf16.h>

#define IN_C 8
#define HID 64
#define N_NODES 20000
#define WINDOW 8
#define N_BIG 160000
#define NE 1600000
#define E_DEC 500000
#define DHV 143
#define EPSV 1e-5f

typedef __hip_bfloat16 bf;
typedef unsigned long long ull;
typedef __attribute__((ext_vector_type(8))) short short8;
typedef __attribute__((ext_vector_type(4))) float float4_;

__device__ __forceinline__ float b2f(bf v) { return __bfloat162float(v); }
__device__ __forceinline__ bf f2b(float v) { return __float2bfloat16(v); }
// bf16 pair decode from packed u32 (little-endian: elem0 = low 16 bits)
__device__ __forceinline__ float bflo(unsigned int u) { return __uint_as_float(u << 16); }
__device__ __forceinline__ float bfhi(unsigned int u) { return __uint_as_float(u & 0xffff0000u); }
// pack two floats -> two bf16 in one u32 (elem0 low, elem1 high)
__device__ __forceinline__ unsigned int packbf2(float lo, float hi) {
    unsigned int ul = __bfloat16_as_ushort(f2b(lo));
    unsigned int uh = __bfloat16_as_ushort(f2b(hi));
    return ul | (uh << 16);
}
__device__ __forceinline__ float sigf(float x) {
    return __builtin_amdgcn_rcpf(1.f + __expf(-x));
}
__device__ __forceinline__ float tanhfast(float x) {
    x = fminf(fmaxf(x, -15.f), 15.f);
    float e = __expf(2.f * x);
    return (e - 1.f) * __builtin_amdgcn_rcpf(e + 1.f);
}

// ---------------------------------------------------------------- prep ------
__global__ void k_prep(const float* Wih1, const float* Whh1, const float* bih1, const float* bhh1,
                       const float* Wih2, const float* Whh2, const float* bih2, const float* bhh2,
                       const float* dWa,  const float* W2,
                       ull* deg64, bf* B1f, bf* B2f, bf* W2t,
                       float* bc1, float* bc2, bf* Bpqf, float* stats)
{
    int i0 = blockIdx.x * blockDim.x + threadIdx.x;
    int stride = gridDim.x * blockDim.x;
    for (int i = i0; i < N_BIG; i += stride) deg64[i] = 0ull;
    for (int i = i0; i < 16 * 6 * 64 * 8; i += stride) {   // B1 fragments (K=192)
        int j = i & 7, lane = (i >> 3) & 63, r = i >> 9;
        int c = r % 6, ct = r / 6;
        int q = lane >> 4, l15 = lane & 15;
        int n = ct * 16 + l15, k = c * 32 + q * 8 + j;
        B1f[i] = f2b((k < 128) ? Wih1[n * 128 + k] : Whh1[n * 64 + (k - 128)]);
    }
    for (int i = i0; i < 16 * 4 * 64 * 8; i += stride) {   // B2 fragments (K=128)
        int j = i & 7, lane = (i >> 3) & 63, r = i >> 9;
        int c = r & 3, ct = r >> 2;
        int q = lane >> 4, l15 = lane & 15;
        int n = ct * 16 + l15, k = c * 32 + q * 8 + j;
        B2f[i] = f2b((k < 64) ? Wih2[n * 64 + k] : Whh2[n * 64 + (k - 64)]);
    }
    for (int i = i0; i < 64 * 64; i += stride) {          // W2^T [n][k]
        int n = i >> 6, k = i & 63;
        W2t[i] = f2b(W2[k * 64 + n]);
    }
    for (int i = i0; i < 256; i += stride) {
        bc1[i] = bih1[i] + bhh1[i];
        bc2[i] = bih2[i] + bhh2[i];
    }
    // decoder weight fragments: N=288 (18 tiles), K=160 (5 chunks; k<143 real)
    for (int i = i0; i < 18 * 5 * 64 * 8; i += stride) {
        int j = i & 7, lane = (i >> 3) & 63, r = i >> 9;
        int c = r % 5, ct = r / 5;
        int q = lane >> 4, l15 = lane & 15;
        int n = ct * 16 + l15, k = c * 32 + q * 8 + j;
        float v = 0.f;
        if (k < DHV) {
            if (n < DHV) v = dWa[k * DHV + n];
            else if (n >= 144 && n < 144 + DHV) v = dWa[(DHV + k) * DHV + (n - 144)];
        }
        Bpqf[i] = f2b(v);
    }
    for (int i = i0; i < 256; i += stride) stats[i] = 0.f;
}

// ---------------------------------- degree + edge count (one packed atomic) --
__global__ void k_deg_count(const int* ei, const float* ea, ull* deg64) {
    int e = blockIdx.x * blockDim.x + threadIdx.x;
    if (e >= NE) return;
    int c = ei[NE + e];
    unsigned int q = (unsigned int)(ea[e] * 16777216.f + 0.5f);
    atomicAdd(&deg64[c], (1ull << 40) | (ull)q);
}

__global__ void k_dis(const ull* deg64, float* dis, int* cnt) {
    int i = blockIdx.x * blockDim.x + threadIdx.x;
    if (i < N_BIG) {
        ull v = deg64[i];
        cnt[i] = (int)(v >> 40);
        float deg = 1.f + (float)(v & 0xFFFFFFFFFFull) * (1.f / 16777216.f);
        dis[i] = rsqrtf(fmaxf(deg, EPSV));
    }
}

// ----------------------------------------------- exclusive scan (3-phase) ---
__global__ __launch_bounds__(256) void k_scan1(const int* cnt, int* offs, int* part) {
    __shared__ int s[256];
    int tid = threadIdx.x;
    int base = blockIdx.x * 1024 + tid * 4;
    int c[4];
    int sum = 0;
#pragma unroll
    for (int j = 0; j < 4; j++) {
        c[j] = (base + j < N_BIG) ? cnt[base + j] : 0;
        sum += c[j];
    }
    s[tid] = sum;
    __syncthreads();
    for (int off = 1; off < 256; off <<= 1) {
        int v = (tid >= off) ? s[tid - off] : 0;
        __syncthreads();
        s[tid] += v;
        __syncthreads();
    }
    int run = s[tid] - sum;
#pragma unroll
    for (int j = 0; j < 4; j++) {
        if (base + j < N_BIG) offs[base + j] = run;
        run += c[j];
    }
    if (tid == 255) part[blockIdx.x] = s[255];
}

__global__ __launch_bounds__(256) void k_scan2(int* part, int np) {
    __shared__ int s[256];
    int tid = threadIdx.x;
    int v = (tid < np) ? part[tid] : 0;
    s[tid] = v;
    __syncthreads();
    for (int off = 1; off < 256; off <<= 1) {
        int w = (tid >= off) ? s[tid - off] : 0;
        __syncthreads();
        s[tid] += w;
        __syncthreads();
    }
    if (tid < np) part[tid] = s[tid] - v;
}

__global__ __launch_bounds__(256) void k_scan3(int* offs, int* cur, const int* part) {
    int add = part[blockIdx.x];
    int base = blockIdx.x * 1024 + threadIdx.x * 4;
#pragma unroll
    for (int j = 0; j < 4; j++) {
        if (base + j < N_BIG) {
            int v = offs[base + j] + add;
            offs[base + j] = v;
            cur[base + j] = v;
        }
    }
}

// ------------------------------------------------------------ CSR fill ------
__global__ void k_fill(const int* ei, const float* ea, const float* dis, int* cur, float2* pairs) {
    int e = blockIdx.x * blockDim.x + threadIdx.x;
    if (e >= NE) return;
    int r = ei[e], c = ei[NE + e];
    float norm = dis[r] * ea[e] * dis[c];
    int p = atomicAdd(&cur[c], 1);
    pairs[p] = make_float2(__int_as_float(r), norm);
}

// ------------------------------------------------------------ x @ W1 --------
__global__ __launch_bounds__(256) void k_xw1(const float* x, const float* W1, bf* hbufb) {
    __shared__ float Ws[IN_C * HID];
    __shared__ float xs[4][IN_C];
    int tid = threadIdx.x;
    Ws[tid] = W1[tid];
    Ws[tid + 256] = W1[tid + 256];
    int node0 = blockIdx.x * 4;
    if (tid < 32) xs[tid >> 3][tid & 7] = x[node0 * IN_C + tid];
    __syncthreads();
    int ch = tid & 63, ns = tid >> 6;
    float acc = 0.f;
#pragma unroll
    for (int c = 0; c < IN_C; c++) acc += xs[ns][c] * Ws[c * 64 + ch];
    hbufb[(size_t)(node0 + ns) * 64 + ch] = f2b(acc);
}

// ------------------------------------------- GCN aggregation (CSR gather) ---
// 2 nodes per wave (32 lanes/node, 2 channels/lane via packed u32 decode);
// 8-wide edge unroll -> up to 16 rows in flight per wave.
__global__ void k_gcn_gather(const bf* h, const float* dis, const int* offs, const int* cnt,
                             const float2* pairs, const float* bias, bf* outb) {
    int wv = (blockIdx.x * blockDim.x + threadIdx.x) >> 6;
    int half = (threadIdx.x >> 5) & 1, l = threadIdx.x & 31;
    int c = wv * 2 + half;
    if (c >= N_BIG) return;
    float d = dis[c];
    unsigned int hv = *(const unsigned int*)(h + (size_t)c * 64 + 2 * l);
    float dd = d * d;
    float ax = dd * bflo(hv), ay = dd * bfhi(hv);
    int o = offs[c], n = cnt[c];
    int e = 0;
    for (; e + 8 <= n; e += 8) {
        float2 p[8];
#pragma unroll
        for (int j = 0; j < 8; j++) p[j] = pairs[o + e + j];
        unsigned int v[8];
#pragma unroll
        for (int j = 0; j < 8; j++)
            v[j] = *(const unsigned int*)(h + (size_t)__float_as_int(p[j].x) * 64 + 2 * l);
#pragma unroll
        for (int j = 0; j < 8; j++) { ax += p[j].y * bflo(v[j]); ay += p[j].y * bfhi(v[j]); }
    }
    for (; e + 4 <= n; e += 4) {
        float2 p[4];
#pragma unroll
        for (int j = 0; j < 4; j++) p[j] = pairs[o + e + j];
        unsigned int v[4];
#pragma unroll
        for (int j = 0; j < 4; j++)
            v[j] = *(const unsigned int*)(h + (size_t)__float_as_int(p[j].x) * 64 + 2 * l);
#pragma unroll
        for (int j = 0; j < 4; j++) { ax += p[j].y * bflo(v[j]); ay += p[j].y * bfhi(v[j]); }
    }
    for (; e < n; e++) {
        float2 p = pairs[o + e];
        unsigned int v = *(const unsigned int*)(h + (size_t)__float_as_int(p.x) * 64 + 2 * l);
        ax += p.y * bflo(v);
        ay += p.y * bfhi(v);
    }
    float2 bv = *(const float2*)(bias + 2 * l);
    unsigned int st = packbf2(fmaxf(ax + bv.x, 0.f), fmaxf(ay + bv.y, 0.f));
    *(unsigned int*)(outb + (size_t)c * 64 + 2 * l) = st;
}

// ------------------------------------------------------------ BatchNorm -----
__global__ void k_bnstats(const bf* buf, float* s_sum, float* s_sq) {
    int ch = threadIdx.x & 63, g = threadIdx.x >> 6;
    float s = 0.f, q = 0.f;
    for (int r = blockIdx.x * 4 + g; r < N_BIG; r += gridDim.x * 4) {
        float v = b2f(buf[(size_t)r * 64 + ch]);
        s += v;
        q += v * v;
    }
    unsafeAtomicAdd(&s_sum[ch], s);
    unsafeAtomicAdd(&s_sq[ch], q);
}

__global__ void k_bnapply(const bf* buf, const float* gamma, const float* beta,
                          const float* s_sum, const float* s_sq, bf* outb) {
    const float invn = 1.f / (float)N_BIG;
    int stride = gridDim.x * blockDim.x;
    for (int idx = blockIdx.x * blockDim.x + threadIdx.x; idx < N_BIG * 64; idx += stride) {
        int ch = idx & 63;
        float m = s_sum[ch] * invn;
        float var = s_sq[ch] * invn - m * m;
        outb[idx] = f2b((b2f(buf[idx]) - m) * rsqrtf(var + EPSV) * gamma[ch] + beta[ch]);
    }
}

// ------------------------------------------------- h1 @ W2 (bf16 MFMA) ------
__global__ __launch_bounds__(256) void k_h1w2(const bf* h1b, const bf* W2t, bf* outb) {
    int tid = threadIdx.x, w = tid >> 6, lane = tid & 63;
    int q = lane >> 4, l15 = lane & 15;
    size_t r0 = (size_t)blockIdx.x * 64 + w * 16;
    float4_ acc[4];
#pragma unroll
    for (int ct = 0; ct < 4; ct++) acc[ct] = (float4_){0.f, 0.f, 0.f, 0.f};
#pragma unroll
    for (int c = 0; c < 2; c++) {
        int koff = c * 32 + q * 8;
        short8 a = *(const short8*)(h1b + (r0 + l15) * 64 + koff);
#pragma unroll
        for (int ct = 0; ct < 4; ct++) {
            short8 b = *(const short8*)(W2t + (size_t)(ct * 16 + l15) * 64 + koff);
            acc[ct] = __builtin_amdgcn_mfma_f32_16x16x32_bf16(a, b, acc[ct], 0, 0, 0);
        }
    }
    size_t node0 = r0 + q * 4;
#pragma unroll
    for (int reg = 0; reg < 4; reg++)
#pragma unroll
        for (int ct = 0; ct < 4; ct++)
            outb[(node0 + reg) * 64 + ct * 16 + l15] = f2b(acc[ct][reg]);
}

// ----------------------------------------- fully fused double LSTM (MFMA) ---
__global__ __launch_bounds__(256, 1) void k_lstm_fused(
    const bf* h1b, const bf* h2b, const bf* B1f, const bf* B2f,
    const float* bc1, const float* bc2, bf* H1out, bf* H2out)
{
    __shared__ bf h1s[32][72];
    __shared__ bf h2s[32][72];
    int tid = threadIdx.x, w = tid >> 6, lane = tid & 63;
    int q = lane >> 4, l15 = lane & 15;
    int gnode0 = blockIdx.x * 32;
    short8 B1r[6][4];
    short8 B2r[4][4];
#pragma unroll
    for (int c = 0; c < 6; c++)
#pragma unroll
        for (int g = 0; g < 4; g++)
            B1r[c][g] = *(const short8*)(B1f + (size_t)(((w + 4 * g) * 6 + c) * 64 + lane) * 8);
#pragma unroll
    for (int c = 0; c < 4; c++)
#pragma unroll
        for (int g = 0; g < 4; g++)
            B2r[c][g] = *(const short8*)(B2f + (size_t)(((w + 4 * g) * 4 + c) * 64 + lane) * 8);
    float c1[2][4] = {}, c2[2][4] = {};
    float bv1[4], bv2[4];
#pragma unroll
    for (int g = 0; g < 4; g++) {
        bv1[g] = bc1[(w + 4 * g) * 16 + l15];
        bv2[g] = bc2[(w + 4 * g) * 16 + l15];
    }
    for (int t = 0; t < WINDOW; t++) {
        const size_t toff = (size_t)t * N_NODES * 64;
        float4_ acc[2][4];
#pragma unroll
        for (int m = 0; m < 2; m++)
#pragma unroll
            for (int g = 0; g < 4; g++) acc[m][g] = (float4_){bv1[g], bv1[g], bv1[g], bv1[g]};
#pragma unroll
        for (int c = 0; c < 4; c++) {
            const bf* sp = (c < 2) ? h1b + toff : h2b + toff;
            int koff = (c & 1) * 32 + q * 8;
#pragma unroll
            for (int m = 0; m < 2; m++) {
                short8 a = *(const short8*)(sp + (size_t)(gnode0 + m * 16 + l15) * 64 + koff);
#pragma unroll
                for (int g = 0; g < 4; g++)
                    acc[m][g] = __builtin_amdgcn_mfma_f32_16x16x32_bf16(a, B1r[c][g], acc[m][g], 0, 0, 0);
            }
        }
        if (t > 0) {
#pragma unroll
            for (int c = 4; c < 6; c++) {
                int koff = (c & 1) * 32 + q * 8;
#pragma unroll
                for (int m = 0; m < 2; m++) {
                    short8 a = *(const short8*)&h1s[m * 16 + l15][koff];
#pragma unroll
                    for (int g = 0; g < 4; g++)
                        acc[m][g] = __builtin_amdgcn_mfma_f32_16x16x32_bf16(a, B1r[c][g], acc[m][g], 0, 0, 0);
                }
            }
        }
        __syncthreads();
#pragma unroll
        for (int m = 0; m < 2; m++)
#pragma unroll
            for (int reg = 0; reg < 4; reg++) {
                float gi = acc[m][0][reg], gf = acc[m][1][reg];
                float gg = acc[m][2][reg], go = acc[m][3][reg];
                float co = (t == 0) ? 0.f : c1[m][reg];
                float cn = sigf(gf) * co + sigf(gi) * tanhfast(gg);
                float hn = sigf(go) * tanhfast(cn);
                c1[m][reg] = cn;
                int nl = m * 16 + q * 4 + reg;
                h1s[nl][w * 16 + l15] = f2b(hn);
                if (t == WINDOW - 1)
                    H1out[(size_t)(gnode0 + nl) * 64 + w * 16 + l15] = f2b(hn);
            }
        __syncthreads();
#pragma unroll
        for (int m = 0; m < 2; m++)
#pragma unroll
            for (int g = 0; g < 4; g++) acc[m][g] = (float4_){bv2[g], bv2[g], bv2[g], bv2[g]};
#pragma unroll
        for (int c = 0; c < 2; c++) {
            int koff = (c & 1) * 32 + q * 8;
#pragma unroll
            for (int m = 0; m < 2; m++) {
                short8 a = *(const short8*)&h1s[m * 16 + l15][koff];
#pragma unroll
                for (int g = 0; g < 4; g++)
                    acc[m][g] = __builtin_amdgcn_mfma_f32_16x16x32_bf16(a, B2r[c][g], acc[m][g], 0, 0, 0);
            }
        }
        if (t > 0) {
#pragma unroll
            for (int c = 2; c < 4; c++) {
                int koff = (c & 1) * 32 + q * 8;
#pragma unroll
                for (int m = 0; m < 2; m++) {
                    short8 a = *(const short8*)&h2s[m * 16 + l15][koff];
#pragma unroll
                    for (int g = 0; g < 4; g++)
                        acc[m][g] = __builtin_amdgcn_mfma_f32_16x16x32_bf16(a, B2r[c][g], acc[m][g], 0, 0, 0);
                }
            }
        }
        __syncthreads();
#pragma unroll
        for (int m = 0; m < 2; m++)
#pragma unroll
            for (int reg = 0; reg < 4; reg++) {
                float gi = acc[m][0][reg], gf = acc[m][1][reg];
                float gg = acc[m][2][reg], go = acc[m][3][reg];
                float co = (t == 0) ? 0.f : c2[m][reg];
                float cn = sigf(gf) * co + sigf(gi) * tanhfast(gg);
                float hn = sigf(go) * tanhfast(cn);
                c2[m][reg] = cn;
                int nl = m * 16 + q * 4 + reg;
                h2s[nl][w * 16 + l15] = f2b(hn);
                if (t == WINDOW - 1)
                    H2out[(size_t)(gnode0 + nl) * 64 + w * 16 + l15] = f2b(hn);
            }
        __syncthreads();
    }
}

// ----------------------------------------------------------- small utils ----
__global__ void k_nodeemb(const bf* H1, const bf* H2, const float* x, bf* neb) {
    int stride = gridDim.x * blockDim.x;
    for (int idx = blockIdx.x * blockDim.x + threadIdx.x; idx < N_NODES * 160; idx += stride) {
        int n = idx / 160, j = idx % 160;
        float v;
        if (j < 64) v = b2f(H1[(size_t)n * 64 + j]);
        else if (j < 128) v = b2f(H2[(size_t)n * 64 + (j - 64)]);
        else if (j < DHV) {
            int s = j - 128;
            v = (s < 8) ? x[n * IN_C + s] : x[(size_t)((s - 7) * N_NODES + n) * IN_C + 7];
        } else v = 0.f;
        neb[idx] = f2b(v);
    }
}

// PQ = neb @ Bpq (bf16 MFMA, M=20032, N=288, K=160); dba folded into P block
__global__ __launch_bounds__(256) void k_pq(const bf* neb, const bf* Bpqf, const float* dba, bf* PQb) {
    int tid = threadIdx.x, w = tid >> 6, lane = tid & 63;
    int q = lane >> 4, l15 = lane & 15;
    int r0 = blockIdx.x * 64 + w * 16;
    float4_ acc[18];
#pragma unroll
    for (int ct = 0; ct < 18; ct++) acc[ct] = (float4_){0.f, 0.f, 0.f, 0.f};
#pragma unroll
    for (int c = 0; c < 5; c++) {
        short8 a = *(const short8*)(neb + (size_t)(r0 + l15) * 160 + c * 32 + q * 8);
#pragma unroll
        for (int ct = 0; ct < 18; ct++) {
            short8 b = *(const short8*)(Bpqf + (size_t)((ct * 5 + c) * 64 + lane) * 8);
            acc[ct] = __builtin_amdgcn_mfma_f32_16x16x32_bf16(a, b, acc[ct], 0, 0, 0);
        }
    }
#pragma unroll
    for (int reg = 0; reg < 4; reg++) {
        int node = r0 + q * 4 + reg;
        if (node < N_NODES)
#pragma unroll
            for (int ct = 0; ct < 18; ct++) {
                int col = ct * 16 + l15;
                float add = (ct < 9 && col < DHV) ? dba[col] : 0.f;   // fold bias into P
                PQb[(size_t)node * 288 + col] = f2b(acc[ct][reg] + add);
            }
    }
}

// decoder: 2 edges/wave, 32 lanes/edge, 8B loads; P' already has +dba
__global__ __launch_bounds__(256) void k_edge(const int* ewi, const bf* PQb,
                                              const float* dWb, const float* dbb, float* out) {
    int wv = (blockIdx.x * blockDim.x + threadIdx.x) >> 6;
    int half = (threadIdx.x >> 5) & 1, l = threadIdx.x & 31;
    int e = wv * 2 + half;
    if (e >= E_DEC) return;
    int src = ewi[e], trg = ewi[E_DEC + e];
    const bf* Pr = PQb + (size_t)src * 288;
    const bf* Qr = PQb + (size_t)trg * 288 + 144;
    float acc;
    {   // main: elements 4l..4l+3 (covers 0..127)
        uint2 pv = *(const uint2*)(Pr + 4 * l);
        uint2 qv = *(const uint2*)(Qr + 4 * l);
        float4 wv4 = *(const float4*)(dWb + 4 * l);
        float s0 = fmaxf(bflo(pv.x) + bflo(qv.x), 0.f);
        float s1 = fmaxf(bfhi(pv.x) + bfhi(qv.x), 0.f);
        float s2 = fmaxf(bflo(pv.y) + bflo(qv.y), 0.f);
        float s3 = fmaxf(bfhi(pv.y) + bfhi(qv.y), 0.f);
        acc = s0 * wv4.x + s1 * wv4.y + s2 * wv4.z + s3 * wv4.w;
    }
    if (l < 4) {   // remainder: elements 128..143 (element 143 is zero-pad)
        int u0 = 128 + 4 * l;
        uint2 pv = *(const uint2*)(Pr + u0);
        uint2 qv = *(const uint2*)(Qr + u0);
        float w0 = dWb[u0], w1 = dWb[u0 + 1], w2 = dWb[u0 + 2];
        float w3 = (u0 + 3 < DHV) ? dWb[u0 + 3] : 0.f;
        acc += fmaxf(bflo(pv.x) + bflo(qv.x), 0.f) * w0;
        acc += fmaxf(bfhi(pv.x) + bfhi(qv.x), 0.f) * w1;
        acc += fmaxf(bflo(pv.y) + bflo(qv.y), 0.f) * w2;
        acc += fmaxf(bfhi(pv.y) + bfhi(qv.y), 0.f) * w3;
    }
#pragma unroll
    for (int off = 16; off > 0; off >>= 1) acc += __shfl_xor(acc, off);
    if (l == 0) out[e] = acc + dbb[0];
}

// ---------------------------------------------------------------------------
extern "C" void kernel_launch(void* const* d_in, const int* in_sizes, int n_in,
                              void* d_out, int out_size, void* d_ws, size_t ws_size,
                              hipStream_t stream) {
    (void)in_sizes; (void)n_in; (void)out_size; (void)ws_size;
    const float* x    = (const float*)d_in[0];
    const float* ea   = (const float*)d_in[1];
    const int*   ei   = (const int*)d_in[2];
    const int*   ewi  = (const int*)d_in[3];
    const float* W1   = (const float*)d_in[4];
    const float* b1   = (const float*)d_in[5];
    const float* g1   = (const float*)d_in[6];
    const float* be1  = (const float*)d_in[7];
    const float* W2   = (const float*)d_in[8];
    const float* b2   = (const float*)d_in[9];
    const float* g2   = (const float*)d_in[10];
    const float* be2  = (const float*)d_in[11];
    const float* Wih1 = (const float*)d_in[12];
    const float* Whh1 = (const float*)d_in[13];
    const float* bih1 = (const float*)d_in[14];
    const float* bhh1 = (const float*)d_in[15];
    const float* Wih2 = (const float*)d_in[16];
    const float* Whh2 = (const float*)d_in[17];
    const float* bih2 = (const float*)d_in[18];
    const float* bhh2 = (const float*)d_in[19];
    const float* dWa  = (const float*)d_in[20];
    const float* dba  = (const float*)d_in[21];
    const float* dWb  = (const float*)d_in[22];
    const float* dbb  = (const float*)d_in[23];
    float* out = (float*)d_out;

    const size_t NSB = (size_t)N_BIG * 64;   // 10.24M
    const size_t NS  = (size_t)N_NODES * 64; // 1.28M
    char* base = (char*)d_ws;
    size_t o = 0;
    float* dis  = (float*)(base + o); o += (size_t)N_BIG * 4;
    ull* deg64  = (ull*)(base + o);   o += (size_t)N_BIG * 8;
    bf* aggb    = (bf*)(base + o);    o += NSB * 2;                // gather out; neb/PQb later
    bf* hbufb   = (bf*)(base + o);    o += NSB * 2;
    bf* h1b     = (bf*)(base + o);    o += NSB * 2;
    bf* h2b     = (bf*)(base + o);    o += NSB * 2;
    bf* hs1     = (bf*)(base + o);    o += NS * 2;
    bf* hs2     = (bf*)(base + o);    o += NS * 2;
    bf* B1f     = (bf*)(base + o);    o += (size_t)16 * 6 * 64 * 8 * 2;
    bf* B2f     = (bf*)(base + o);    o += (size_t)16 * 4 * 64 * 8 * 2;
    bf* W2t     = (bf*)(base + o);    o += 64 * 64 * 2;
    float* bc1  = (float*)(base + o); o += 256 * 4;
    float* bc2  = (float*)(base + o); o += 256 * 4;
    bf* Bpqf    = (bf*)(base + o);    o += (size_t)18 * 5 * 64 * 8 * 2;
    float* stats= (float*)(base + o); o += 256 * 4;
    float2* pairs = (float2*)(base + o); o += (size_t)NE * 8;
    int* offs = (int*)(base + o); o += (size_t)N_BIG * 4;
    int* cnt  = (int*)(base + o); o += (size_t)N_BIG * 4;
    int* cur  = (int*)(base + o); o += (size_t)N_BIG * 4;
    int* part = (int*)(base + o); o += 256 * 4;
    bf* neb = aggb;                          // 20032 x 160 bf16
    bf* PQb = aggb + (size_t)20032 * 160;    // 20000 x 288 bf16

    // ---- prep + CSR build ----
    k_prep<<<512, 256, 0, stream>>>(Wih1, Whh1, bih1, bhh1, Wih2, Whh2, bih2, bhh2,
                                    dWa, W2, deg64, B1f, B2f, W2t, bc1, bc2, Bpqf, stats);
    k_deg_count<<<(NE + 255) / 256, 256, 0, stream>>>(ei, ea, deg64);
    k_dis<<<(N_BIG + 255) / 256, 256, 0, stream>>>(deg64, dis, cnt);
    k_scan1<<<157, 256, 0, stream>>>(cnt, offs, part);
    k_scan2<<<1, 256, 0, stream>>>(part, 157);
    k_scan3<<<157, 256, 0, stream>>>(offs, cur, part);
    k_fill<<<(NE + 255) / 256, 256, 0, stream>>>(ei, ea, dis, cur, pairs);

    // ---- GCN layer 1 ----
    k_xw1<<<N_BIG / 4, 256, 0, stream>>>(x, W1, hbufb);
    k_gcn_gather<<<N_BIG / 8, 256, 0, stream>>>(hbufb, dis, offs, cnt, pairs, b1, aggb);
    k_bnstats<<<256, 256, 0, stream>>>(aggb, stats, stats + 64);
    k_bnapply<<<4096, 256, 0, stream>>>(aggb, g1, be1, stats, stats + 64, h1b);

    // ---- GCN layer 2 ----
    k_h1w2<<<2500, 256, 0, stream>>>(h1b, W2t, hbufb);
    k_gcn_gather<<<N_BIG / 8, 256, 0, stream>>>(hbufb, dis, offs, cnt, pairs, b2, aggb);
    k_bnstats<<<256, 256, 0, stream>>>(aggb, stats + 128, stats + 192);
    k_bnapply<<<4096, 256, 0, stream>>>(aggb, g2, be2, stats + 128, stats + 192, h2b);

    // ---- both LSTMs, all 8 steps, one launch ----
    k_lstm_fused<<<625, 256, 0, stream>>>(h1b, h2b, B1f, B2f, bc1, bc2, hs1, hs2);

    // ---- node embeddings + decoder ----
    k_nodeemb<<<12500, 256, 0, stream>>>(hs1, hs2, x, neb);
    k_pq<<<313, 256, 0, stream>>>(neb, Bpqf, dba, PQb);
    k_edge<<<E_DEC / 8, 256, 0, stream>>>(ewi, PQb, dWb, dbb, out);
}

// Round 11
// 733.962 us; speedup vs baseline: 2.6207x; 1.0024x over previous
//
#include <hip/hip_runtime.h>
#include <hip/hip_bf16.h>

#define IN_C 8
#define HID 64
#define N_NODES 20000
#define WINDOW 8
#define N_BIG 160000
#define NE 1600000
#define E_DEC 500000
#define DHV 143
#define EPSV 1e-5f

typedef __hip_bfloat16 bf;
typedef unsigned long long ull;
typedef __attribute__((ext_vector_type(8))) short short8;
typedef __attribute__((ext_vector_type(4))) float float4_;

__device__ __forceinline__ float b2f(bf v) { return __bfloat162float(v); }
__device__ __forceinline__ bf f2b(float v) { return __float2bfloat16(v); }
__device__ __forceinline__ float bflo(unsigned int u) { return __uint_as_float(u << 16); }
__device__ __forceinline__ float bfhi(unsigned int u) { return __uint_as_float(u & 0xffff0000u); }
__device__ __forceinline__ unsigned int packbf2(float lo, float hi) {
    unsigned int ul = __bfloat16_as_ushort(f2b(lo));
    unsigned int uh = __bfloat16_as_ushort(f2b(hi));
    return ul | (uh << 16);
}
__device__ __forceinline__ float sigf(float x) {
    return __builtin_amdgcn_rcpf(1.f + __expf(-x));
}
__device__ __forceinline__ float tanhfast(float x) {
    x = fminf(fmaxf(x, -15.f), 15.f);
    float e = __expf(2.f * x);
    return (e - 1.f) * __builtin_amdgcn_rcpf(e + 1.f);
}

// ---------------------------------------------------------------- prep ------
// (B1f and W2t are now built at runtime by k_fold1/k_fold2 with BN folded in)
__global__ void k_prep(const float* Wih2, const float* Whh2, const float* bih1, const float* bhh1,
                       const float* bih2, const float* bhh2, const float* dWa,
                       ull* deg64, bf* B2f, float* bc1, float* bc2, bf* Bpqf, float* stats)
{
    int i0 = blockIdx.x * blockDim.x + threadIdx.x;
    int stride = gridDim.x * blockDim.x;
    for (int i = i0; i < N_BIG; i += stride) deg64[i] = 0ull;
    for (int i = i0; i < 16 * 4 * 64 * 8; i += stride) {   // B2 fragments (K=128)
        int j = i & 7, lane = (i >> 3) & 63, r = i >> 9;
        int c = r & 3, ct = r >> 2;
        int q = lane >> 4, l15 = lane & 15;
        int n = ct * 16 + l15, k = c * 32 + q * 8 + j;
        B2f[i] = f2b((k < 64) ? Wih2[n * 64 + k] : Whh2[n * 64 + (k - 64)]);
    }
    for (int i = i0; i < 256; i += stride) {
        bc1[i] = bih1[i] + bhh1[i];
        bc2[i] = bih2[i] + bhh2[i];
    }
    // decoder weight fragments: N=288 (18 tiles), K=160 (5 chunks; k<143 real)
    for (int i = i0; i < 18 * 5 * 64 * 8; i += stride) {
        int j = i & 7, lane = (i >> 3) & 63, r = i >> 9;
        int c = r % 5, ct = r / 5;
        int q = lane >> 4, l15 = lane & 15;
        int n = ct * 16 + l15, k = c * 32 + q * 8 + j;
        float v = 0.f;
        if (k < DHV) {
            if (n < DHV) v = dWa[k * DHV + n];
            else if (n >= 144 && n < 144 + DHV) v = dWa[(DHV + k) * DHV + (n - 144)];
        }
        Bpqf[i] = f2b(v);
    }
    for (int i = i0; i < 256; i += stride) stats[i] = 0.f;
}

// ---------------------------------- degree + edge count (one packed atomic) --
__global__ void k_deg_count(const int* ei, const float* ea, ull* deg64) {
    int e = blockIdx.x * blockDim.x + threadIdx.x;
    if (e >= NE) return;
    int c = ei[NE + e];
    unsigned int q = (unsigned int)(ea[e] * 16777216.f + 0.5f);
    atomicAdd(&deg64[c], (1ull << 40) | (ull)q);
}

__global__ void k_dis(const ull* deg64, float* dis, int* cnt) {
    int i = blockIdx.x * blockDim.x + threadIdx.x;
    if (i < N_BIG) {
        ull v = deg64[i];
        cnt[i] = (int)(v >> 40);
        float deg = 1.f + (float)(v & 0xFFFFFFFFFFull) * (1.f / 16777216.f);
        dis[i] = rsqrtf(fmaxf(deg, EPSV));
    }
}

// ----------------------------------------------- exclusive scan (3-phase) ---
__global__ __launch_bounds__(256) void k_scan1(const int* cnt, int* offs, int* part) {
    __shared__ int s[256];
    int tid = threadIdx.x;
    int base = blockIdx.x * 1024 + tid * 4;
    int c[4];
    int sum = 0;
#pragma unroll
    for (int j = 0; j < 4; j++) {
        c[j] = (base + j < N_BIG) ? cnt[base + j] : 0;
        sum += c[j];
    }
    s[tid] = sum;
    __syncthreads();
    for (int off = 1; off < 256; off <<= 1) {
        int v = (tid >= off) ? s[tid - off] : 0;
        __syncthreads();
        s[tid] += v;
        __syncthreads();
    }
    int run = s[tid] - sum;
#pragma unroll
    for (int j = 0; j < 4; j++) {
        if (base + j < N_BIG) offs[base + j] = run;
        run += c[j];
    }
    if (tid == 255) part[blockIdx.x] = s[255];
}

__global__ __launch_bounds__(256) void k_scan2(int* part, int np) {
    __shared__ int s[256];
    int tid = threadIdx.x;
    int v = (tid < np) ? part[tid] : 0;
    s[tid] = v;
    __syncthreads();
    for (int off = 1; off < 256; off <<= 1) {
        int w = (tid >= off) ? s[tid - off] : 0;
        __syncthreads();
        s[tid] += w;
        __syncthreads();
    }
    if (tid < np) part[tid] = s[tid] - v;
}

__global__ __launch_bounds__(256) void k_scan3(int* offs, int* cur, const int* part) {
    int add = part[blockIdx.x];
    int base = blockIdx.x * 1024 + threadIdx.x * 4;
#pragma unroll
    for (int j = 0; j < 4; j++) {
        if (base + j < N_BIG) {
            int v = offs[base + j] + add;
            offs[base + j] = v;
            cur[base + j] = v;
        }
    }
}

// ------------------------------------------------------------ CSR fill ------
__global__ void k_fill(const int* ei, const float* ea, const float* dis, int* cur, float2* pairs) {
    int e = blockIdx.x * blockDim.x + threadIdx.x;
    if (e >= NE) return;
    int r = ei[e], c = ei[NE + e];
    float norm = dis[r] * ea[e] * dis[c];
    int p = atomicAdd(&cur[c], 1);
    pairs[p] = make_float2(__int_as_float(r), norm);
}

// ------------------------------------------------------------ x @ W1 --------
__global__ __launch_bounds__(256) void k_xw1(const float* x, const float* W1, bf* hbufb) {
    __shared__ float Ws[IN_C * HID];
    __shared__ float xs[4][IN_C];
    int tid = threadIdx.x;
    Ws[tid] = W1[tid];
    Ws[tid + 256] = W1[tid + 256];
    int node0 = blockIdx.x * 4;
    if (tid < 32) xs[tid >> 3][tid & 7] = x[node0 * IN_C + tid];
    __syncthreads();
    int ch = tid & 63, ns = tid >> 6;
    float acc = 0.f;
#pragma unroll
    for (int c = 0; c < IN_C; c++) acc += xs[ns][c] * Ws[c * 64 + ch];
    hbufb[(size_t)(node0 + ns) * 64 + ch] = f2b(acc);
}

// ------------------------------------------- GCN aggregation (CSR gather) ---
// 2 nodes/wave (32 lanes/node, 2 ch/lane); 8-wide edge unroll; raw relu out.
__global__ void k_gcn_gather(const bf* h, const float* dis, const int* offs, const int* cnt,
                             const float2* pairs, const float* bias, bf* outb) {
    int wv = (blockIdx.x * blockDim.x + threadIdx.x) >> 6;
    int half = (threadIdx.x >> 5) & 1, l = threadIdx.x & 31;
    int c = wv * 2 + half;
    if (c >= N_BIG) return;
    float d = dis[c];
    unsigned int hv = *(const unsigned int*)(h + (size_t)c * 64 + 2 * l);
    float dd = d * d;
    float ax = dd * bflo(hv), ay = dd * bfhi(hv);
    int o = offs[c], n = cnt[c];
    int e = 0;
    for (; e + 8 <= n; e += 8) {
        float2 p[8];
#pragma unroll
        for (int j = 0; j < 8; j++) p[j] = pairs[o + e + j];
        unsigned int v[8];
#pragma unroll
        for (int j = 0; j < 8; j++)
            v[j] = *(const unsigned int*)(h + (size_t)__float_as_int(p[j].x) * 64 + 2 * l);
#pragma unroll
        for (int j = 0; j < 8; j++) { ax += p[j].y * bflo(v[j]); ay += p[j].y * bfhi(v[j]); }
    }
    for (; e + 4 <= n; e += 4) {
        float2 p[4];
#pragma unroll
        for (int j = 0; j < 4; j++) p[j] = pairs[o + e + j];
        unsigned int v[4];
#pragma unroll
        for (int j = 0; j < 4; j++)
            v[j] = *(const unsigned int*)(h + (size_t)__float_as_int(p[j].x) * 64 + 2 * l);
#pragma unroll
        for (int j = 0; j < 4; j++) { ax += p[j].y * bflo(v[j]); ay += p[j].y * bfhi(v[j]); }
    }
    for (; e < n; e++) {
        float2 p = pairs[o + e];
        unsigned int v = *(const unsigned int*)(h + (size_t)__float_as_int(p.x) * 64 + 2 * l);
        ax += p.y * bflo(v);
        ay += p.y * bfhi(v);
    }
    float2 bv = *(const float2*)(bias + 2 * l);
    unsigned int st = packbf2(fmaxf(ax + bv.x, 0.f), fmaxf(ay + bv.y, 0.f));
    *(unsigned int*)(outb + (size_t)c * 64 + 2 * l) = st;
}

// ------------------------------------------------------------ BN stats ------
__global__ void k_bnstats(const bf* buf, float* s_sum, float* s_sq) {
    int ch = threadIdx.x & 63, g = threadIdx.x >> 6;
    float s = 0.f, q = 0.f;
    for (int r = blockIdx.x * 4 + g; r < N_BIG; r += gridDim.x * 4) {
        float v = b2f(buf[(size_t)r * 64 + ch]);
        s += v;
        q += v * v;
    }
    unsafeAtomicAdd(&s_sum[ch], s);
    unsafeAtomicAdd(&s_sq[ch], q);
}

// ------------------------------- fold BN1 affine into W2^T + bias ----------
// A1 = g1*rsqrt(var+eps), C1 = be1 - m*A1;  W2t'[n][k] = W2[k][n]*A1[k];
// w2b[n] = sum_k C1[k]*W2[k][n].  AC[0..63]=A1, AC[64..127]=C1.
__global__ __launch_bounds__(256) void k_fold1(const float* W2, const float* g1, const float* be1,
                                               const float* stats, bf* W2t, float* w2b, float* AC) {
    __shared__ float A[64], C[64];
    int tid = threadIdx.x;
    if (tid < 64) {
        float m = stats[tid] * (1.f / (float)N_BIG);
        float var = stats[64 + tid] * (1.f / (float)N_BIG) - m * m;
        float a = g1[tid] * rsqrtf(var + EPSV);
        float c = be1[tid] - m * a;
        A[tid] = a; C[tid] = c;
        AC[tid] = a; AC[64 + tid] = c;
    }
    __syncthreads();
    for (int i = tid; i < 4096; i += 256) {
        int n = i >> 6, k = i & 63;
        W2t[i] = f2b(W2[k * 64 + n] * A[k]);
    }
    if (tid < 64) {
        float s = 0.f;
        for (int k = 0; k < 64; k++) s += C[k] * W2[k * 64 + tid];
        w2b[tid] = s;
    }
}

// -------- fold BN1/BN2 affine into LSTM1 weights (B1f fragments) + bias ----
__global__ void k_fold2(const float* Wih1, const float* Whh1,
                        const float* g2, const float* be2, const float* stats,
                        const float* AC, const float* bc1, bf* B1f, float* bc1f) {
    int i0 = blockIdx.x * blockDim.x + threadIdx.x;
    int stride = gridDim.x * blockDim.x;
    for (int i = i0; i < 16 * 6 * 64 * 8; i += stride) {
        int j = i & 7, lane = (i >> 3) & 63, r = i >> 9;
        int c = r % 6, ct = r / 6;
        int q = lane >> 4, l15 = lane & 15;
        int n = ct * 16 + l15, k = c * 32 + q * 8 + j;
        float w = (k < 128) ? Wih1[n * 128 + k] : Whh1[n * 64 + (k - 128)];
        float scale = 1.f;
        if (k < 64) scale = AC[k];
        else if (k < 128) {
            int ch = k - 64;
            float m = stats[128 + ch] * (1.f / (float)N_BIG);
            float var = stats[192 + ch] * (1.f / (float)N_BIG) - m * m;
            scale = g2[ch] * rsqrtf(var + EPSV);
        }
        B1f[i] = f2b(w * scale);
    }
    for (int n = i0; n < 256; n += stride) {
        float s = bc1[n];
        for (int k = 0; k < 64; k++) s += AC[64 + k] * Wih1[n * 128 + k];
        for (int ch = 0; ch < 64; ch++) {
            float m = stats[128 + ch] * (1.f / (float)N_BIG);
            float var = stats[192 + ch] * (1.f / (float)N_BIG) - m * m;
            float a = g2[ch] * rsqrtf(var + EPSV);
            float c2v = be2[ch] - m * a;
            s += c2v * Wih1[n * 128 + 64 + ch];
        }
        bc1f[n] = s;
    }
}

// -------------------------- h1_raw @ (A1-scaled W2) + w2b  (bf16 MFMA) ------
__global__ __launch_bounds__(256) void k_h1w2(const bf* h1b, const bf* W2t, const float* w2b, bf* outb) {
    int tid = threadIdx.x, w = tid >> 6, lane = tid & 63;
    int q = lane >> 4, l15 = lane & 15;
    size_t r0 = (size_t)blockIdx.x * 64 + w * 16;
    float4_ acc[4];
#pragma unroll
    for (int ct = 0; ct < 4; ct++) acc[ct] = (float4_){0.f, 0.f, 0.f, 0.f};
#pragma unroll
    for (int c = 0; c < 2; c++) {
        int koff = c * 32 + q * 8;
        short8 a = *(const short8*)(h1b + (r0 + l15) * 64 + koff);
#pragma unroll
        for (int ct = 0; ct < 4; ct++) {
            short8 b = *(const short8*)(W2t + (size_t)(ct * 16 + l15) * 64 + koff);
            acc[ct] = __builtin_amdgcn_mfma_f32_16x16x32_bf16(a, b, acc[ct], 0, 0, 0);
        }
    }
    size_t node0 = r0 + q * 4;
#pragma unroll
    for (int reg = 0; reg < 4; reg++)
#pragma unroll
        for (int ct = 0; ct < 4; ct++)
            outb[(node0 + reg) * 64 + ct * 16 + l15] = f2b(acc[ct][reg] + w2b[ct * 16 + l15]);
}

// ----------------------------------------- fully fused double LSTM (MFMA) ---
// Double-buffered LDS h-state (parity on t) -> 2 barriers/step instead of 4.
__global__ __launch_bounds__(256, 1) void k_lstm_fused(
    const bf* h1b, const bf* h2b, const bf* B1f, const bf* B2f,
    const float* bc1, const float* bc2, bf* H1out, bf* H2out)
{
    __shared__ bf h1s[2][32][72];
    __shared__ bf h2s[2][32][72];
    int tid = threadIdx.x, w = tid >> 6, lane = tid & 63;
    int q = lane >> 4, l15 = lane & 15;
    int gnode0 = blockIdx.x * 32;
    short8 B1r[6][4];
    short8 B2r[4][4];
#pragma unroll
    for (int c = 0; c < 6; c++)
#pragma unroll
        for (int g = 0; g < 4; g++)
            B1r[c][g] = *(const short8*)(B1f + (size_t)(((w + 4 * g) * 6 + c) * 64 + lane) * 8);
#pragma unroll
    for (int c = 0; c < 4; c++)
#pragma unroll
        for (int g = 0; g < 4; g++)
            B2r[c][g] = *(const short8*)(B2f + (size_t)(((w + 4 * g) * 4 + c) * 64 + lane) * 8);
    float c1[2][4] = {}, c2[2][4] = {};
    float bv1[4], bv2[4];
#pragma unroll
    for (int g = 0; g < 4; g++) {
        bv1[g] = bc1[(w + 4 * g) * 16 + l15];
        bv2[g] = bc2[(w + 4 * g) * 16 + l15];
    }
    for (int t = 0; t < WINDOW; t++) {
        int cur = t & 1, prv = cur ^ 1;
        const size_t toff = (size_t)t * N_NODES * 64;
        // ======== LSTM 1: gates = [h1n_t | h2n_t | h1_{t-1}] @ B1' ========
        float4_ acc[2][4];
#pragma unroll
        for (int m = 0; m < 2; m++)
#pragma unroll
            for (int g = 0; g < 4; g++) acc[m][g] = (float4_){bv1[g], bv1[g], bv1[g], bv1[g]};
#pragma unroll
        for (int c = 0; c < 4; c++) {
            const bf* sp = (c < 2) ? h1b + toff : h2b + toff;
            int koff = (c & 1) * 32 + q * 8;
#pragma unroll
            for (int m = 0; m < 2; m++) {
                short8 a = *(const short8*)(sp + (size_t)(gnode0 + m * 16 + l15) * 64 + koff);
#pragma unroll
                for (int g = 0; g < 4; g++)
                    acc[m][g] = __builtin_amdgcn_mfma_f32_16x16x32_bf16(a, B1r[c][g], acc[m][g], 0, 0, 0);
            }
        }
        if (t > 0) {
#pragma unroll
            for (int c = 4; c < 6; c++) {
                int koff = (c & 1) * 32 + q * 8;
#pragma unroll
                for (int m = 0; m < 2; m++) {
                    short8 a = *(const short8*)&h1s[prv][m * 16 + l15][koff];
#pragma unroll
                    for (int g = 0; g < 4; g++)
                        acc[m][g] = __builtin_amdgcn_mfma_f32_16x16x32_bf16(a, B1r[c][g], acc[m][g], 0, 0, 0);
                }
            }
        }
#pragma unroll
        for (int m = 0; m < 2; m++)
#pragma unroll
            for (int reg = 0; reg < 4; reg++) {
                float gi = acc[m][0][reg], gf = acc[m][1][reg];
                float gg = acc[m][2][reg], go = acc[m][3][reg];
                float co = (t == 0) ? 0.f : c1[m][reg];
                float cn = sigf(gf) * co + sigf(gi) * tanhfast(gg);
                float hn = sigf(go) * tanhfast(cn);
                c1[m][reg] = cn;
                int nl = m * 16 + q * 4 + reg;
                h1s[cur][nl][w * 16 + l15] = f2b(hn);
                if (t == WINDOW - 1)
                    H1out[(size_t)(gnode0 + nl) * 64 + w * 16 + l15] = f2b(hn);
            }
        __syncthreads();   // h1s[cur] visible for LSTM2
        // ======== LSTM 2: gates = [h1_t | h2_{t-1}] @ B2 ========
#pragma unroll
        for (int m = 0; m < 2; m++)
#pragma unroll
            for (int g = 0; g < 4; g++) acc[m][g] = (float4_){bv2[g], bv2[g], bv2[g], bv2[g]};
#pragma unroll
        for (int c = 0; c < 2; c++) {
            int koff = (c & 1) * 32 + q * 8;
#pragma unroll
            for (int m = 0; m < 2; m++) {
                short8 a = *(const short8*)&h1s[cur][m * 16 + l15][koff];
#pragma unroll
                for (int g = 0; g < 4; g++)
                    acc[m][g] = __builtin_amdgcn_mfma_f32_16x16x32_bf16(a, B2r[c][g], acc[m][g], 0, 0, 0);
            }
        }
        if (t > 0) {
#pragma unroll
            for (int c = 2; c < 4; c++) {
                int koff = (c & 1) * 32 + q * 8;
#pragma unroll
                for (int m = 0; m < 2; m++) {
                    short8 a = *(const short8*)&h2s[prv][m * 16 + l15][koff];
#pragma unroll
                    for (int g = 0; g < 4; g++)
                        acc[m][g] = __builtin_amdgcn_mfma_f32_16x16x32_bf16(a, B2r[c][g], acc[m][g], 0, 0, 0);
                }
            }
        }
#pragma unroll
        for (int m = 0; m < 2; m++)
#pragma unroll
            for (int reg = 0; reg < 4; reg++) {
                float gi = acc[m][0][reg], gf = acc[m][1][reg];
                float gg = acc[m][2][reg], go = acc[m][3][reg];
                float co = (t == 0) ? 0.f : c2[m][reg];
                float cn = sigf(gf) * co + sigf(gi) * tanhfast(gg);
                float hn = sigf(go) * tanhfast(cn);
                c2[m][reg] = cn;
                int nl = m * 16 + q * 4 + reg;
                h2s[cur][nl][w * 16 + l15] = f2b(hn);
                if (t == WINDOW - 1)
                    H2out[(size_t)(gnode0 + nl) * 64 + w * 16 + l15] = f2b(hn);
            }
        __syncthreads();   // h2s[cur] visible for next step
    }
}

// ----------------------------------------------------------- small utils ----
__global__ void k_nodeemb(const bf* H1, const bf* H2, const float* x, bf* neb) {
    int stride = gridDim.x * blockDim.x;
    for (int idx = blockIdx.x * blockDim.x + threadIdx.x; idx < N_NODES * 160; idx += stride) {
        int n = idx / 160, j = idx % 160;
        float v;
        if (j < 64) v = b2f(H1[(size_t)n * 64 + j]);
        else if (j < 128) v = b2f(H2[(size_t)n * 64 + (j - 64)]);
        else if (j < DHV) {
            int s = j - 128;
            v = (s < 8) ? x[n * IN_C + s] : x[(size_t)((s - 7) * N_NODES + n) * IN_C + 7];
        } else v = 0.f;
        neb[idx] = f2b(v);
    }
}

// PQ = neb @ Bpq (bf16 MFMA); dba folded into P block
__global__ __launch_bounds__(256) void k_pq(const bf* neb, const bf* Bpqf, const float* dba, bf* PQb) {
    int tid = threadIdx.x, w = tid >> 6, lane = tid & 63;
    int q = lane >> 4, l15 = lane & 15;
    int r0 = blockIdx.x * 64 + w * 16;
    float4_ acc[18];
#pragma unroll
    for (int ct = 0; ct < 18; ct++) acc[ct] = (float4_){0.f, 0.f, 0.f, 0.f};
#pragma unroll
    for (int c = 0; c < 5; c++) {
        short8 a = *(const short8*)(neb + (size_t)(r0 + l15) * 160 + c * 32 + q * 8);
#pragma unroll
        for (int ct = 0; ct < 18; ct++) {
            short8 b = *(const short8*)(Bpqf + (size_t)((ct * 5 + c) * 64 + lane) * 8);
            acc[ct] = __builtin_amdgcn_mfma_f32_16x16x32_bf16(a, b, acc[ct], 0, 0, 0);
        }
    }
#pragma unroll
    for (int reg = 0; reg < 4; reg++) {
        int node = r0 + q * 4 + reg;
        if (node < N_NODES)
#pragma unroll
            for (int ct = 0; ct < 18; ct++) {
                int col = ct * 16 + l15;
                float add = (ct < 9 && col < DHV) ? dba[col] : 0.f;
                PQb[(size_t)node * 288 + col] = f2b(acc[ct][reg] + add);
            }
    }
}

// decoder: 2 edges/wave, 32 lanes/edge, 8B loads; P' already has +dba
__global__ __launch_bounds__(256) void k_edge(const int* ewi, const bf* PQb,
                                              const float* dWb, const float* dbb, float* out) {
    int wv = (blockIdx.x * blockDim.x + threadIdx.x) >> 6;
    int half = (threadIdx.x >> 5) & 1, l = threadIdx.x & 31;
    int e = wv * 2 + half;
    if (e >= E_DEC) return;
    int src = ewi[e], trg = ewi[E_DEC + e];
    const bf* Pr = PQb + (size_t)src * 288;
    const bf* Qr = PQb + (size_t)trg * 288 + 144;
    float acc;
    {
        uint2 pv = *(const uint2*)(Pr + 4 * l);
        uint2 qv = *(const uint2*)(Qr + 4 * l);
        float4 wv4 = *(const float4*)(dWb + 4 * l);
        float s0 = fmaxf(bflo(pv.x) + bflo(qv.x), 0.f);
        float s1 = fmaxf(bfhi(pv.x) + bfhi(qv.x), 0.f);
        float s2 = fmaxf(bflo(pv.y) + bflo(qv.y), 0.f);
        float s3 = fmaxf(bfhi(pv.y) + bfhi(qv.y), 0.f);
        acc = s0 * wv4.x + s1 * wv4.y + s2 * wv4.z + s3 * wv4.w;
    }
    if (l < 4) {
        int u0 = 128 + 4 * l;
        uint2 pv = *(const uint2*)(Pr + u0);
        uint2 qv = *(const uint2*)(Qr + u0);
        float w0 = dWb[u0], w1 = dWb[u0 + 1], w2 = dWb[u0 + 2];
        float w3 = (u0 + 3 < DHV) ? dWb[u0 + 3] : 0.f;
        acc += fmaxf(bflo(pv.x) + bflo(qv.x), 0.f) * w0;
        acc += fmaxf(bfhi(pv.x) + bfhi(qv.x), 0.f) * w1;
        acc += fmaxf(bflo(pv.y) + bflo(qv.y), 0.f) * w2;
        acc += fmaxf(bfhi(pv.y) + bfhi(qv.y), 0.f) * w3;
    }
#pragma unroll
    for (int off = 16; off > 0; off >>= 1) acc += __shfl_xor(acc, off);
    if (l == 0) out[e] = acc + dbb[0];
}

// ---------------------------------------------------------------------------
extern "C" void kernel_launch(void* const* d_in, const int* in_sizes, int n_in,
                              void* d_out, int out_size, void* d_ws, size_t ws_size,
                              hipStream_t stream) {
    (void)in_sizes; (void)n_in; (void)out_size; (void)ws_size;
    const float* x    = (const float*)d_in[0];
    const float* ea   = (const float*)d_in[1];
    const int*   ei   = (const int*)d_in[2];
    const int*   ewi  = (const int*)d_in[3];
    const float* W1   = (const float*)d_in[4];
    const float* b1   = (const float*)d_in[5];
    const float* g1   = (const float*)d_in[6];
    const float* be1  = (const float*)d_in[7];
    const float* W2   = (const float*)d_in[8];
    const float* b2   = (const float*)d_in[9];
    const float* g2   = (const float*)d_in[10];
    const float* be2  = (const float*)d_in[11];
    const float* Wih1 = (const float*)d_in[12];
    const float* Whh1 = (const float*)d_in[13];
    const float* bih1 = (const float*)d_in[14];
    const float* bhh1 = (const float*)d_in[15];
    const float* Wih2 = (const float*)d_in[16];
    const float* Whh2 = (const float*)d_in[17];
    const float* bih2 = (const float*)d_in[18];
    const float* bhh2 = (const float*)d_in[19];
    const float* dWa  = (const float*)d_in[20];
    const float* dba  = (const float*)d_in[21];
    const float* dWb  = (const float*)d_in[22];
    const float* dbb  = (const float*)d_in[23];
    float* out = (float*)d_out;

    const size_t NSB = (size_t)N_BIG * 64;
    const size_t NS  = (size_t)N_NODES * 64;
    char* base = (char*)d_ws;
    size_t o = 0;
    float* dis  = (float*)(base + o); o += (size_t)N_BIG * 4;
    ull* deg64  = (ull*)(base + o);   o += (size_t)N_BIG * 8;
    bf* aggb    = (bf*)(base + o);    o += NSB * 2;                // neb/PQb alias region
    bf* hbufb   = (bf*)(base + o);    o += NSB * 2;
    bf* h1b     = (bf*)(base + o);    o += NSB * 2;                // raw relu layer1
    bf* h2b     = (bf*)(base + o);    o += NSB * 2;                // raw relu layer2
    bf* hs1     = (bf*)(base + o);    o += NS * 2;
    bf* hs2     = (bf*)(base + o);    o += NS * 2;
    bf* B1f     = (bf*)(base + o);    o += (size_t)16 * 6 * 64 * 8 * 2;
    bf* B2f     = (bf*)(base + o);    o += (size_t)16 * 4 * 64 * 8 * 2;
    bf* W2t     = (bf*)(base + o);    o += 64 * 64 * 2;
    float* bc1  = (float*)(base + o); o += 256 * 4;
    float* bc2  = (float*)(base + o); o += 256 * 4;
    bf* Bpqf    = (bf*)(base + o);    o += (size_t)18 * 5 * 64 * 8 * 2;
    float* stats= (float*)(base + o); o += 256 * 4;
    float* w2b  = (float*)(base + o); o += 64 * 4;
    float* AC   = (float*)(base + o); o += 128 * 4;
    float* bc1f = (float*)(base + o); o += 256 * 4;
    float2* pairs = (float2*)(base + o); o += (size_t)NE * 8;
    int* offs = (int*)(base + o); o += (size_t)N_BIG * 4;
    int* cnt  = (int*)(base + o); o += (size_t)N_BIG * 4;
    int* cur  = (int*)(base + o); o += (size_t)N_BIG * 4;
    int* part = (int*)(base + o); o += 256 * 4;
    bf* neb = aggb;                          // 20032 x 160 bf16
    bf* PQb = aggb + (size_t)20032 * 160;    // 20000 x 288 bf16

    // ---- prep + CSR build ----
    k_prep<<<512, 256, 0, stream>>>(Wih2, Whh2, bih1, bhh1, bih2, bhh2, dWa,
                                    deg64, B2f, bc1, bc2, Bpqf, stats);
    k_deg_count<<<(NE + 255) / 256, 256, 0, stream>>>(ei, ea, deg64);
    k_dis<<<(N_BIG + 255) / 256, 256, 0, stream>>>(deg64, dis, cnt);
    k_scan1<<<157, 256, 0, stream>>>(cnt, offs, part);
    k_scan2<<<1, 256, 0, stream>>>(part, 157);
    k_scan3<<<157, 256, 0, stream>>>(offs, cur, part);
    k_fill<<<(NE + 255) / 256, 256, 0, stream>>>(ei, ea, dis, cur, pairs);

    // ---- GCN layer 1 (raw relu out; BN folded downstream) ----
    k_xw1<<<N_BIG / 4, 256, 0, stream>>>(x, W1, hbufb);
    k_gcn_gather<<<N_BIG / 8, 256, 0, stream>>>(hbufb, dis, offs, cnt, pairs, b1, h1b);
    k_bnstats<<<256, 256, 0, stream>>>(h1b, stats, stats + 64);
    k_fold1<<<1, 256, 0, stream>>>(W2, g1, be1, stats, W2t, w2b, AC);

    // ---- GCN layer 2 ----
    k_h1w2<<<2500, 256, 0, stream>>>(h1b, W2t, w2b, hbufb);
    k_gcn_gather<<<N_BIG / 8, 256, 0, stream>>>(hbufb, dis, offs, cnt, pairs, b2, h2b);
    k_bnstats<<<256, 256, 0, stream>>>(h2b, stats + 128, stats + 192);
    k_fold2<<<64, 256, 0, stream>>>(Wih1, Whh1, g2, be2, stats, AC, bc1, B1f, bc1f);

    // ---- both LSTMs, all 8 steps, one launch ----
    k_lstm_fused<<<625, 256, 0, stream>>>(h1b, h2b, B1f, B2f, bc1f, bc2, hs1, hs2);

    // ---- node embeddings + decoder ----
    k_nodeemb<<<12500, 256, 0, stream>>>(hs1, hs2, x, neb);
    k_pq<<<313, 256, 0, stream>>>(neb, Bpqf, dba, PQb);
    k_edge<<<E_DEC / 8, 256, 0, stream>>>(ewi, PQb, dWb, dbb, out);
}

// Round 12
// 688.294 us; speedup vs baseline: 2.7946x; 1.0663x over previous
//
#include <hip/hip_runtime.h>
#include <hip/hip_bf16.h>

#define IN_C 8
#define HID 64
#define N_NODES 20000
#define WINDOW 8
#define N_BIG 160000
#define NE 1600000
#define E_DEC 500000
#define DHV 143
#define EPSV 1e-5f
#define CAP 32
#define OVF_CAP 4096

typedef __hip_bfloat16 bf;
typedef __attribute__((ext_vector_type(8))) short short8;
typedef __attribute__((ext_vector_type(4))) float float4_;

__device__ __forceinline__ float b2f(bf v) { return __bfloat162float(v); }
__device__ __forceinline__ bf f2b(float v) { return __float2bfloat16(v); }
__device__ __forceinline__ float bflo(unsigned int u) { return __uint_as_float(u << 16); }
__device__ __forceinline__ float bfhi(unsigned int u) { return __uint_as_float(u & 0xffff0000u); }
__device__ __forceinline__ unsigned int packbf2(float lo, float hi) {
    unsigned int ul = __bfloat16_as_ushort(f2b(lo));
    unsigned int uh = __bfloat16_as_ushort(f2b(hi));
    return ul | (uh << 16);
}
__device__ __forceinline__ float sigf(float x) {
    return __builtin_amdgcn_rcpf(1.f + __expf(-x));
}
__device__ __forceinline__ float tanhfast(float x) {
    x = fminf(fmaxf(x, -15.f), 15.f);
    float e = __expf(2.f * x);
    return (e - 1.f) * __builtin_amdgcn_rcpf(e + 1.f);
}

// ---------------------------------------------------------------- prep ------
__global__ void k_prep(const float* Wih2, const float* Whh2, const float* bih1, const float* bhh1,
                       const float* bih2, const float* bhh2, const float* dWa,
                       int* cnt, int* ovfn, bf* B2f, float* bc1, float* bc2, bf* Bpqf, float* stats)
{
    int i0 = blockIdx.x * blockDim.x + threadIdx.x;
    int stride = gridDim.x * blockDim.x;
    for (int i = i0; i < N_BIG; i += stride) cnt[i] = 0;
    if (i0 == 0) *ovfn = 0;
    for (int i = i0; i < 16 * 4 * 64 * 8; i += stride) {   // B2 fragments (K=128)
        int j = i & 7, lane = (i >> 3) & 63, r = i >> 9;
        int c = r & 3, ct = r >> 2;
        int q = lane >> 4, l15 = lane & 15;
        int n = ct * 16 + l15, k = c * 32 + q * 8 + j;
        B2f[i] = f2b((k < 64) ? Wih2[n * 64 + k] : Whh2[n * 64 + (k - 64)]);
    }
    for (int i = i0; i < 256; i += stride) {
        bc1[i] = bih1[i] + bhh1[i];
        bc2[i] = bih2[i] + bhh2[i];
    }
    for (int i = i0; i < 18 * 5 * 64 * 8; i += stride) {   // decoder fragments
        int j = i & 7, lane = (i >> 3) & 63, r = i >> 9;
        int c = r % 5, ct = r / 5;
        int q = lane >> 4, l15 = lane & 15;
        int n = ct * 16 + l15, k = c * 32 + q * 8 + j;
        float v = 0.f;
        if (k < DHV) {
            if (n < DHV) v = dWa[k * DHV + n];
            else if (n >= 144 && n < 144 + DHV) v = dWa[(DHV + k) * DHV + (n - 144)];
        }
        Bpqf[i] = f2b(v);
    }
    for (int i = i0; i < 256; i += stride) stats[i] = 0.f;
}

// --------------------- direct bucket fill (1 atomic/edge) fused with x@W1 ---
__global__ __launch_bounds__(256) void k_fill_xw1(const int* ei, const float* ea,
                                                  const float* x, const float* W1,
                                                  int* cnt, float2* bucket, int* ovfn, float4* ovf,
                                                  bf* hbufb) {
    __shared__ float Ws[IN_C * HID];
    __shared__ float xs[4][IN_C];
    int tid = threadIdx.x;
    if (blockIdx.x < 6250) {            // ---- edge fill: 6250*256 = 1.6M exact
        int e = blockIdx.x * 256 + tid;
        int r = ei[e], c = ei[NE + e];
        float a = ea[e];
        int p = atomicAdd(&cnt[c], 1);
        if (p < CAP) bucket[(size_t)c * CAP + p] = make_float2(__int_as_float(r), a);
        else {
            int q = atomicAdd(ovfn, 1);
            if (q < OVF_CAP) ovf[q] = make_float4(__int_as_float(c), __int_as_float(r), a, 0.f);
        }
    } else {                            // ---- x@W1 (raw, unscaled)
        int bid = blockIdx.x - 6250;    // 40000 blocks x 4 nodes
        Ws[tid] = W1[tid];
        Ws[tid + 256] = W1[tid + 256];
        int node0 = bid * 4;
        if (tid < 32) xs[tid >> 3][tid & 7] = x[node0 * IN_C + tid];
        __syncthreads();
        int ch = tid & 63, ns = tid >> 6;
        float acc = 0.f;
#pragma unroll
        for (int c = 0; c < IN_C; c++) acc += xs[ns][c] * Ws[c * 64 + ch];
        hbufb[(size_t)(node0 + ns) * 64 + ch] = f2b(acc);
    }
}

// ------------- deg from buckets -> dis; scale h row in place (h' = dis*h) ---
// 2 nodes/wave (32 lanes each)
__global__ __launch_bounds__(256) void k_disscale(const int* cnt, const float2* bucket,
                                                  const int* ovfn, const float4* ovf,
                                                  float* dis, bf* h) {
    int wv = (blockIdx.x * blockDim.x + threadIdx.x) >> 6;
    int half = (threadIdx.x >> 5) & 1, l = threadIdx.x & 31;
    int c = wv * 2 + half;
    if (c >= N_BIG) return;
    int n = cnt[c];
    int nb = (n < CAP) ? n : CAP;
    float s = 0.f;
    for (int i = l; i < nb; i += 32) s += bucket[(size_t)c * CAP + i].y;
    if (n > CAP) {
        int m = *ovfn; if (m > OVF_CAP) m = OVF_CAP;
        for (int i = l; i < m; i += 32) {
            float4 v = ovf[i];
            if (__float_as_int(v.x) == c) s += v.z;
        }
    }
#pragma unroll
    for (int off = 16; off > 0; off >>= 1) s += __shfl_xor(s, off);
    float deg = 1.f + s;
    float dv = rsqrtf(fmaxf(deg, EPSV));
    if (l == 0) dis[c] = dv;
    unsigned int hv = *(const unsigned int*)(h + (size_t)c * 64 + 2 * l);
    *(unsigned int*)(h + (size_t)c * 64 + 2 * l) = packbf2(dv * bflo(hv), dv * bfhi(hv));
}

// ------------------------------------------- GCN aggregation (bucket gather) -
// agg_c = relu( dis_c * (h'_c + sum ea*h'_r) + bias );  h' pre-scaled by dis_r
__global__ void k_gcn_gather(const bf* h, const float* dis, const int* cnt,
                             const float2* bucket, const int* ovfn, const float4* ovf,
                             const float* bias, bf* outb) {
    int wv = (blockIdx.x * blockDim.x + threadIdx.x) >> 6;
    int half = (threadIdx.x >> 5) & 1, l = threadIdx.x & 31;
    int c = wv * 2 + half;
    if (c >= N_BIG) return;
    unsigned int hv = *(const unsigned int*)(h + (size_t)c * 64 + 2 * l);
    float ax = bflo(hv), ay = bfhi(hv);
    size_t o = (size_t)c * CAP;
    int nfull = cnt[c];
    int n = (nfull < CAP) ? nfull : CAP;
    int e = 0;
    for (; e + 8 <= n; e += 8) {
        float2 p[8];
#pragma unroll
        for (int j = 0; j < 8; j++) p[j] = bucket[o + e + j];
        unsigned int v[8];
#pragma unroll
        for (int j = 0; j < 8; j++)
            v[j] = *(const unsigned int*)(h + (size_t)__float_as_int(p[j].x) * 64 + 2 * l);
#pragma unroll
        for (int j = 0; j < 8; j++) { ax += p[j].y * bflo(v[j]); ay += p[j].y * bfhi(v[j]); }
    }
    for (; e + 4 <= n; e += 4) {
        float2 p[4];
#pragma unroll
        for (int j = 0; j < 4; j++) p[j] = bucket[o + e + j];
        unsigned int v[4];
#pragma unroll
        for (int j = 0; j < 4; j++)
            v[j] = *(const unsigned int*)(h + (size_t)__float_as_int(p[j].x) * 64 + 2 * l);
#pragma unroll
        for (int j = 0; j < 4; j++) { ax += p[j].y * bflo(v[j]); ay += p[j].y * bfhi(v[j]); }
    }
    for (; e < n; e++) {
        float2 p = bucket[o + e];
        unsigned int v = *(const unsigned int*)(h + (size_t)__float_as_int(p.x) * 64 + 2 * l);
        ax += p.y * bflo(v);
        ay += p.y * bfhi(v);
    }
    if (nfull > CAP) {      // practically never
        int m = *ovfn; if (m > OVF_CAP) m = OVF_CAP;
        for (int i = 0; i < m; i++) {
            float4 v = ovf[i];
            if (__float_as_int(v.x) == c) {
                unsigned int hw = *(const unsigned int*)(h + (size_t)__float_as_int(v.y) * 64 + 2 * l);
                ax += v.z * bflo(hw);
                ay += v.z * bfhi(hw);
            }
        }
    }
    float dv = dis[c];
    float2 bv = *(const float2*)(bias + 2 * l);
    unsigned int st = packbf2(fmaxf(dv * ax + bv.x, 0.f), fmaxf(dv * ay + bv.y, 0.f));
    *(unsigned int*)(outb + (size_t)c * 64 + 2 * l) = st;
}

// ------------------------------------------------------------ BN stats ------
__global__ void k_bnstats(const bf* buf, float* s_sum, float* s_sq) {
    int ch = threadIdx.x & 63, g = threadIdx.x >> 6;
    float s = 0.f, q = 0.f;
    for (int r = blockIdx.x * 4 + g; r < N_BIG; r += gridDim.x * 4) {
        float v = b2f(buf[(size_t)r * 64 + ch]);
        s += v;
        q += v * v;
    }
    unsafeAtomicAdd(&s_sum[ch], s);
    unsafeAtomicAdd(&s_sq[ch], q);
}

// ------------------------------- fold BN1 affine into W2^T + bias ----------
__global__ __launch_bounds__(256) void k_fold1(const float* W2, const float* g1, const float* be1,
                                               const float* stats, bf* W2t, float* w2b, float* AC) {
    __shared__ float A[64], C[64];
    int tid = threadIdx.x;
    if (tid < 64) {
        float m = stats[tid] * (1.f / (float)N_BIG);
        float var = stats[64 + tid] * (1.f / (float)N_BIG) - m * m;
        float a = g1[tid] * rsqrtf(var + EPSV);
        float c = be1[tid] - m * a;
        A[tid] = a; C[tid] = c;
        AC[tid] = a; AC[64 + tid] = c;
    }
    __syncthreads();
    for (int i = tid; i < 4096; i += 256) {
        int n = i >> 6, k = i & 63;
        W2t[i] = f2b(W2[k * 64 + n] * A[k]);
    }
    if (tid < 64) {
        float s = 0.f;
        for (int k = 0; k < 64; k++) s += C[k] * W2[k * 64 + tid];
        w2b[tid] = s;
    }
}

// -------- fold BN1/BN2 affine into LSTM1 weights (B1f fragments) + bias ----
__global__ void k_fold2(const float* Wih1, const float* Whh1,
                        const float* g2, const float* be2, const float* stats,
                        const float* AC, const float* bc1, bf* B1f, float* bc1f) {
    int i0 = blockIdx.x * blockDim.x + threadIdx.x;
    int stride = gridDim.x * blockDim.x;
    for (int i = i0; i < 16 * 6 * 64 * 8; i += stride) {
        int j = i & 7, lane = (i >> 3) & 63, r = i >> 9;
        int c = r % 6, ct = r / 6;
        int q = lane >> 4, l15 = lane & 15;
        int n = ct * 16 + l15, k = c * 32 + q * 8 + j;
        float w = (k < 128) ? Wih1[n * 128 + k] : Whh1[n * 64 + (k - 128)];
        float scale = 1.f;
        if (k < 64) scale = AC[k];
        else if (k < 128) {
            int ch = k - 64;
            float m = stats[128 + ch] * (1.f / (float)N_BIG);
            float var = stats[192 + ch] * (1.f / (float)N_BIG) - m * m;
            scale = g2[ch] * rsqrtf(var + EPSV);
        }
        B1f[i] = f2b(w * scale);
    }
    for (int n = i0; n < 256; n += stride) {
        float s = bc1[n];
        for (int k = 0; k < 64; k++) s += AC[64 + k] * Wih1[n * 128 + k];
        for (int ch = 0; ch < 64; ch++) {
            float m = stats[128 + ch] * (1.f / (float)N_BIG);
            float var = stats[192 + ch] * (1.f / (float)N_BIG) - m * m;
            float a = g2[ch] * rsqrtf(var + EPSV);
            float c2v = be2[ch] - m * a;
            s += c2v * Wih1[n * 128 + 64 + ch];
        }
        bc1f[n] = s;
    }
}

// ------------- h1_raw @ (A1-scaled W2) + w2b, epilogue x dis (bf16 MFMA) ----
__global__ __launch_bounds__(256) void k_h1w2(const bf* h1b, const bf* W2t, const float* w2b,
                                              const float* dis, bf* outb) {
    int tid = threadIdx.x, w = tid >> 6, lane = tid & 63;
    int q = lane >> 4, l15 = lane & 15;
    size_t r0 = (size_t)blockIdx.x * 64 + w * 16;
    float4_ acc[4];
#pragma unroll
    for (int ct = 0; ct < 4; ct++) acc[ct] = (float4_){0.f, 0.f, 0.f, 0.f};
#pragma unroll
    for (int c = 0; c < 2; c++) {
        int koff = c * 32 + q * 8;
        short8 a = *(const short8*)(h1b + (r0 + l15) * 64 + koff);
#pragma unroll
        for (int ct = 0; ct < 4; ct++) {
            short8 b = *(const short8*)(W2t + (size_t)(ct * 16 + l15) * 64 + koff);
            acc[ct] = __builtin_amdgcn_mfma_f32_16x16x32_bf16(a, b, acc[ct], 0, 0, 0);
        }
    }
    size_t node0 = r0 + q * 4;
#pragma unroll
    for (int reg = 0; reg < 4; reg++) {
        float dv = dis[node0 + reg];
#pragma unroll
        for (int ct = 0; ct < 4; ct++)
            outb[(node0 + reg) * 64 + ct * 16 + l15] = f2b(dv * (acc[ct][reg] + w2b[ct * 16 + l15]));
    }
}

// ----------------------------------------- fully fused double LSTM (MFMA) ---
// Register-prefetch of next step's global A fragments (issued after step-t's
// global MFMAs; consumed 2 barriers + one LSTM2 later -> HBM latency hidden).
__global__ __launch_bounds__(256, 1) void k_lstm_fused(
    const bf* h1b, const bf* h2b, const bf* B1f, const bf* B2f,
    const float* bc1, const float* bc2, bf* H1out, bf* H2out)
{
    __shared__ bf h1s[2][32][72];
    __shared__ bf h2s[2][32][72];
    int tid = threadIdx.x, w = tid >> 6, lane = tid & 63;
    int q = lane >> 4, l15 = lane & 15;
    int gnode0 = blockIdx.x * 32;
    short8 B1r[6][4];
    short8 B2r[4][4];
#pragma unroll
    for (int c = 0; c < 6; c++)
#pragma unroll
        for (int g = 0; g < 4; g++)
            B1r[c][g] = *(const short8*)(B1f + (size_t)(((w + 4 * g) * 6 + c) * 64 + lane) * 8);
#pragma unroll
    for (int c = 0; c < 4; c++)
#pragma unroll
        for (int g = 0; g < 4; g++)
            B2r[c][g] = *(const short8*)(B2f + (size_t)(((w + 4 * g) * 4 + c) * 64 + lane) * 8);
    float c1[2][4] = {}, c2[2][4] = {};
    float bv1[4], bv2[4];
#pragma unroll
    for (int g = 0; g < 4; g++) {
        bv1[g] = bc1[(w + 4 * g) * 16 + l15];
        bv2[g] = bc2[(w + 4 * g) * 16 + l15];
    }
    // preload A for t=0
    short8 Ag[4][2], An[4][2];
#pragma unroll
    for (int c = 0; c < 4; c++) {
        const bf* sp = (c < 2) ? h1b : h2b;
        int koff = (c & 1) * 32 + q * 8;
#pragma unroll
        for (int m = 0; m < 2; m++)
            Ag[c][m] = *(const short8*)(sp + (size_t)(gnode0 + m * 16 + l15) * 64 + koff);
    }
#pragma unroll
    for (int t = 0; t < WINDOW; t++) {
        int cur = t & 1, prv = cur ^ 1;
        // ======== LSTM 1 ========
        float4_ acc[2][4];
#pragma unroll
        for (int m = 0; m < 2; m++)
#pragma unroll
            for (int g = 0; g < 4; g++) acc[m][g] = (float4_){bv1[g], bv1[g], bv1[g], bv1[g]};
#pragma unroll
        for (int c = 0; c < 4; c++)
#pragma unroll
            for (int m = 0; m < 2; m++)
#pragma unroll
                for (int g = 0; g < 4; g++)
                    acc[m][g] = __builtin_amdgcn_mfma_f32_16x16x32_bf16(Ag[c][m], B1r[c][g], acc[m][g], 0, 0, 0);
        // prefetch next step's A (loads retire during the rest of this step)
        if (t < WINDOW - 1) {
            const size_t toff2 = (size_t)(t + 1) * N_NODES * 64;
#pragma unroll
            for (int c = 0; c < 4; c++) {
                const bf* sp = (c < 2) ? h1b + toff2 : h2b + toff2;
                int koff = (c & 1) * 32 + q * 8;
#pragma unroll
                for (int m = 0; m < 2; m++)
                    An[c][m] = *(const short8*)(sp + (size_t)(gnode0 + m * 16 + l15) * 64 + koff);
            }
        }
        if (t > 0) {
#pragma unroll
            for (int c = 4; c < 6; c++) {
                int koff = (c & 1) * 32 + q * 8;
#pragma unroll
                for (int m = 0; m < 2; m++) {
                    short8 a = *(const short8*)&h1s[prv][m * 16 + l15][koff];
#pragma unroll
                    for (int g = 0; g < 4; g++)
                        acc[m][g] = __builtin_amdgcn_mfma_f32_16x16x32_bf16(a, B1r[c][g], acc[m][g], 0, 0, 0);
                }
            }
        }
#pragma unroll
        for (int m = 0; m < 2; m++)
#pragma unroll
            for (int reg = 0; reg < 4; reg++) {
                float gi = acc[m][0][reg], gf = acc[m][1][reg];
                float gg = acc[m][2][reg], go = acc[m][3][reg];
                float co = (t == 0) ? 0.f : c1[m][reg];
                float cn = sigf(gf) * co + sigf(gi) * tanhfast(gg);
                float hn = sigf(go) * tanhfast(cn);
                c1[m][reg] = cn;
                int nl = m * 16 + q * 4 + reg;
                h1s[cur][nl][w * 16 + l15] = f2b(hn);
                if (t == WINDOW - 1)
                    H1out[(size_t)(gnode0 + nl) * 64 + w * 16 + l15] = f2b(hn);
            }
        __syncthreads();
        // ======== LSTM 2 ========
#pragma unroll
        for (int m = 0; m < 2; m++)
#pragma unroll
            for (int g = 0; g < 4; g++) acc[m][g] = (float4_){bv2[g], bv2[g], bv2[g], bv2[g]};
#pragma unroll
        for (int c = 0; c < 2; c++) {
            int koff = (c & 1) * 32 + q * 8;
#pragma unroll
            for (int m = 0; m < 2; m++) {
                short8 a = *(const short8*)&h1s[cur][m * 16 + l15][koff];
#pragma unroll
                for (int g = 0; g < 4; g++)
                    acc[m][g] = __builtin_amdgcn_mfma_f32_16x16x32_bf16(a, B2r[c][g], acc[m][g], 0, 0, 0);
            }
        }
        if (t > 0) {
#pragma unroll
            for (int c = 2; c < 4; c++) {
                int koff = (c & 1) * 32 + q * 8;
#pragma unroll
                for (int m = 0; m < 2; m++) {
                    short8 a = *(const short8*)&h2s[prv][m * 16 + l15][koff];
#pragma unroll
                    for (int g = 0; g < 4; g++)
                        acc[m][g] = __builtin_amdgcn_mfma_f32_16x16x32_bf16(a, B2r[c][g], acc[m][g], 0, 0, 0);
                }
            }
        }
#pragma unroll
        for (int m = 0; m < 2; m++)
#pragma unroll
            for (int reg = 0; reg < 4; reg++) {
                float gi = acc[m][0][reg], gf = acc[m][1][reg];
                float gg = acc[m][2][reg], go = acc[m][3][reg];
                float co = (t == 0) ? 0.f : c2[m][reg];
                float cn = sigf(gf) * co + sigf(gi) * tanhfast(gg);
                float hn = sigf(go) * tanhfast(cn);
                c2[m][reg] = cn;
                int nl = m * 16 + q * 4 + reg;
                h2s[cur][nl][w * 16 + l15] = f2b(hn);
                if (t == WINDOW - 1)
                    H2out[(size_t)(gnode0 + nl) * 64 + w * 16 + l15] = f2b(hn);
            }
        __syncthreads();
        // rotate prefetch
#pragma unroll
        for (int c = 0; c < 4; c++)
#pragma unroll
            for (int m = 0; m < 2; m++) Ag[c][m] = An[c][m];
    }
}

// ----------------------------------------------------------- small utils ----
__global__ void k_nodeemb(const bf* H1, const bf* H2, const float* x, bf* neb) {
    int stride = gridDim.x * blockDim.x;
    for (int idx = blockIdx.x * blockDim.x + threadIdx.x; idx < N_NODES * 160; idx += stride) {
        int n = idx / 160, j = idx % 160;
        float v;
        if (j < 64) v = b2f(H1[(size_t)n * 64 + j]);
        else if (j < 128) v = b2f(H2[(size_t)n * 64 + (j - 64)]);
        else if (j < DHV) {
            int s = j - 128;
            v = (s < 8) ? x[n * IN_C + s] : x[(size_t)((s - 7) * N_NODES + n) * IN_C + 7];
        } else v = 0.f;
        neb[idx] = f2b(v);
    }
}

__global__ __launch_bounds__(256) void k_pq(const bf* neb, const bf* Bpqf, const float* dba, bf* PQb) {
    int tid = threadIdx.x, w = tid >> 6, lane = tid & 63;
    int q = lane >> 4, l15 = lane & 15;
    int r0 = blockIdx.x * 64 + w * 16;
    float4_ acc[18];
#pragma unroll
    for (int ct = 0; ct < 18; ct++) acc[ct] = (float4_){0.f, 0.f, 0.f, 0.f};
#pragma unroll
    for (int c = 0; c < 5; c++) {
        short8 a = *(const short8*)(neb + (size_t)(r0 + l15) * 160 + c * 32 + q * 8);
#pragma unroll
        for (int ct = 0; ct < 18; ct++) {
            short8 b = *(const short8*)(Bpqf + (size_t)((ct * 5 + c) * 64 + lane) * 8);
            acc[ct] = __builtin_amdgcn_mfma_f32_16x16x32_bf16(a, b, acc[ct], 0, 0, 0);
        }
    }
#pragma unroll
    for (int reg = 0; reg < 4; reg++) {
        int node = r0 + q * 4 + reg;
        if (node < N_NODES)
#pragma unroll
            for (int ct = 0; ct < 18; ct++) {
                int col = ct * 16 + l15;
                float add = (ct < 9 && col < DHV) ? dba[col] : 0.f;
                PQb[(size_t)node * 288 + col] = f2b(acc[ct][reg] + add);
            }
    }
}

__global__ __launch_bounds__(256) void k_edge(const int* ewi, const bf* PQb,
                                              const float* dWb, const float* dbb, float* out) {
    int wv = (blockIdx.x * blockDim.x + threadIdx.x) >> 6;
    int half = (threadIdx.x >> 5) & 1, l = threadIdx.x & 31;
    int e = wv * 2 + half;
    if (e >= E_DEC) return;
    int src = ewi[e], trg = ewi[E_DEC + e];
    const bf* Pr = PQb + (size_t)src * 288;
    const bf* Qr = PQb + (size_t)trg * 288 + 144;
    float acc;
    {
        uint2 pv = *(const uint2*)(Pr + 4 * l);
        uint2 qv = *(const uint2*)(Qr + 4 * l);
        float4 wv4 = *(const float4*)(dWb + 4 * l);
        float s0 = fmaxf(bflo(pv.x) + bflo(qv.x), 0.f);
        float s1 = fmaxf(bfhi(pv.x) + bfhi(qv.x), 0.f);
        float s2 = fmaxf(bflo(pv.y) + bflo(qv.y), 0.f);
        float s3 = fmaxf(bfhi(pv.y) + bfhi(qv.y), 0.f);
        acc = s0 * wv4.x + s1 * wv4.y + s2 * wv4.z + s3 * wv4.w;
    }
    if (l < 4) {
        int u0 = 128 + 4 * l;
        uint2 pv = *(const uint2*)(Pr + u0);
        uint2 qv = *(const uint2*)(Qr + u0);
        float w0 = dWb[u0], w1 = dWb[u0 + 1], w2 = dWb[u0 + 2];
        float w3 = (u0 + 3 < DHV) ? dWb[u0 + 3] : 0.f;
        acc += fmaxf(bflo(pv.x) + bflo(qv.x), 0.f) * w0;
        acc += fmaxf(bfhi(pv.x) + bfhi(qv.x), 0.f) * w1;
        acc += fmaxf(bflo(pv.y) + bflo(qv.y), 0.f) * w2;
        acc += fmaxf(bfhi(pv.y) + bfhi(qv.y), 0.f) * w3;
    }
#pragma unroll
    for (int off = 16; off > 0; off >>= 1) acc += __shfl_xor(acc, off);
    if (l == 0) out[e] = acc + dbb[0];
}

// ---------------------------------------------------------------------------
extern "C" void kernel_launch(void* const* d_in, const int* in_sizes, int n_in,
                              void* d_out, int out_size, void* d_ws, size_t ws_size,
                              hipStream_t stream) {
    (void)in_sizes; (void)n_in; (void)out_size; (void)ws_size;
    const float* x    = (const float*)d_in[0];
    const float* ea   = (const float*)d_in[1];
    const int*   ei   = (const int*)d_in[2];
    const int*   ewi  = (const int*)d_in[3];
    const float* W1   = (const float*)d_in[4];
    const float* b1   = (const float*)d_in[5];
    const float* g1   = (const float*)d_in[6];
    const float* be1  = (const float*)d_in[7];
    const float* W2   = (const float*)d_in[8];
    const float* b2   = (const float*)d_in[9];
    const float* g2   = (const float*)d_in[10];
    const float* be2  = (const float*)d_in[11];
    const float* Wih1 = (const float*)d_in[12];
    const float* Whh1 = (const float*)d_in[13];
    const float* bih1 = (const float*)d_in[14];
    const float* bhh1 = (const float*)d_in[15];
    const float* Wih2 = (const float*)d_in[16];
    const float* Whh2 = (const float*)d_in[17];
    const float* bih2 = (const float*)d_in[18];
    const float* bhh2 = (const float*)d_in[19];
    const float* dWa  = (const float*)d_in[20];
    const float* dba  = (const float*)d_in[21];
    const float* dWb  = (const float*)d_in[22];
    const float* dbb  = (const float*)d_in[23];
    float* out = (float*)d_out;

    const size_t NSB = (size_t)N_BIG * 64;
    const size_t NS  = (size_t)N_NODES * 64;
    char* base = (char*)d_ws;
    size_t o = 0;
    float* dis  = (float*)(base + o); o += (size_t)N_BIG * 4;
    bf* aggb    = (bf*)(base + o);    o += NSB * 2;                // neb/PQb alias region
    bf* hbufb   = (bf*)(base + o);    o += NSB * 2;
    bf* h1b     = (bf*)(base + o);    o += NSB * 2;
    bf* h2b     = (bf*)(base + o);    o += NSB * 2;
    bf* hs1     = (bf*)(base + o);    o += NS * 2;
    bf* hs2     = (bf*)(base + o);    o += NS * 2;
    bf* B1f     = (bf*)(base + o);    o += (size_t)16 * 6 * 64 * 8 * 2;
    bf* B2f     = (bf*)(base + o);    o += (size_t)16 * 4 * 64 * 8 * 2;
    bf* W2t     = (bf*)(base + o);    o += 64 * 64 * 2;
    float* bc1  = (float*)(base + o); o += 256 * 4;
    float* bc2  = (float*)(base + o); o += 256 * 4;
    bf* Bpqf    = (bf*)(base + o);    o += (size_t)18 * 5 * 64 * 8 * 2;
    float* stats= (float*)(base + o); o += 256 * 4;
    float* w2b  = (float*)(base + o); o += 64 * 4;
    float* AC   = (float*)(base + o); o += 128 * 4;
    float* bc1f = (float*)(base + o); o += 256 * 4;
    int* cnt    = (int*)(base + o);   o += (size_t)N_BIG * 4;
    int* ovfn   = (int*)(base + o);   o += 256;
    float4* ovf = (float4*)(base + o); o += (size_t)OVF_CAP * 16;
    float2* bucket = (float2*)(base + o); o += (size_t)N_BIG * CAP * 8;   // 41 MB
    bf* neb = aggb;                          // 20032 x 160 bf16
    bf* PQb = aggb + (size_t)20032 * 160;    // 20000 x 288 bf16

    // ---- prep + direct bucket build (fused with x@W1) ----
    k_prep<<<512, 256, 0, stream>>>(Wih2, Whh2, bih1, bhh1, bih2, bhh2, dWa,
                                    cnt, ovfn, B2f, bc1, bc2, Bpqf, stats);
    k_fill_xw1<<<6250 + 40000, 256, 0, stream>>>(ei, ea, x, W1, cnt, bucket, ovfn, ovf, hbufb);
    k_disscale<<<N_BIG / 8, 256, 0, stream>>>(cnt, bucket, ovfn, ovf, dis, hbufb);

    // ---- GCN layer 1 (raw relu out; BN folded downstream) ----
    k_gcn_gather<<<N_BIG / 8, 256, 0, stream>>>(hbufb, dis, cnt, bucket, ovfn, ovf, b1, h1b);
    k_bnstats<<<256, 256, 0, stream>>>(h1b, stats, stats + 64);
    k_fold1<<<1, 256, 0, stream>>>(W2, g1, be1, stats, W2t, w2b, AC);

    // ---- GCN layer 2 ----
    k_h1w2<<<2500, 256, 0, stream>>>(h1b, W2t, w2b, dis, hbufb);
    k_gcn_gather<<<N_BIG / 8, 256, 0, stream>>>(hbufb, dis, cnt, bucket, ovfn, ovf, b2, h2b);
    k_bnstats<<<256, 256, 0, stream>>>(h2b, stats + 128, stats + 192);
    k_fold2<<<64, 256, 0, stream>>>(Wih1, Whh1, g2, be2, stats, AC, bc1, B1f, bc1f);

    // ---- both LSTMs, all 8 steps, one launch ----
    k_lstm_fused<<<625, 256, 0, stream>>>(h1b, h2b, B1f, B2f, bc1f, bc2, hs1, hs2);

    // ---- node embeddings + decoder ----
    k_nodeemb<<<12500, 256, 0, stream>>>(hs1, hs2, x, neb);
    k_pq<<<313, 256, 0, stream>>>(neb, Bpqf, dba, PQb);
    k_edge<<<E_DEC / 8, 256, 0, stream>>>(ewi, PQb, dWb, dbb, out);
}

// Round 13
// 638.928 us; speedup vs baseline: 3.0105x; 1.0773x over previous
//
#include <hip/hip_runtime.h>
#include <hip/hip_bf16.h>

#define IN_C 8
#define HID 64
#define N_NODES 20000
#define WINDOW 8
#define N_BIG 160000
#define NE 1600000
#define E_DEC 500000
#define DHV 143
#define EPSV 1e-5f
#define CAP 32
#define OVF_CAP 4096
#define NER 168   // padded LDS row stride (shorts) for the pq embedding tile

typedef __hip_bfloat16 bf;
typedef __attribute__((ext_vector_type(8))) short short8;
typedef __attribute__((ext_vector_type(4))) float float4_;

__device__ __forceinline__ float b2f(bf v) { return __bfloat162float(v); }
__device__ __forceinline__ bf f2b(float v) { return __float2bfloat16(v); }
__device__ __forceinline__ float bflo(unsigned int u) { return __uint_as_float(u << 16); }
__device__ __forceinline__ float bfhi(unsigned int u) { return __uint_as_float(u & 0xffff0000u); }
__device__ __forceinline__ unsigned int packbf2(float lo, float hi) {
    unsigned int ul = __bfloat16_as_ushort(f2b(lo));
    unsigned int uh = __bfloat16_as_ushort(f2b(hi));
    return ul | (uh << 16);
}
__device__ __forceinline__ float sigf(float x) {
    return __builtin_amdgcn_rcpf(1.f + __expf(-x));
}
__device__ __forceinline__ float tanhfast(float x) {
    x = fminf(fmaxf(x, -15.f), 15.f);
    float e = __expf(2.f * x);
    return (e - 1.f) * __builtin_amdgcn_rcpf(e + 1.f);
}

// ---------------------------------------------------------------- prep ------
__global__ void k_prep(const float* Wih2, const float* Whh2, const float* bih1, const float* bhh1,
                       const float* bih2, const float* bhh2, const float* dWa,
                       int* cnt, int* ovfn, bf* B2f, float* bc1, float* bc2, bf* Bpqf, float* stats)
{
    int i0 = blockIdx.x * blockDim.x + threadIdx.x;
    int stride = gridDim.x * blockDim.x;
    for (int i = i0; i < N_BIG; i += stride) cnt[i] = 0;
    if (i0 == 0) *ovfn = 0;
    for (int i = i0; i < 16 * 4 * 64 * 8; i += stride) {   // B2 fragments (K=128)
        int j = i & 7, lane = (i >> 3) & 63, r = i >> 9;
        int c = r & 3, ct = r >> 2;
        int q = lane >> 4, l15 = lane & 15;
        int n = ct * 16 + l15, k = c * 32 + q * 8 + j;
        B2f[i] = f2b((k < 64) ? Wih2[n * 64 + k] : Whh2[n * 64 + (k - 64)]);
    }
    for (int i = i0; i < 256; i += stride) {
        bc1[i] = bih1[i] + bhh1[i];
        bc2[i] = bih2[i] + bhh2[i];
    }
    for (int i = i0; i < 18 * 5 * 64 * 8; i += stride) {   // decoder fragments
        int j = i & 7, lane = (i >> 3) & 63, r = i >> 9;
        int c = r % 5, ct = r / 5;
        int q = lane >> 4, l15 = lane & 15;
        int n = ct * 16 + l15, k = c * 32 + q * 8 + j;
        float v = 0.f;
        if (k < DHV) {
            if (n < DHV) v = dWa[k * DHV + n];
            else if (n >= 144 && n < 144 + DHV) v = dWa[(DHV + k) * DHV + (n - 144)];
        }
        Bpqf[i] = f2b(v);
    }
    for (int i = i0; i < 256; i += stride) stats[i] = 0.f;
}

// --------------------- direct bucket fill (1 atomic/edge), standalone -------
__global__ __launch_bounds__(256) void k_fill(const int* ei, const float* ea,
                                              int* cnt, float2* bucket, int* ovfn, float4* ovf) {
    int e = blockIdx.x * 256 + threadIdx.x;
    int r = ei[e], c = ei[NE + e];
    float a = ea[e];
    int p = atomicAdd(&cnt[c], 1);
    if (p < CAP) bucket[(size_t)c * CAP + p] = make_float2(__int_as_float(r), a);
    else {
        int q = atomicAdd(ovfn, 1);
        if (q < OVF_CAP) ovf[q] = make_float4(__int_as_float(c), __int_as_float(r), a, 0.f);
    }
}

// ------------------------------------------------------------ x @ W1 --------
__global__ __launch_bounds__(256) void k_xw1(const float* x, const float* W1, bf* hbufb) {
    __shared__ float Ws[IN_C * HID];
    __shared__ float xs[4][IN_C];
    int tid = threadIdx.x;
    Ws[tid] = W1[tid];
    Ws[tid + 256] = W1[tid + 256];
    int node0 = blockIdx.x * 4;
    if (tid < 32) xs[tid >> 3][tid & 7] = x[node0 * IN_C + tid];
    __syncthreads();
    int ch = tid & 63, ns = tid >> 6;
    float acc = 0.f;
#pragma unroll
    for (int c = 0; c < IN_C; c++) acc += xs[ns][c] * Ws[c * 64 + ch];
    hbufb[(size_t)(node0 + ns) * 64 + ch] = f2b(acc);
}

// ------------- deg from buckets -> dis; scale h row in place (h' = dis*h) ---
__global__ __launch_bounds__(256) void k_disscale(const int* cnt, const float2* bucket,
                                                  const int* ovfn, const float4* ovf,
                                                  float* dis, bf* h) {
    int wv = (blockIdx.x * blockDim.x + threadIdx.x) >> 6;
    int half = (threadIdx.x >> 5) & 1, l = threadIdx.x & 31;
    int c = wv * 2 + half;
    if (c >= N_BIG) return;
    int n = cnt[c];
    int nb = (n < CAP) ? n : CAP;
    float s = 0.f;
    for (int i = l; i < nb; i += 32) s += bucket[(size_t)c * CAP + i].y;
    if (n > CAP) {
        int m = *ovfn; if (m > OVF_CAP) m = OVF_CAP;
        for (int i = l; i < m; i += 32) {
            float4 v = ovf[i];
            if (__float_as_int(v.x) == c) s += v.z;
        }
    }
#pragma unroll
    for (int off = 16; off > 0; off >>= 1) s += __shfl_xor(s, off);
    float deg = 1.f + s;
    float dv = rsqrtf(fmaxf(deg, EPSV));
    if (l == 0) dis[c] = dv;
    unsigned int hv = *(const unsigned int*)(h + (size_t)c * 64 + 2 * l);
    *(unsigned int*)(h + (size_t)c * 64 + 2 * l) = packbf2(dv * bflo(hv), dv * bfhi(hv));
}

// ---------------- GCN aggregation (bucket gather) + fused BN partial stats --
// agg_c = relu( dis_c * (h'_c + sum ea*h'_r) + bias );  h' pre-scaled by dis_r
// Block = 8 nodes; per-block per-channel (sum, sumsq) partials -> part[128].
__global__ __launch_bounds__(256) void k_gcn_gather(const bf* h, const float* dis, const int* cnt,
                             const float2* bucket, const int* ovfn, const float4* ovf,
                             const float* bias, bf* outb, float* part) {
    __shared__ float4 red[256];
    int tid = threadIdx.x;
    int wv = (blockIdx.x * 256 + tid) >> 6;
    int half = (tid >> 5) & 1, l = tid & 31;
    int c = wv * 2 + half;                 // grid exact: c < N_BIG always
    unsigned int hv = *(const unsigned int*)(h + (size_t)c * 64 + 2 * l);
    float ax = bflo(hv), ay = bfhi(hv);
    size_t o = (size_t)c * CAP;
    int nfull = cnt[c];
    int n = (nfull < CAP) ? nfull : CAP;
    int e = 0;
    for (; e + 8 <= n; e += 8) {
        float2 p[8];
#pragma unroll
        for (int j = 0; j < 8; j++) p[j] = bucket[o + e + j];
        unsigned int v[8];
#pragma unroll
        for (int j = 0; j < 8; j++)
            v[j] = *(const unsigned int*)(h + (size_t)__float_as_int(p[j].x) * 64 + 2 * l);
#pragma unroll
        for (int j = 0; j < 8; j++) { ax += p[j].y * bflo(v[j]); ay += p[j].y * bfhi(v[j]); }
    }
    for (; e + 4 <= n; e += 4) {
        float2 p[4];
#pragma unroll
        for (int j = 0; j < 4; j++) p[j] = bucket[o + e + j];
        unsigned int v[4];
#pragma unroll
        for (int j = 0; j < 4; j++)
            v[j] = *(const unsigned int*)(h + (size_t)__float_as_int(p[j].x) * 64 + 2 * l);
#pragma unroll
        for (int j = 0; j < 4; j++) { ax += p[j].y * bflo(v[j]); ay += p[j].y * bfhi(v[j]); }
    }
    for (; e < n; e++) {
        float2 p = bucket[o + e];
        unsigned int v = *(const unsigned int*)(h + (size_t)__float_as_int(p.x) * 64 + 2 * l);
        ax += p.y * bflo(v);
        ay += p.y * bfhi(v);
    }
    if (nfull > CAP) {      // practically never
        int m = *ovfn; if (m > OVF_CAP) m = OVF_CAP;
        for (int i = 0; i < m; i++) {
            float4 v = ovf[i];
            if (__float_as_int(v.x) == c) {
                unsigned int hw = *(const unsigned int*)(h + (size_t)__float_as_int(v.y) * 64 + 2 * l);
                ax += v.z * bflo(hw);
                ay += v.z * bfhi(hw);
            }
        }
    }
    float dv = dis[c];
    float2 bv = *(const float2*)(bias + 2 * l);
    float vx = fmaxf(dv * ax + bv.x, 0.f);
    float vy = fmaxf(dv * ay + bv.y, 0.f);
    *(unsigned int*)(outb + (size_t)c * 64 + 2 * l) = packbf2(vx, vy);
    // ---- BN partial stats (fp32, pre-round) ----
    red[tid] = make_float4(vx, vy, vx * vx, vy * vy);
    __syncthreads();
    if (tid < 32) {
        float4 s = make_float4(0.f, 0.f, 0.f, 0.f);
#pragma unroll
        for (int i = 0; i < 8; i++) {
            float4 v = red[((i >> 1) << 6) + ((i & 1) << 5) + tid];
            s.x += v.x; s.y += v.y; s.z += v.z; s.w += v.w;
        }
        float* pb = part + (size_t)blockIdx.x * 128;
        pb[2 * tid] = s.x; pb[2 * tid + 1] = s.y;
        pb[64 + 2 * tid] = s.z; pb[64 + 2 * tid + 1] = s.w;
    }
}

// ---------------- reduce per-block BN partials: stats_out[j] = sum part[b][j]
__global__ __launch_bounds__(256) void k_bnred(const float* part, int nblk, float* stats_out) {
    __shared__ float s[256];
    float acc = 0.f;
    for (int b = threadIdx.x; b < nblk; b += 256) acc += part[(size_t)b * 128 + blockIdx.x];
    s[threadIdx.x] = acc;
    __syncthreads();
    for (int off = 128; off; off >>= 1) {
        if (threadIdx.x < off) s[threadIdx.x] += s[threadIdx.x + off];
        __syncthreads();
    }
    if (threadIdx.x == 0) stats_out[blockIdx.x] = s[0];
}

// ------------------------------- fold BN1 affine into W2^T + bias ----------
__global__ __launch_bounds__(256) void k_fold1(const float* W2, const float* g1, const float* be1,
                                               const float* stats, bf* W2t, float* w2b, float* AC) {
    __shared__ float A[64], C[64];
    int tid = threadIdx.x;
    if (tid < 64) {
        float m = stats[tid] * (1.f / (float)N_BIG);
        float var = stats[64 + tid] * (1.f / (float)N_BIG) - m * m;
        float a = g1[tid] * rsqrtf(var + EPSV);
        float c = be1[tid] - m * a;
        A[tid] = a; C[tid] = c;
        AC[tid] = a; AC[64 + tid] = c;
    }
    __syncthreads();
    for (int i = tid; i < 4096; i += 256) {
        int n = i >> 6, k = i & 63;
        W2t[i] = f2b(W2[k * 64 + n] * A[k]);
    }
    if (tid < 64) {
        float s = 0.f;
        for (int k = 0; k < 64; k++) s += C[k] * W2[k * 64 + tid];
        w2b[tid] = s;
    }
}

// -------- fold BN1/BN2 affine into LSTM1 weights (B1f fragments) + bias ----
__global__ void k_fold2(const float* Wih1, const float* Whh1,
                        const float* g2, const float* be2, const float* stats,
                        const float* AC, const float* bc1, bf* B1f, float* bc1f) {
    int i0 = blockIdx.x * blockDim.x + threadIdx.x;
    int stride = gridDim.x * blockDim.x;
    for (int i = i0; i < 16 * 6 * 64 * 8; i += stride) {
        int j = i & 7, lane = (i >> 3) & 63, r = i >> 9;
        int c = r % 6, ct = r / 6;
        int q = lane >> 4, l15 = lane & 15;
        int n = ct * 16 + l15, k = c * 32 + q * 8 + j;
        float w = (k < 128) ? Wih1[n * 128 + k] : Whh1[n * 64 + (k - 128)];
        float scale = 1.f;
        if (k < 64) scale = AC[k];
        else if (k < 128) {
            int ch = k - 64;
            float m = stats[128 + ch] * (1.f / (float)N_BIG);
            float var = stats[192 + ch] * (1.f / (float)N_BIG) - m * m;
            scale = g2[ch] * rsqrtf(var + EPSV);
        }
        B1f[i] = f2b(w * scale);
    }
    for (int n = i0; n < 256; n += stride) {
        float s = bc1[n];
        for (int k = 0; k < 64; k++) s += AC[64 + k] * Wih1[n * 128 + k];
        for (int ch = 0; ch < 64; ch++) {
            float m = stats[128 + ch] * (1.f / (float)N_BIG);
            float var = stats[192 + ch] * (1.f / (float)N_BIG) - m * m;
            float a = g2[ch] * rsqrtf(var + EPSV);
            float c2v = be2[ch] - m * a;
            s += c2v * Wih1[n * 128 + 64 + ch];
        }
        bc1f[n] = s;
    }
}

// ------------- h1_raw @ (A1-scaled W2) + w2b, epilogue x dis (bf16 MFMA) ----
__global__ __launch_bounds__(256) void k_h1w2(const bf* h1b, const bf* W2t, const float* w2b,
                                              const float* dis, bf* outb) {
    int tid = threadIdx.x, w = tid >> 6, lane = tid & 63;
    int q = lane >> 4, l15 = lane & 15;
    size_t r0 = (size_t)blockIdx.x * 64 + w * 16;
    float4_ acc[4];
#pragma unroll
    for (int ct = 0; ct < 4; ct++) acc[ct] = (float4_){0.f, 0.f, 0.f, 0.f};
#pragma unroll
    for (int c = 0; c < 2; c++) {
        int koff = c * 32 + q * 8;
        short8 a = *(const short8*)(h1b + (r0 + l15) * 64 + koff);
#pragma unroll
        for (int ct = 0; ct < 4; ct++) {
            short8 b = *(const short8*)(W2t + (size_t)(ct * 16 + l15) * 64 + koff);
            acc[ct] = __builtin_amdgcn_mfma_f32_16x16x32_bf16(a, b, acc[ct], 0, 0, 0);
        }
    }
    size_t node0 = r0 + q * 4;
#pragma unroll
    for (int reg = 0; reg < 4; reg++) {
        float dv = dis[node0 + reg];
#pragma unroll
        for (int ct = 0; ct < 4; ct++)
            outb[(node0 + reg) * 64 + ct * 16 + l15] = f2b(dv * (acc[ct][reg] + w2b[ct * 16 + l15]));
    }
}

// ----------------------------------------- fully fused double LSTM (MFMA) ---
__global__ __launch_bounds__(256, 1) void k_lstm_fused(
    const bf* h1b, const bf* h2b, const bf* B1f, const bf* B2f,
    const float* bc1, const float* bc2, bf* H1out, bf* H2out)
{
    __shared__ bf h1s[2][32][72];
    __shared__ bf h2s[2][32][72];
    int tid = threadIdx.x, w = tid >> 6, lane = tid & 63;
    int q = lane >> 4, l15 = lane & 15;
    int gnode0 = blockIdx.x * 32;
    short8 B1r[6][4];
    short8 B2r[4][4];
#pragma unroll
    for (int c = 0; c < 6; c++)
#pragma unroll
        for (int g = 0; g < 4; g++)
            B1r[c][g] = *(const short8*)(B1f + (size_t)(((w + 4 * g) * 6 + c) * 64 + lane) * 8);
#pragma unroll
    for (int c = 0; c < 4; c++)
#pragma unroll
        for (int g = 0; g < 4; g++)
            B2r[c][g] = *(const short8*)(B2f + (size_t)(((w + 4 * g) * 4 + c) * 64 + lane) * 8);
    float c1[2][4] = {}, c2[2][4] = {};
    float bv1[4], bv2[4];
#pragma unroll
    for (int g = 0; g < 4; g++) {
        bv1[g] = bc1[(w + 4 * g) * 16 + l15];
        bv2[g] = bc2[(w + 4 * g) * 16 + l15];
    }
    short8 Ag[4][2], An[4][2];
#pragma unroll
    for (int c = 0; c < 4; c++) {
        const bf* sp = (c < 2) ? h1b : h2b;
        int koff = (c & 1) * 32 + q * 8;
#pragma unroll
        for (int m = 0; m < 2; m++)
            Ag[c][m] = *(const short8*)(sp + (size_t)(gnode0 + m * 16 + l15) * 64 + koff);
    }
#pragma unroll
    for (int t = 0; t < WINDOW; t++) {
        int cur = t & 1, prv = cur ^ 1;
        float4_ acc[2][4];
#pragma unroll
        for (int m = 0; m < 2; m++)
#pragma unroll
            for (int g = 0; g < 4; g++) acc[m][g] = (float4_){bv1[g], bv1[g], bv1[g], bv1[g]};
#pragma unroll
        for (int c = 0; c < 4; c++)
#pragma unroll
            for (int m = 0; m < 2; m++)
#pragma unroll
                for (int g = 0; g < 4; g++)
                    acc[m][g] = __builtin_amdgcn_mfma_f32_16x16x32_bf16(Ag[c][m], B1r[c][g], acc[m][g], 0, 0, 0);
        if (t < WINDOW - 1) {
            const size_t toff2 = (size_t)(t + 1) * N_NODES * 64;
#pragma unroll
            for (int c = 0; c < 4; c++) {
                const bf* sp = (c < 2) ? h1b + toff2 : h2b + toff2;
                int koff = (c & 1) * 32 + q * 8;
#pragma unroll
                for (int m = 0; m < 2; m++)
                    An[c][m] = *(const short8*)(sp + (size_t)(gnode0 + m * 16 + l15) * 64 + koff);
            }
        }
        if (t > 0) {
#pragma unroll
            for (int c = 4; c < 6; c++) {
                int koff = (c & 1) * 32 + q * 8;
#pragma unroll
                for (int m = 0; m < 2; m++) {
                    short8 a = *(const short8*)&h1s[prv][m * 16 + l15][koff];
#pragma unroll
                    for (int g = 0; g < 4; g++)
                        acc[m][g] = __builtin_amdgcn_mfma_f32_16x16x32_bf16(a, B1r[c][g], acc[m][g], 0, 0, 0);
                }
            }
        }
#pragma unroll
        for (int m = 0; m < 2; m++)
#pragma unroll
            for (int reg = 0; reg < 4; reg++) {
                float gi = acc[m][0][reg], gf = acc[m][1][reg];
                float gg = acc[m][2][reg], go = acc[m][3][reg];
                float co = (t == 0) ? 0.f : c1[m][reg];
                float cn = sigf(gf) * co + sigf(gi) * tanhfast(gg);
                float hn = sigf(go) * tanhfast(cn);
                c1[m][reg] = cn;
                int nl = m * 16 + q * 4 + reg;
                h1s[cur][nl][w * 16 + l15] = f2b(hn);
                if (t == WINDOW - 1)
                    H1out[(size_t)(gnode0 + nl) * 64 + w * 16 + l15] = f2b(hn);
            }
        __syncthreads();
#pragma unroll
        for (int m = 0; m < 2; m++)
#pragma unroll
            for (int g = 0; g < 4; g++) acc[m][g] = (float4_){bv2[g], bv2[g], bv2[g], bv2[g]};
#pragma unroll
        for (int c = 0; c < 2; c++) {
            int koff = (c & 1) * 32 + q * 8;
#pragma unroll
            for (int m = 0; m < 2; m++) {
                short8 a = *(const short8*)&h1s[cur][m * 16 + l15][koff];
#pragma unroll
                for (int g = 0; g < 4; g++)
                    acc[m][g] = __builtin_amdgcn_mfma_f32_16x16x32_bf16(a, B2r[c][g], acc[m][g], 0, 0, 0);
            }
        }
        if (t > 0) {
#pragma unroll
            for (int c = 2; c < 4; c++) {
                int koff = (c & 1) * 32 + q * 8;
#pragma unroll
                for (int m = 0; m < 2; m++) {
                    short8 a = *(const short8*)&h2s[prv][m * 16 + l15][koff];
#pragma unroll
                    for (int g = 0; g < 4; g++)
                        acc[m][g] = __builtin_amdgcn_mfma_f32_16x16x32_bf16(a, B2r[c][g], acc[m][g], 0, 0, 0);
                }
            }
        }
#pragma unroll
        for (int m = 0; m < 2; m++)
#pragma unroll
            for (int reg = 0; reg < 4; reg++) {
                float gi = acc[m][0][reg], gf = acc[m][1][reg];
                float gg = acc[m][2][reg], go = acc[m][3][reg];
                float co = (t == 0) ? 0.f : c2[m][reg];
                float cn = sigf(gf) * co + sigf(gi) * tanhfast(gg);
                float hn = sigf(go) * tanhfast(cn);
                c2[m][reg] = cn;
                int nl = m * 16 + q * 4 + reg;
                h2s[cur][nl][w * 16 + l15] = f2b(hn);
                if (t == WINDOW - 1)
                    H2out[(size_t)(gnode0 + nl) * 64 + w * 16 + l15] = f2b(hn);
            }
        __syncthreads();
#pragma unroll
        for (int c = 0; c < 4; c++)
#pragma unroll
            for (int m = 0; m < 2; m++) Ag[c][m] = An[c][m];
    }
}

// ------------- PQ = nodeemb @ Bpq, nodeemb built in LDS (fused) -------------
// Block = 64 rows; LDS tile 64 x NER shorts; dba folded into P block.
__global__ __launch_bounds__(256) void k_pq(const bf* H1, const bf* H2, const float* x,
                                            const bf* Bpqf, const float* dba, bf* PQb) {
    __shared__ bf ne[64][NER];
    int tid = threadIdx.x, w = tid >> 6, lane = tid & 63;
    int q = lane >> 4, l15 = lane & 15;
    int r0 = blockIdx.x * 64;
    // stage H1 -> cols 0..63, H2 -> cols 64..127 (8B chunks)
    for (int i = tid; i < 64 * 16; i += 256) {
        int rr = i >> 4, cc = (i & 15) * 4;
        int gr = r0 + rr;
        uint2 v1 = make_uint2(0u, 0u), v2 = make_uint2(0u, 0u);
        if (gr < N_NODES) {
            v1 = *(const uint2*)(H1 + (size_t)gr * 64 + cc);
            v2 = *(const uint2*)(H2 + (size_t)gr * 64 + cc);
        }
        *(uint2*)&ne[rr][cc] = v1;
        *(uint2*)&ne[rr][64 + cc] = v2;
    }
    // skip features cols 128..159 (143..159 zero)
    for (int i = tid; i < 64 * 32; i += 256) {
        int rr = i >> 5, cc = 128 + (i & 31);
        int gr = r0 + rr;
        float v = 0.f;
        if (gr < N_NODES && cc < DHV) {
            int s = cc - 128;
            v = (s < 8) ? x[gr * IN_C + s] : x[(size_t)((s - 7) * N_NODES + gr) * IN_C + 7];
        }
        ne[rr][cc] = f2b(v);
    }
    __syncthreads();
    float4_ acc[18];
#pragma unroll
    for (int ct = 0; ct < 18; ct++) acc[ct] = (float4_){0.f, 0.f, 0.f, 0.f};
#pragma unroll
    for (int c = 0; c < 5; c++) {
        short8 a = *(const short8*)&ne[w * 16 + l15][c * 32 + q * 8];
#pragma unroll
        for (int ct = 0; ct < 18; ct++) {
            short8 b = *(const short8*)(Bpqf + (size_t)((ct * 5 + c) * 64 + lane) * 8);
            acc[ct] = __builtin_amdgcn_mfma_f32_16x16x32_bf16(a, b, acc[ct], 0, 0, 0);
        }
    }
#pragma unroll
    for (int reg = 0; reg < 4; reg++) {
        int node = r0 + w * 16 + 0;   // node base for this wave
        int nrow = r0 + w * 16 + q * 4 + reg;
        (void)node;
        if (nrow < N_NODES)
#pragma unroll
            for (int ct = 0; ct < 18; ct++) {
                int col = ct * 16 + l15;
                float add = (ct < 9 && col < DHV) ? dba[col] : 0.f;
                PQb[(size_t)nrow * 288 + col] = f2b(acc[ct][reg] + add);
            }
    }
}

// decoder: 2 edges/wave, 32 lanes/edge, 8B loads; P' already has +dba
__global__ __launch_bounds__(256) void k_edge(const int* ewi, const bf* PQb,
                                              const float* dWb, const float* dbb, float* out) {
    int wv = (blockIdx.x * blockDim.x + threadIdx.x) >> 6;
    int half = (threadIdx.x >> 5) & 1, l = threadIdx.x & 31;
    int e = wv * 2 + half;
    if (e >= E_DEC) return;
    int src = ewi[e], trg = ewi[E_DEC + e];
    const bf* Pr = PQb + (size_t)src * 288;
    const bf* Qr = PQb + (size_t)trg * 288 + 144;
    float acc;
    {
        uint2 pv = *(const uint2*)(Pr + 4 * l);
        uint2 qv = *(const uint2*)(Qr + 4 * l);
        float4 wv4 = *(const float4*)(dWb + 4 * l);
        float s0 = fmaxf(bflo(pv.x) + bflo(qv.x), 0.f);
        float s1 = fmaxf(bfhi(pv.x) + bfhi(qv.x), 0.f);
        float s2 = fmaxf(bflo(pv.y) + bflo(qv.y), 0.f);
        float s3 = fmaxf(bfhi(pv.y) + bfhi(qv.y), 0.f);
        acc = s0 * wv4.x + s1 * wv4.y + s2 * wv4.z + s3 * wv4.w;
    }
    if (l < 4) {
        int u0 = 128 + 4 * l;
        uint2 pv = *(const uint2*)(Pr + u0);
        uint2 qv = *(const uint2*)(Qr + u0);
        float w0 = dWb[u0], w1 = dWb[u0 + 1], w2 = dWb[u0 + 2];
        float w3 = (u0 + 3 < DHV) ? dWb[u0 + 3] : 0.f;
        acc += fmaxf(bflo(pv.x) + bflo(qv.x), 0.f) * w0;
        acc += fmaxf(bfhi(pv.x) + bfhi(qv.x), 0.f) * w1;
        acc += fmaxf(bflo(pv.y) + bflo(qv.y), 0.f) * w2;
        acc += fmaxf(bfhi(pv.y) + bfhi(qv.y), 0.f) * w3;
    }
#pragma unroll
    for (int off = 16; off > 0; off >>= 1) acc += __shfl_xor(acc, off);
    if (l == 0) out[e] = acc + dbb[0];
}

// ---------------------------------------------------------------------------
extern "C" void kernel_launch(void* const* d_in, const int* in_sizes, int n_in,
                              void* d_out, int out_size, void* d_ws, size_t ws_size,
                              hipStream_t stream) {
    (void)in_sizes; (void)n_in; (void)out_size; (void)ws_size;
    const float* x    = (const float*)d_in[0];
    const float* ea   = (const float*)d_in[1];
    const int*   ei   = (const int*)d_in[2];
    const int*   ewi  = (const int*)d_in[3];
    const float* W1   = (const float*)d_in[4];
    const float* b1   = (const float*)d_in[5];
    const float* g1   = (const float*)d_in[6];
    const float* be1  = (const float*)d_in[7];
    const float* W2   = (const float*)d_in[8];
    const float* b2   = (const float*)d_in[9];
    const float* g2   = (const float*)d_in[10];
    const float* be2  = (const float*)d_in[11];
    const float* Wih1 = (const float*)d_in[12];
    const float* Whh1 = (const float*)d_in[13];
    const float* bih1 = (const float*)d_in[14];
    const float* bhh1 = (const float*)d_in[15];
    const float* Wih2 = (const float*)d_in[16];
    const float* Whh2 = (const float*)d_in[17];
    const float* bih2 = (const float*)d_in[18];
    const float* bhh2 = (const float*)d_in[19];
    const float* dWa  = (const float*)d_in[20];
    const float* dba  = (const float*)d_in[21];
    const float* dWb  = (const float*)d_in[22];
    const float* dbb  = (const float*)d_in[23];
    float* out = (float*)d_out;

    const size_t NSB = (size_t)N_BIG * 64;
    const size_t NS  = (size_t)N_NODES * 64;
    char* base = (char*)d_ws;
    size_t o = 0;
    float* dis  = (float*)(base + o); o += (size_t)N_BIG * 4;
    bf* PQb     = (bf*)(base + o);    o += NSB * 2;                // PQb lives here
    bf* hbufb   = (bf*)(base + o);    o += NSB * 2;
    bf* h1b     = (bf*)(base + o);    o += NSB * 2;
    bf* h2b     = (bf*)(base + o);    o += NSB * 2;
    bf* hs1     = (bf*)(base + o);    o += NS * 2;
    bf* hs2     = (bf*)(base + o);    o += NS * 2;
    bf* B1f     = (bf*)(base + o);    o += (size_t)16 * 6 * 64 * 8 * 2;
    bf* B2f     = (bf*)(base + o);    o += (size_t)16 * 4 * 64 * 8 * 2;
    bf* W2t     = (bf*)(base + o);    o += 64 * 64 * 2;
    float* bc1  = (float*)(base + o); o += 256 * 4;
    float* bc2  = (float*)(base + o); o += 256 * 4;
    bf* Bpqf    = (bf*)(base + o);    o += (size_t)18 * 5 * 64 * 8 * 2;
    float* stats= (float*)(base + o); o += 256 * 4;
    float* w2b  = (float*)(base + o); o += 64 * 4;
    float* AC   = (float*)(base + o); o += 128 * 4;
    float* bc1f = (float*)(base + o); o += 256 * 4;
    int* cnt    = (int*)(base + o);   o += (size_t)N_BIG * 4;
    int* ovfn   = (int*)(base + o);   o += 256;
    float4* ovf = (float4*)(base + o); o += (size_t)OVF_CAP * 16;
    float2* bucket = (float2*)(base + o); o += (size_t)N_BIG * CAP * 8;   // 41 MB
    float* part = (float*)(base + o); o += (size_t)20000 * 128 * 4;       // 10.24 MB

    // ---- prep + direct bucket build ----
    k_prep<<<512, 256, 0, stream>>>(Wih2, Whh2, bih1, bhh1, bih2, bhh2, dWa,
                                    cnt, ovfn, B2f, bc1, bc2, Bpqf, stats);
    k_fill<<<6250, 256, 0, stream>>>(ei, ea, cnt, bucket, ovfn, ovf);
    k_xw1<<<N_BIG / 4, 256, 0, stream>>>(x, W1, hbufb);
    k_disscale<<<N_BIG / 8, 256, 0, stream>>>(cnt, bucket, ovfn, ovf, dis, hbufb);

    // ---- GCN layer 1 (raw relu out; BN stats fused into gather) ----
    k_gcn_gather<<<N_BIG / 8, 256, 0, stream>>>(hbufb, dis, cnt, bucket, ovfn, ovf, b1, h1b, part);
    k_bnred<<<128, 256, 0, stream>>>(part, 20000, stats);
    k_fold1<<<1, 256, 0, stream>>>(W2, g1, be1, stats, W2t, w2b, AC);

    // ---- GCN layer 2 ----
    k_h1w2<<<2500, 256, 0, stream>>>(h1b, W2t, w2b, dis, hbufb);
    k_gcn_gather<<<N_BIG / 8, 256, 0, stream>>>(hbufb, dis, cnt, bucket, ovfn, ovf, b2, h2b, part);
    k_bnred<<<128, 256, 0, stream>>>(part, 20000, stats + 128);
    k_fold2<<<64, 256, 0, stream>>>(Wih1, Whh1, g2, be2, stats, AC, bc1, B1f, bc1f);

    // ---- both LSTMs, all 8 steps, one launch ----
    k_lstm_fused<<<625, 256, 0, stream>>>(h1b, h2b, B1f, B2f, bc1f, bc2, hs1, hs2);

    // ---- decoder (nodeemb fused into pq) ----
    k_pq<<<313, 256, 0, stream>>>(hs1, hs2, x, Bpqf, dba, PQb);
    k_edge<<<E_DEC / 8, 256, 0, stream>>>(ewi, PQb, dWb, dbb, out);
}

// Round 14
// 619.873 us; speedup vs baseline: 3.1030x; 1.0307x over previous
//
#include <hip/hip_runtime.h>
#include <hip/hip_bf16.h>

#define IN_C 8
#define HID 64
#define N_NODES 20000
#define WINDOW 8
#define N_BIG 160000
#define NE 1600000
#define E_DEC 500000
#define DHV 143
#define EPSV 1e-5f
#define CAP 32
#define OVF_CAP 4096
#define NER 168   // padded LDS row stride (shorts) for the pq embedding tile
#define QS 16384.0f
#define IQS (1.0f / 16384.0f)

typedef __hip_bfloat16 bf;
typedef __attribute__((ext_vector_type(8))) short short8;
typedef __attribute__((ext_vector_type(4))) float float4_;

__device__ __forceinline__ float b2f(bf v) { return __bfloat162float(v); }
__device__ __forceinline__ bf f2b(float v) { return __float2bfloat16(v); }
__device__ __forceinline__ float bflo(unsigned int u) { return __uint_as_float(u << 16); }
__device__ __forceinline__ float bfhi(unsigned int u) { return __uint_as_float(u & 0xffff0000u); }
__device__ __forceinline__ unsigned int packbf2(float lo, float hi) {
    unsigned int ul = __bfloat16_as_ushort(f2b(lo));
    unsigned int uh = __bfloat16_as_ushort(f2b(hi));
    return ul | (uh << 16);
}
__device__ __forceinline__ float sigf(float x) {
    return __builtin_amdgcn_rcpf(1.f + __expf(-x));
}
__device__ __forceinline__ float tanhfast(float x) {
    x = fminf(fmaxf(x, -15.f), 15.f);
    float e = __expf(2.f * x);
    return (e - 1.f) * __builtin_amdgcn_rcpf(e + 1.f);
}

// ---------------------------------------------------------------- prep ------
__global__ void k_prep(const float* Wih2, const float* Whh2, const float* bih1, const float* bhh1,
                       const float* bih2, const float* bhh2, const float* dWa,
                       int* cnt, int* ovfn, bf* B2f, float* bc1, float* bc2, bf* Bpqf, float* stats)
{
    int i0 = blockIdx.x * blockDim.x + threadIdx.x;
    int stride = gridDim.x * blockDim.x;
    for (int i = i0; i < N_BIG; i += stride) cnt[i] = 0;
    if (i0 == 0) *ovfn = 0;
    for (int i = i0; i < 16 * 4 * 64 * 8; i += stride) {   // B2 fragments (K=128)
        int j = i & 7, lane = (i >> 3) & 63, r = i >> 9;
        int c = r & 3, ct = r >> 2;
        int q = lane >> 4, l15 = lane & 15;
        int n = ct * 16 + l15, k = c * 32 + q * 8 + j;
        B2f[i] = f2b((k < 64) ? Wih2[n * 64 + k] : Whh2[n * 64 + (k - 64)]);
    }
    for (int i = i0; i < 256; i += stride) {
        bc1[i] = bih1[i] + bhh1[i];
        bc2[i] = bih2[i] + bhh2[i];
    }
    for (int i = i0; i < 18 * 5 * 64 * 8; i += stride) {   // decoder fragments
        int j = i & 7, lane = (i >> 3) & 63, r = i >> 9;
        int c = r % 5, ct = r / 5;
        int q = lane >> 4, l15 = lane & 15;
        int n = ct * 16 + l15, k = c * 32 + q * 8 + j;
        float v = 0.f;
        if (k < DHV) {
            if (n < DHV) v = dWa[k * DHV + n];
            else if (n >= 144 && n < 144 + DHV) v = dWa[(DHV + k) * DHV + (n - 144)];
        }
        Bpqf[i] = f2b(v);
    }
    for (int i = i0; i < 256; i += stride) stats[i] = 0.f;
}

// ------------- direct bucket fill (1 atomic/edge), u32-packed entries -------
// entry = (r << 14) | q14(ea);  bucket footprint 20.5 MB (fits aggregate L2)
__global__ __launch_bounds__(256) void k_fill(const int* ei, const float* ea,
                                              int* cnt, unsigned int* bucket,
                                              int* ovfn, float4* ovf) {
    int e = blockIdx.x * 256 + threadIdx.x;
    int r = ei[e], c = ei[NE + e];
    float a = ea[e];
    unsigned int q = (unsigned int)(a * QS + 0.5f);
    if (q > 16383u) q = 16383u;
    int p = atomicAdd(&cnt[c], 1);
    if (p < CAP) bucket[(size_t)c * CAP + p] = ((unsigned int)r << 14) | q;
    else {
        int qq = atomicAdd(ovfn, 1);
        if (qq < OVF_CAP) ovf[qq] = make_float4(__int_as_float(c), __int_as_float(r), a, 0.f);
    }
}

// ------------------------------------------------------------ x @ W1 --------
__global__ __launch_bounds__(256) void k_xw1(const float* x, const float* W1, bf* hbufb) {
    __shared__ float Ws[IN_C * HID];
    __shared__ float xs[4][IN_C];
    int tid = threadIdx.x;
    Ws[tid] = W1[tid];
    Ws[tid + 256] = W1[tid + 256];
    int node0 = blockIdx.x * 4;
    if (tid < 32) xs[tid >> 3][tid & 7] = x[node0 * IN_C + tid];
    __syncthreads();
    int ch = tid & 63, ns = tid >> 6;
    float acc = 0.f;
#pragma unroll
    for (int c = 0; c < IN_C; c++) acc += xs[ns][c] * Ws[c * 64 + ch];
    hbufb[(size_t)(node0 + ns) * 64 + ch] = f2b(acc);
}

// ------------- deg from buckets -> dis; scale h row in place (h' = dis*h) ---
__global__ __launch_bounds__(256) void k_disscale(const int* cnt, const unsigned int* bucket,
                                                  const int* ovfn, const float4* ovf,
                                                  float* dis, bf* h) {
    int wv = (blockIdx.x * blockDim.x + threadIdx.x) >> 6;
    int half = (threadIdx.x >> 5) & 1, l = threadIdx.x & 31;
    int c = wv * 2 + half;
    if (c >= N_BIG) return;
    int n = cnt[c];
    int nb = (n < CAP) ? n : CAP;
    float s = 0.f;
    for (int i = l; i < nb; i += 32) s += (float)(bucket[(size_t)c * CAP + i] & 0x3FFFu);
    s *= IQS;
    if (n > CAP) {
        int m = *ovfn; if (m > OVF_CAP) m = OVF_CAP;
        for (int i = l; i < m; i += 32) {
            float4 v = ovf[i];
            if (__float_as_int(v.x) == c) s += v.z;
        }
    }
#pragma unroll
    for (int off = 16; off > 0; off >>= 1) s += __shfl_xor(s, off);
    float deg = 1.f + s;
    float dv = rsqrtf(fmaxf(deg, EPSV));
    if (l == 0) dis[c] = dv;
    unsigned int hv = *(const unsigned int*)(h + (size_t)c * 64 + 2 * l);
    *(unsigned int*)(h + (size_t)c * 64 + 2 * l) = packbf2(dv * bflo(hv), dv * bfhi(hv));
}

// ---------------- GCN aggregation (bucket gather) + fused BN partial stats --
__global__ __launch_bounds__(256) void k_gcn_gather(const bf* h, const float* dis, const int* cnt,
                             const unsigned int* bucket, const int* ovfn, const float4* ovf,
                             const float* bias, bf* outb, float* part) {
    __shared__ float4 red[256];
    int tid = threadIdx.x;
    int wv = (blockIdx.x * 256 + tid) >> 6;
    int half = (tid >> 5) & 1, l = tid & 31;
    int c = wv * 2 + half;                 // grid exact: c < N_BIG always
    unsigned int hv = *(const unsigned int*)(h + (size_t)c * 64 + 2 * l);
    float ax = bflo(hv), ay = bfhi(hv);
    size_t o = (size_t)c * CAP;
    int nfull = cnt[c];
    int n = (nfull < CAP) ? nfull : CAP;
    int e = 0;
    for (; e + 8 <= n; e += 8) {
        unsigned int p[8];
#pragma unroll
        for (int j = 0; j < 8; j++) p[j] = bucket[o + e + j];
        unsigned int v[8];
#pragma unroll
        for (int j = 0; j < 8; j++)
            v[j] = *(const unsigned int*)(h + (size_t)(p[j] >> 14) * 64 + 2 * l);
#pragma unroll
        for (int j = 0; j < 8; j++) {
            float a = (float)(p[j] & 0x3FFFu) * IQS;
            ax += a * bflo(v[j]); ay += a * bfhi(v[j]);
        }
    }
    for (; e + 4 <= n; e += 4) {
        unsigned int p[4];
#pragma unroll
        for (int j = 0; j < 4; j++) p[j] = bucket[o + e + j];
        unsigned int v[4];
#pragma unroll
        for (int j = 0; j < 4; j++)
            v[j] = *(const unsigned int*)(h + (size_t)(p[j] >> 14) * 64 + 2 * l);
#pragma unroll
        for (int j = 0; j < 4; j++) {
            float a = (float)(p[j] & 0x3FFFu) * IQS;
            ax += a * bflo(v[j]); ay += a * bfhi(v[j]);
        }
    }
    for (; e < n; e++) {
        unsigned int p = bucket[o + e];
        unsigned int v = *(const unsigned int*)(h + (size_t)(p >> 14) * 64 + 2 * l);
        float a = (float)(p & 0x3FFFu) * IQS;
        ax += a * bflo(v);
        ay += a * bfhi(v);
    }
    if (nfull > CAP) {      // practically never
        int m = *ovfn; if (m > OVF_CAP) m = OVF_CAP;
        for (int i = 0; i < m; i++) {
            float4 v = ovf[i];
            if (__float_as_int(v.x) == c) {
                unsigned int hw = *(const unsigned int*)(h + (size_t)__float_as_int(v.y) * 64 + 2 * l);
                ax += v.z * bflo(hw);
                ay += v.z * bfhi(hw);
            }
        }
    }
    float dv = dis[c];
    float2 bv = *(const float2*)(bias + 2 * l);
    float vx = fmaxf(dv * ax + bv.x, 0.f);
    float vy = fmaxf(dv * ay + bv.y, 0.f);
    *(unsigned int*)(outb + (size_t)c * 64 + 2 * l) = packbf2(vx, vy);
    // ---- BN partial stats (fp32, pre-round) ----
    red[tid] = make_float4(vx, vy, vx * vx, vy * vy);
    __syncthreads();
    if (tid < 32) {
        float4 s = make_float4(0.f, 0.f, 0.f, 0.f);
#pragma unroll
        for (int i = 0; i < 8; i++) {
            float4 v = red[((i >> 1) << 6) + ((i & 1) << 5) + tid];
            s.x += v.x; s.y += v.y; s.z += v.z; s.w += v.w;
        }
        float* pb = part + (size_t)blockIdx.x * 128;
        pb[2 * tid] = s.x; pb[2 * tid + 1] = s.y;
        pb[64 + 2 * tid] = s.z; pb[64 + 2 * tid + 1] = s.w;
    }
}

// ---------------- reduce per-block BN partials ------------------------------
__global__ __launch_bounds__(256) void k_bnred(const float* part, int nblk, float* stats_out) {
    __shared__ float s[256];
    float acc = 0.f;
    for (int b = threadIdx.x; b < nblk; b += 256) acc += part[(size_t)b * 128 + blockIdx.x];
    s[threadIdx.x] = acc;
    __syncthreads();
    for (int off = 128; off; off >>= 1) {
        if (threadIdx.x < off) s[threadIdx.x] += s[threadIdx.x + off];
        __syncthreads();
    }
    if (threadIdx.x == 0) stats_out[blockIdx.x] = s[0];
}

// ------------------------------- fold BN1 affine into W2^T + bias ----------
__global__ __launch_bounds__(256) void k_fold1(const float* W2, const float* g1, const float* be1,
                                               const float* stats, bf* W2t, float* w2b, float* AC) {
    __shared__ float A[64], C[64];
    int tid = threadIdx.x;
    if (tid < 64) {
        float m = stats[tid] * (1.f / (float)N_BIG);
        float var = stats[64 + tid] * (1.f / (float)N_BIG) - m * m;
        float a = g1[tid] * rsqrtf(var + EPSV);
        float c = be1[tid] - m * a;
        A[tid] = a; C[tid] = c;
        AC[tid] = a; AC[64 + tid] = c;
    }
    __syncthreads();
    for (int i = tid; i < 4096; i += 256) {
        int n = i >> 6, k = i & 63;
        W2t[i] = f2b(W2[k * 64 + n] * A[k]);
    }
    if (tid < 64) {
        float s = 0.f;
        for (int k = 0; k < 64; k++) s += C[k] * W2[k * 64 + tid];
        w2b[tid] = s;
    }
}

// -------- fold BN1/BN2 affine into LSTM1 weights (B1f fragments) + bias ----
__global__ void k_fold2(const float* Wih1, const float* Whh1,
                        const float* g2, const float* be2, const float* stats,
                        const float* AC, const float* bc1, bf* B1f, float* bc1f) {
    int i0 = blockIdx.x * blockDim.x + threadIdx.x;
    int stride = gridDim.x * blockDim.x;
    for (int i = i0; i < 16 * 6 * 64 * 8; i += stride) {
        int j = i & 7, lane = (i >> 3) & 63, r = i >> 9;
        int c = r % 6, ct = r / 6;
        int q = lane >> 4, l15 = lane & 15;
        int n = ct * 16 + l15, k = c * 32 + q * 8 + j;
        float w = (k < 128) ? Wih1[n * 128 + k] : Whh1[n * 64 + (k - 128)];
        float scale = 1.f;
        if (k < 64) scale = AC[k];
        else if (k < 128) {
            int ch = k - 64;
            float m = stats[128 + ch] * (1.f / (float)N_BIG);
            float var = stats[192 + ch] * (1.f / (float)N_BIG) - m * m;
            scale = g2[ch] * rsqrtf(var + EPSV);
        }
        B1f[i] = f2b(w * scale);
    }
    for (int n = i0; n < 256; n += stride) {
        float s = bc1[n];
        for (int k = 0; k < 64; k++) s += AC[64 + k] * Wih1[n * 128 + k];
        for (int ch = 0; ch < 64; ch++) {
            float m = stats[128 + ch] * (1.f / (float)N_BIG);
            float var = stats[192 + ch] * (1.f / (float)N_BIG) - m * m;
            float a = g2[ch] * rsqrtf(var + EPSV);
            float c2v = be2[ch] - m * a;
            s += c2v * Wih1[n * 128 + 64 + ch];
        }
        bc1f[n] = s;
    }
}

// ------------- h1_raw @ (A1-scaled W2) + w2b, epilogue x dis (bf16 MFMA) ----
__global__ __launch_bounds__(256) void k_h1w2(const bf* h1b, const bf* W2t, const float* w2b,
                                              const float* dis, bf* outb) {
    int tid = threadIdx.x, w = tid >> 6, lane = tid & 63;
    int q = lane >> 4, l15 = lane & 15;
    size_t r0 = (size_t)blockIdx.x * 64 + w * 16;
    float4_ acc[4];
#pragma unroll
    for (int ct = 0; ct < 4; ct++) acc[ct] = (float4_){0.f, 0.f, 0.f, 0.f};
#pragma unroll
    for (int c = 0; c < 2; c++) {
        int koff = c * 32 + q * 8;
        short8 a = *(const short8*)(h1b + (r0 + l15) * 64 + koff);
#pragma unroll
        for (int ct = 0; ct < 4; ct++) {
            short8 b = *(const short8*)(W2t + (size_t)(ct * 16 + l15) * 64 + koff);
            acc[ct] = __builtin_amdgcn_mfma_f32_16x16x32_bf16(a, b, acc[ct], 0, 0, 0);
        }
    }
    size_t node0 = r0 + q * 4;
#pragma unroll
    for (int reg = 0; reg < 4; reg++) {
        float dv = dis[node0 + reg];
#pragma unroll
        for (int ct = 0; ct < 4; ct++)
            outb[(node0 + reg) * 64 + ct * 16 + l15] = f2b(dv * (acc[ct][reg] + w2b[ct * 16 + l15]));
    }
}

// ----------------------------------------- fully fused double LSTM (MFMA) ---
__global__ __launch_bounds__(256, 1) void k_lstm_fused(
    const bf* h1b, const bf* h2b, const bf* B1f, const bf* B2f,
    const float* bc1, const float* bc2, bf* H1out, bf* H2out)
{
    __shared__ bf h1s[2][32][72];
    __shared__ bf h2s[2][32][72];
    int tid = threadIdx.x, w = tid >> 6, lane = tid & 63;
    int q = lane >> 4, l15 = lane & 15;
    int gnode0 = blockIdx.x * 32;
    short8 B1r[6][4];
    short8 B2r[4][4];
#pragma unroll
    for (int c = 0; c < 6; c++)
#pragma unroll
        for (int g = 0; g < 4; g++)
            B1r[c][g] = *(const short8*)(B1f + (size_t)(((w + 4 * g) * 6 + c) * 64 + lane) * 8);
#pragma unroll
    for (int c = 0; c < 4; c++)
#pragma unroll
        for (int g = 0; g < 4; g++)
            B2r[c][g] = *(const short8*)(B2f + (size_t)(((w + 4 * g) * 4 + c) * 64 + lane) * 8);
    float c1[2][4] = {}, c2[2][4] = {};
    float bv1[4], bv2[4];
#pragma unroll
    for (int g = 0; g < 4; g++) {
        bv1[g] = bc1[(w + 4 * g) * 16 + l15];
        bv2[g] = bc2[(w + 4 * g) * 16 + l15];
    }
    short8 Ag[4][2], An[4][2];
#pragma unroll
    for (int c = 0; c < 4; c++) {
        const bf* sp = (c < 2) ? h1b : h2b;
        int koff = (c & 1) * 32 + q * 8;
#pragma unroll
        for (int m = 0; m < 2; m++)
            Ag[c][m] = *(const short8*)(sp + (size_t)(gnode0 + m * 16 + l15) * 64 + koff);
    }
#pragma unroll
    for (int t = 0; t < WINDOW; t++) {
        int cur = t & 1, prv = cur ^ 1;
        float4_ acc[2][4];
#pragma unroll
        for (int m = 0; m < 2; m++)
#pragma unroll
            for (int g = 0; g < 4; g++) acc[m][g] = (float4_){bv1[g], bv1[g], bv1[g], bv1[g]};
#pragma unroll
        for (int c = 0; c < 4; c++)
#pragma unroll
            for (int m = 0; m < 2; m++)
#pragma unroll
                for (int g = 0; g < 4; g++)
                    acc[m][g] = __builtin_amdgcn_mfma_f32_16x16x32_bf16(Ag[c][m], B1r[c][g], acc[m][g], 0, 0, 0);
        if (t < WINDOW - 1) {
            const size_t toff2 = (size_t)(t + 1) * N_NODES * 64;
#pragma unroll
            for (int c = 0; c < 4; c++) {
                const bf* sp = (c < 2) ? h1b + toff2 : h2b + toff2;
                int koff = (c & 1) * 32 + q * 8;
#pragma unroll
                for (int m = 0; m < 2; m++)
                    An[c][m] = *(const short8*)(sp + (size_t)(gnode0 + m * 16 + l15) * 64 + koff);
            }
        }
        if (t > 0) {
#pragma unroll
            for (int c = 4; c < 6; c++) {
                int koff = (c & 1) * 32 + q * 8;
#pragma unroll
                for (int m = 0; m < 2; m++) {
                    short8 a = *(const short8*)&h1s[prv][m * 16 + l15][koff];
#pragma unroll
                    for (int g = 0; g < 4; g++)
                        acc[m][g] = __builtin_amdgcn_mfma_f32_16x16x32_bf16(a, B1r[c][g], acc[m][g], 0, 0, 0);
                }
            }
        }
#pragma unroll
        for (int m = 0; m < 2; m++)
#pragma unroll
            for (int reg = 0; reg < 4; reg++) {
                float gi = acc[m][0][reg], gf = acc[m][1][reg];
                float gg = acc[m][2][reg], go = acc[m][3][reg];
                float co = (t == 0) ? 0.f : c1[m][reg];
                float cn = sigf(gf) * co + sigf(gi) * tanhfast(gg);
                float hn = sigf(go) * tanhfast(cn);
                c1[m][reg] = cn;
                int nl = m * 16 + q * 4 + reg;
                h1s[cur][nl][w * 16 + l15] = f2b(hn);
                if (t == WINDOW - 1)
                    H1out[(size_t)(gnode0 + nl) * 64 + w * 16 + l15] = f2b(hn);
            }
        __syncthreads();
#pragma unroll
        for (int m = 0; m < 2; m++)
#pragma unroll
            for (int g = 0; g < 4; g++) acc[m][g] = (float4_){bv2[g], bv2[g], bv2[g], bv2[g]};
#pragma unroll
        for (int c = 0; c < 2; c++) {
            int koff = (c & 1) * 32 + q * 8;
#pragma unroll
            for (int m = 0; m < 2; m++) {
                short8 a = *(const short8*)&h1s[cur][m * 16 + l15][koff];
#pragma unroll
                for (int g = 0; g < 4; g++)
                    acc[m][g] = __builtin_amdgcn_mfma_f32_16x16x32_bf16(a, B2r[c][g], acc[m][g], 0, 0, 0);
            }
        }
        if (t > 0) {
#pragma unroll
            for (int c = 2; c < 4; c++) {
                int koff = (c & 1) * 32 + q * 8;
#pragma unroll
                for (int m = 0; m < 2; m++) {
                    short8 a = *(const short8*)&h2s[prv][m * 16 + l15][koff];
#pragma unroll
                    for (int g = 0; g < 4; g++)
                        acc[m][g] = __builtin_amdgcn_mfma_f32_16x16x32_bf16(a, B2r[c][g], acc[m][g], 0, 0, 0);
                }
            }
        }
#pragma unroll
        for (int m = 0; m < 2; m++)
#pragma unroll
            for (int reg = 0; reg < 4; reg++) {
                float gi = acc[m][0][reg], gf = acc[m][1][reg];
                float gg = acc[m][2][reg], go = acc[m][3][reg];
                float co = (t == 0) ? 0.f : c2[m][reg];
                float cn = sigf(gf) * co + sigf(gi) * tanhfast(gg);
                float hn = sigf(go) * tanhfast(cn);
                c2[m][reg] = cn;
                int nl = m * 16 + q * 4 + reg;
                h2s[cur][nl][w * 16 + l15] = f2b(hn);
                if (t == WINDOW - 1)
                    H2out[(size_t)(gnode0 + nl) * 64 + w * 16 + l15] = f2b(hn);
            }
        __syncthreads();
#pragma unroll
        for (int c = 0; c < 4; c++)
#pragma unroll
            for (int m = 0; m < 2; m++) Ag[c][m] = An[c][m];
    }
}

// ------------- PQ = nodeemb @ Bpq, nodeemb built in LDS (fused) -------------
__global__ __launch_bounds__(256) void k_pq(const bf* H1, const bf* H2, const float* x,
                                            const bf* Bpqf, const float* dba, bf* PQb) {
    __shared__ bf ne[64][NER];
    int tid = threadIdx.x, w = tid >> 6, lane = tid & 63;
    int q = lane >> 4, l15 = lane & 15;
    int r0 = blockIdx.x * 64;
    for (int i = tid; i < 64 * 16; i += 256) {
        int rr = i >> 4, cc = (i & 15) * 4;
        int gr = r0 + rr;
        uint2 v1 = make_uint2(0u, 0u), v2 = make_uint2(0u, 0u);
        if (gr < N_NODES) {
            v1 = *(const uint2*)(H1 + (size_t)gr * 64 + cc);
            v2 = *(const uint2*)(H2 + (size_t)gr * 64 + cc);
        }
        *(uint2*)&ne[rr][cc] = v1;
        *(uint2*)&ne[rr][64 + cc] = v2;
    }
    for (int i = tid; i < 64 * 32; i += 256) {
        int rr = i >> 5, cc = 128 + (i & 31);
        int gr = r0 + rr;
        float v = 0.f;
        if (gr < N_NODES && cc < DHV) {
            int s = cc - 128;
            v = (s < 8) ? x[gr * IN_C + s] : x[(size_t)((s - 7) * N_NODES + gr) * IN_C + 7];
        }
        ne[rr][cc] = f2b(v);
    }
    __syncthreads();
    float4_ acc[18];
#pragma unroll
    for (int ct = 0; ct < 18; ct++) acc[ct] = (float4_){0.f, 0.f, 0.f, 0.f};
#pragma unroll
    for (int c = 0; c < 5; c++) {
        short8 a = *(const short8*)&ne[w * 16 + l15][c * 32 + q * 8];
#pragma unroll
        for (int ct = 0; ct < 18; ct++) {
            short8 b = *(const short8*)(Bpqf + (size_t)((ct * 5 + c) * 64 + lane) * 8);
            acc[ct] = __builtin_amdgcn_mfma_f32_16x16x32_bf16(a, b, acc[ct], 0, 0, 0);
        }
    }
#pragma unroll
    for (int reg = 0; reg < 4; reg++) {
        int nrow = r0 + w * 16 + q * 4 + reg;
        if (nrow < N_NODES)
#pragma unroll
            for (int ct = 0; ct < 18; ct++) {
                int col = ct * 16 + l15;
                float add = (ct < 9 && col < DHV) ? dba[col] : 0.f;
                PQb[(size_t)nrow * 288 + col] = f2b(acc[ct][reg] + add);
            }
    }
}

// decoder: 2 edges/wave, 32 lanes/edge, 8B loads; P' already has +dba
__global__ __launch_bounds__(256) void k_edge(const int* ewi, const bf* PQb,
                                              const float* dWb, const float* dbb, float* out) {
    int wv = (blockIdx.x * blockDim.x + threadIdx.x) >> 6;
    int half = (threadIdx.x >> 5) & 1, l = threadIdx.x & 31;
    int e = wv * 2 + half;
    if (e >= E_DEC) return;
    int src = ewi[e], trg = ewi[E_DEC + e];
    const bf* Pr = PQb + (size_t)src * 288;
    const bf* Qr = PQb + (size_t)trg * 288 + 144;
    float acc;
    {
        uint2 pv = *(const uint2*)(Pr + 4 * l);
        uint2 qv = *(const uint2*)(Qr + 4 * l);
        float4 wv4 = *(const float4*)(dWb + 4 * l);
        float s0 = fmaxf(bflo(pv.x) + bflo(qv.x), 0.f);
        float s1 = fmaxf(bfhi(pv.x) + bfhi(qv.x), 0.f);
        float s2 = fmaxf(bflo(pv.y) + bflo(qv.y), 0.f);
        float s3 = fmaxf(bfhi(pv.y) + bfhi(qv.y), 0.f);
        acc = s0 * wv4.x + s1 * wv4.y + s2 * wv4.z + s3 * wv4.w;
    }
    if (l < 4) {
        int u0 = 128 + 4 * l;
        uint2 pv = *(const uint2*)(Pr + u0);
        uint2 qv = *(const uint2*)(Qr + u0);
        float w0 = dWb[u0], w1 = dWb[u0 + 1], w2 = dWb[u0 + 2];
        float w3 = (u0 + 3 < DHV) ? dWb[u0 + 3] : 0.f;
        acc += fmaxf(bflo(pv.x) + bflo(qv.x), 0.f) * w0;
        acc += fmaxf(bfhi(pv.x) + bfhi(qv.x), 0.f) * w1;
        acc += fmaxf(bflo(pv.y) + bflo(qv.y), 0.f) * w2;
        acc += fmaxf(bfhi(pv.y) + bfhi(qv.y), 0.f) * w3;
    }
#pragma unroll
    for (int off = 16; off > 0; off >>= 1) acc += __shfl_xor(acc, off);
    if (l == 0) out[e] = acc + dbb[0];
}

// ---------------------------------------------------------------------------
extern "C" void kernel_launch(void* const* d_in, const int* in_sizes, int n_in,
                              void* d_out, int out_size, void* d_ws, size_t ws_size,
                              hipStream_t stream) {
    (void)in_sizes; (void)n_in; (void)out_size; (void)ws_size;
    const float* x    = (const float*)d_in[0];
    const float* ea   = (const float*)d_in[1];
    const int*   ei   = (const int*)d_in[2];
    const int*   ewi  = (const int*)d_in[3];
    const float* W1   = (const float*)d_in[4];
    const float* b1   = (const float*)d_in[5];
    const float* g1   = (const float*)d_in[6];
    const float* be1  = (const float*)d_in[7];
    const float* W2   = (const float*)d_in[8];
    const float* b2   = (const float*)d_in[9];
    const float* g2   = (const float*)d_in[10];
    const float* be2  = (const float*)d_in[11];
    const float* Wih1 = (const float*)d_in[12];
    const float* Whh1 = (const float*)d_in[13];
    const float* bih1 = (const float*)d_in[14];
    const float* bhh1 = (const float*)d_in[15];
    const float* Wih2 = (const float*)d_in[16];
    const float* Whh2 = (const float*)d_in[17];
    const float* bih2 = (const float*)d_in[18];
    const float* bhh2 = (const float*)d_in[19];
    const float* dWa  = (const float*)d_in[20];
    const float* dba  = (const float*)d_in[21];
    const float* dWb  = (const float*)d_in[22];
    const float* dbb  = (const float*)d_in[23];
    float* out = (float*)d_out;

    const size_t NSB = (size_t)N_BIG * 64;
    const size_t NS  = (size_t)N_NODES * 64;
    char* base = (char*)d_ws;
    size_t o = 0;
    float* dis  = (float*)(base + o); o += (size_t)N_BIG * 4;
    bf* PQb     = (bf*)(base + o);    o += NSB * 2;
    bf* hbufb   = (bf*)(base + o);    o += NSB * 2;
    bf* h1b     = (bf*)(base + o);    o += NSB * 2;
    bf* h2b     = (bf*)(base + o);    o += NSB * 2;
    bf* hs1     = (bf*)(base + o);    o += NS * 2;
    bf* hs2     = (bf*)(base + o);    o += NS * 2;
    bf* B1f     = (bf*)(base + o);    o += (size_t)16 * 6 * 64 * 8 * 2;
    bf* B2f     = (bf*)(base + o);    o += (size_t)16 * 4 * 64 * 8 * 2;
    bf* W2t     = (bf*)(base + o);    o += 64 * 64 * 2;
    float* bc1  = (float*)(base + o); o += 256 * 4;
    float* bc2  = (float*)(base + o); o += 256 * 4;
    bf* Bpqf    = (bf*)(base + o);    o += (size_t)18 * 5 * 64 * 8 * 2;
    float* stats= (float*)(base + o); o += 256 * 4;
    float* w2b  = (float*)(base + o); o += 64 * 4;
    float* AC   = (float*)(base + o); o += 128 * 4;
    float* bc1f = (float*)(base + o); o += 256 * 4;
    int* cnt    = (int*)(base + o);   o += (size_t)N_BIG * 4;
    int* ovfn   = (int*)(base + o);   o += 256;
    float4* ovf = (float4*)(base + o); o += (size_t)OVF_CAP * 16;
    unsigned int* bucket = (unsigned int*)(base + o); o += (size_t)N_BIG * CAP * 4;  // 20.5 MB
    float* part = (float*)(base + o); o += (size_t)20000 * 128 * 4;

    // ---- prep + direct bucket build ----
    k_prep<<<512, 256, 0, stream>>>(Wih2, Whh2, bih1, bhh1, bih2, bhh2, dWa,
                                    cnt, ovfn, B2f, bc1, bc2, Bpqf, stats);
    k_fill<<<6250, 256, 0, stream>>>(ei, ea, cnt, bucket, ovfn, ovf);
    k_xw1<<<N_BIG / 4, 256, 0, stream>>>(x, W1, hbufb);
    k_disscale<<<N_BIG / 8, 256, 0, stream>>>(cnt, bucket, ovfn, ovf, dis, hbufb);

    // ---- GCN layer 1 ----
    k_gcn_gather<<<N_BIG / 8, 256, 0, stream>>>(hbufb, dis, cnt, bucket, ovfn, ovf, b1, h1b, part);
    k_bnred<<<128, 256, 0, stream>>>(part, 20000, stats);
    k_fold1<<<1, 256, 0, stream>>>(W2, g1, be1, stats, W2t, w2b, AC);

    // ---- GCN layer 2 ----
    k_h1w2<<<2500, 256, 0, stream>>>(h1b, W2t, w2b, dis, hbufb);
    k_gcn_gather<<<N_BIG / 8, 256, 0, stream>>>(hbufb, dis, cnt, bucket, ovfn, ovf, b2, h2b, part);
    k_bnred<<<128, 256, 0, stream>>>(part, 20000, stats + 128);
    k_fold2<<<64, 256, 0, stream>>>(Wih1, Whh1, g2, be2, stats, AC, bc1, B1f, bc1f);

    // ---- both LSTMs, all 8 steps, one launch ----
    k_lstm_fused<<<625, 256, 0, stream>>>(h1b, h2b, B1f, B2f, bc1f, bc2, hs1, hs2);

    // ---- decoder ----
    k_pq<<<313, 256, 0, stream>>>(hs1, hs2, x, Bpqf, dba, PQb);
    k_edge<<<E_DEC / 8, 256, 0, stream>>>(ewi, PQb, dWb, dbb, out);
}

// Round 15
// 613.669 us; speedup vs baseline: 3.1344x; 1.0101x over previous
//
#include <hip/hip_runtime.h>
#include <hip/hip_bf16.h>

#define IN_C 8
#define HID 64
#define N_NODES 20000
#define WINDOW 8
#define N_BIG 160000
#define NE 1600000
#define E_DEC 500000
#define DHV 143
#define EPSV 1e-5f
#define CAP 32
#define OVF_CAP 4096
#define NER 168   // padded LDS row stride (shorts) for the pq embedding tile
#define QS 16384.0f
#define IQS (1.0f / 16384.0f)

typedef __hip_bfloat16 bf;
typedef __attribute__((ext_vector_type(8))) short short8;
typedef __attribute__((ext_vector_type(4))) float float4_;

__device__ __forceinline__ float b2f(bf v) { return __bfloat162float(v); }
__device__ __forceinline__ bf f2b(float v) { return __float2bfloat16(v); }
__device__ __forceinline__ float bflo(unsigned int u) { return __uint_as_float(u << 16); }
__device__ __forceinline__ float bfhi(unsigned int u) { return __uint_as_float(u & 0xffff0000u); }
__device__ __forceinline__ unsigned int packbf2(float lo, float hi) {
    unsigned int ul = __bfloat16_as_ushort(f2b(lo));
    unsigned int uh = __bfloat16_as_ushort(f2b(hi));
    return ul | (uh << 16);
}
__device__ __forceinline__ float sigf(float x) {
    return __builtin_amdgcn_rcpf(1.f + __expf(-x));
}
__device__ __forceinline__ float tanhfast(float x) {
    x = fminf(fmaxf(x, -15.f), 15.f);
    float e = __expf(2.f * x);
    return (e - 1.f) * __builtin_amdgcn_rcpf(e + 1.f);
}

// ------------- bucket fill (1 atomic/edge) + prep grid-split ---------------
// blocks [0,6250): edge fill; blocks [6250,6762): weight conversion (prep).
// cnt/ovfn are zeroed by hipMemsetAsync before this launch.
__global__ __launch_bounds__(256) void k_prepfill(
    const int* ei, const float* ea, int* cnt, unsigned int* bucket, int* ovfn, float4* ovf,
    const float* Wih2, const float* Whh2, const float* bih1, const float* bhh1,
    const float* bih2, const float* bhh2, const float* dWa,
    bf* B2f, float* bc1, float* bc2, bf* Bpqf)
{
    int tid = threadIdx.x;
    if (blockIdx.x < 6250) {
        int e = blockIdx.x * 256 + tid;
        int r = ei[e], c = ei[NE + e];
        float a = ea[e];
        unsigned int q = (unsigned int)(a * QS + 0.5f);
        if (q > 16383u) q = 16383u;
        int p = atomicAdd(&cnt[c], 1);
        if (p < CAP) bucket[(size_t)c * CAP + p] = ((unsigned int)r << 14) | q;
        else {
            int qq = atomicAdd(ovfn, 1);
            if (qq < OVF_CAP) ovf[qq] = make_float4(__int_as_float(c), __int_as_float(r), a, 0.f);
        }
        return;
    }
    int i0 = (blockIdx.x - 6250) * 256 + tid;
    int stride = 512 * 256;
    for (int i = i0; i < 16 * 4 * 64 * 8; i += stride) {   // B2 fragments (K=128)
        int j = i & 7, lane = (i >> 3) & 63, r = i >> 9;
        int c = r & 3, ct = r >> 2;
        int q = lane >> 4, l15 = lane & 15;
        int n = ct * 16 + l15, k = c * 32 + q * 8 + j;
        B2f[i] = f2b((k < 64) ? Wih2[n * 64 + k] : Whh2[n * 64 + (k - 64)]);
    }
    for (int i = i0; i < 256; i += stride) {
        bc1[i] = bih1[i] + bhh1[i];
        bc2[i] = bih2[i] + bhh2[i];
    }
    for (int i = i0; i < 18 * 5 * 64 * 8; i += stride) {   // decoder fragments
        int j = i & 7, lane = (i >> 3) & 63, r = i >> 9;
        int c = r % 5, ct = r / 5;
        int q = lane >> 4, l15 = lane & 15;
        int n = ct * 16 + l15, k = c * 32 + q * 8 + j;
        float v = 0.f;
        if (k < DHV) {
            if (n < DHV) v = dWa[k * DHV + n];
            else if (n >= 144 && n < 144 + DHV) v = dWa[(DHV + k) * DHV + (n - 144)];
        }
        Bpqf[i] = f2b(v);
    }
}

// -------- fused: deg from buckets -> dis; write dis*(x@W1) once ------------
// Block = 256 thr = 4 waves = 8 nodes (32 lanes/node, 2 channels/lane).
__global__ __launch_bounds__(256) void k_xw1dis(const float* x, const float* W1,
        const int* cnt, const unsigned int* bucket, const int* ovfn, const float4* ovf,
        float* dis, bf* hbufb) {
    __shared__ float Ws[8][64];
    __shared__ float xs[8][8];
    int tid = threadIdx.x;
    Ws[tid >> 6][tid & 63] = W1[tid];
    Ws[4 + (tid >> 6)][tid & 63] = W1[256 + tid];
    int nb0 = blockIdx.x * 8;
    if (tid < 64) xs[tid >> 3][tid & 7] = x[nb0 * IN_C + tid];
    __syncthreads();
    int wv = tid >> 6, half = (tid >> 5) & 1, l = tid & 31;
    int nl = wv * 2 + half;
    int c = nb0 + nl;
    int n = cnt[c];
    int nbk = (n < CAP) ? n : CAP;
    float s = 0.f;
    for (int i = l; i < nbk; i += 32) s += (float)(bucket[(size_t)c * CAP + i] & 0x3FFFu);
    s *= IQS;
    if (n > CAP) {
        int m = *ovfn; if (m > OVF_CAP) m = OVF_CAP;
        for (int i = l; i < m; i += 32) {
            float4 v = ovf[i];
            if (__float_as_int(v.x) == c) s += v.z;
        }
    }
#pragma unroll
    for (int off = 16; off > 0; off >>= 1) s += __shfl_xor(s, off);
    float dv = rsqrtf(fmaxf(1.f + s, EPSV));
    if (l == 0) dis[c] = dv;
    float a0 = 0.f, a1 = 0.f;
#pragma unroll
    for (int k = 0; k < IN_C; k++) {
        float xv = xs[nl][k];
        a0 += xv * Ws[k][2 * l];
        a1 += xv * Ws[k][2 * l + 1];
    }
    *(unsigned int*)(hbufb + (size_t)c * 64 + 2 * l) = packbf2(dv * a0, dv * a1);
}

// ---------------- GCN aggregation (bucket gather) + fused BN partial stats --
__global__ __launch_bounds__(256) void k_gcn_gather(const bf* h, const float* dis, const int* cnt,
                             const unsigned int* bucket, const int* ovfn, const float4* ovf,
                             const float* bias, bf* outb, float* part) {
    __shared__ float4 red[256];
    int tid = threadIdx.x;
    int wv = (blockIdx.x * 256 + tid) >> 6;
    int half = (tid >> 5) & 1, l = tid & 31;
    int c = wv * 2 + half;                 // grid exact: c < N_BIG always
    unsigned int hv = *(const unsigned int*)(h + (size_t)c * 64 + 2 * l);
    float ax = bflo(hv), ay = bfhi(hv);
    size_t o = (size_t)c * CAP;
    int nfull = cnt[c];
    int n = (nfull < CAP) ? nfull : CAP;
    int e = 0;
    for (; e + 8 <= n; e += 8) {
        unsigned int p[8];
#pragma unroll
        for (int j = 0; j < 8; j++) p[j] = bucket[o + e + j];
        unsigned int v[8];
#pragma unroll
        for (int j = 0; j < 8; j++)
            v[j] = *(const unsigned int*)(h + (size_t)(p[j] >> 14) * 64 + 2 * l);
#pragma unroll
        for (int j = 0; j < 8; j++) {
            float a = (float)(p[j] & 0x3FFFu) * IQS;
            ax += a * bflo(v[j]); ay += a * bfhi(v[j]);
        }
    }
    for (; e + 4 <= n; e += 4) {
        unsigned int p[4];
#pragma unroll
        for (int j = 0; j < 4; j++) p[j] = bucket[o + e + j];
        unsigned int v[4];
#pragma unroll
        for (int j = 0; j < 4; j++)
            v[j] = *(const unsigned int*)(h + (size_t)(p[j] >> 14) * 64 + 2 * l);
#pragma unroll
        for (int j = 0; j < 4; j++) {
            float a = (float)(p[j] & 0x3FFFu) * IQS;
            ax += a * bflo(v[j]); ay += a * bfhi(v[j]);
        }
    }
    for (; e < n; e++) {
        unsigned int p = bucket[o + e];
        unsigned int v = *(const unsigned int*)(h + (size_t)(p >> 14) * 64 + 2 * l);
        float a = (float)(p & 0x3FFFu) * IQS;
        ax += a * bflo(v);
        ay += a * bfhi(v);
    }
    if (nfull > CAP) {      // practically never
        int m = *ovfn; if (m > OVF_CAP) m = OVF_CAP;
        for (int i = 0; i < m; i++) {
            float4 v = ovf[i];
            if (__float_as_int(v.x) == c) {
                unsigned int hw = *(const unsigned int*)(h + (size_t)__float_as_int(v.y) * 64 + 2 * l);
                ax += v.z * bflo(hw);
                ay += v.z * bfhi(hw);
            }
        }
    }
    float dv = dis[c];
    float2 bv = *(const float2*)(bias + 2 * l);
    float vx = fmaxf(dv * ax + bv.x, 0.f);
    float vy = fmaxf(dv * ay + bv.y, 0.f);
    *(unsigned int*)(outb + (size_t)c * 64 + 2 * l) = packbf2(vx, vy);
    // ---- BN partial stats (fp32, pre-round) ----
    red[tid] = make_float4(vx, vy, vx * vx, vy * vy);
    __syncthreads();
    if (tid < 32) {
        float4 s = make_float4(0.f, 0.f, 0.f, 0.f);
#pragma unroll
        for (int i = 0; i < 8; i++) {
            float4 v = red[((i >> 1) << 6) + ((i & 1) << 5) + tid];
            s.x += v.x; s.y += v.y; s.z += v.z; s.w += v.w;
        }
        float* pb = part + (size_t)blockIdx.x * 128;
        pb[2 * tid] = s.x; pb[2 * tid + 1] = s.y;
        pb[64 + 2 * tid] = s.z; pb[64 + 2 * tid + 1] = s.w;
    }
}

// ---------------- reduce per-block BN partials ------------------------------
__global__ __launch_bounds__(256) void k_bnred(const float* part, int nblk, float* stats_out) {
    __shared__ float s[256];
    float acc = 0.f;
    for (int b = threadIdx.x; b < nblk; b += 256) acc += part[(size_t)b * 128 + blockIdx.x];
    s[threadIdx.x] = acc;
    __syncthreads();
    for (int off = 128; off; off >>= 1) {
        if (threadIdx.x < off) s[threadIdx.x] += s[threadIdx.x + off];
        __syncthreads();
    }
    if (threadIdx.x == 0) stats_out[blockIdx.x] = s[0];
}

// ------------------------------- fold BN1 affine into W2^T + bias ----------
__global__ __launch_bounds__(256) void k_fold1(const float* W2, const float* g1, const float* be1,
                                               const float* stats, bf* W2t, float* w2b, float* AC) {
    __shared__ float A[64], C[64];
    int tid = threadIdx.x;
    if (tid < 64) {
        float m = stats[tid] * (1.f / (float)N_BIG);
        float var = stats[64 + tid] * (1.f / (float)N_BIG) - m * m;
        float a = g1[tid] * rsqrtf(var + EPSV);
        float c = be1[tid] - m * a;
        A[tid] = a; C[tid] = c;
        AC[tid] = a; AC[64 + tid] = c;
    }
    __syncthreads();
    for (int i = tid; i < 4096; i += 256) {
        int n = i >> 6, k = i & 63;
        W2t[i] = f2b(W2[k * 64 + n] * A[k]);
    }
    if (tid < 64) {
        float s = 0.f;
        for (int k = 0; k < 64; k++) s += C[k] * W2[k * 64 + tid];
        w2b[tid] = s;
    }
}

// -------- fold BN1/BN2 affine into LSTM1 weights (B1f fragments) + bias ----
__global__ void k_fold2(const float* Wih1, const float* Whh1,
                        const float* g2, const float* be2, const float* stats,
                        const float* AC, const float* bih1, const float* bhh1,
                        bf* B1f, float* bc1f) {
    int i0 = blockIdx.x * blockDim.x + threadIdx.x;
    int stride = gridDim.x * blockDim.x;
    for (int i = i0; i < 16 * 6 * 64 * 8; i += stride) {
        int j = i & 7, lane = (i >> 3) & 63, r = i >> 9;
        int c = r % 6, ct = r / 6;
        int q = lane >> 4, l15 = lane & 15;
        int n = ct * 16 + l15, k = c * 32 + q * 8 + j;
        float w = (k < 128) ? Wih1[n * 128 + k] : Whh1[n * 64 + (k - 128)];
        float scale = 1.f;
        if (k < 64) scale = AC[k];
        else if (k < 128) {
            int ch = k - 64;
            float m = stats[128 + ch] * (1.f / (float)N_BIG);
            float var = stats[192 + ch] * (1.f / (float)N_BIG) - m * m;
            scale = g2[ch] * rsqrtf(var + EPSV);
        }
        B1f[i] = f2b(w * scale);
    }
    for (int n = i0; n < 256; n += stride) {
        float s = bih1[n] + bhh1[n];
        for (int k = 0; k < 64; k++) s += AC[64 + k] * Wih1[n * 128 + k];
        for (int ch = 0; ch < 64; ch++) {
            float m = stats[128 + ch] * (1.f / (float)N_BIG);
            float var = stats[192 + ch] * (1.f / (float)N_BIG) - m * m;
            float a = g2[ch] * rsqrtf(var + EPSV);
            float c2v = be2[ch] - m * a;
            s += c2v * Wih1[n * 128 + 64 + ch];
        }
        bc1f[n] = s;
    }
}

// ------------- h1_raw @ (A1-scaled W2) + w2b, epilogue x dis (bf16 MFMA) ----
__global__ __launch_bounds__(256) void k_h1w2(const bf* h1b, const bf* W2t, const float* w2b,
                                              const float* dis, bf* outb) {
    int tid = threadIdx.x, w = tid >> 6, lane = tid & 63;
    int q = lane >> 4, l15 = lane & 15;
    size_t r0 = (size_t)blockIdx.x * 64 + w * 16;
    float4_ acc[4];
#pragma unroll
    for (int ct = 0; ct < 4; ct++) acc[ct] = (float4_){0.f, 0.f, 0.f, 0.f};
#pragma unroll
    for (int c = 0; c < 2; c++) {
        int koff = c * 32 + q * 8;
        short8 a = *(const short8*)(h1b + (r0 + l15) * 64 + koff);
#pragma unroll
        for (int ct = 0; ct < 4; ct++) {
            short8 b = *(const short8*)(W2t + (size_t)(ct * 16 + l15) * 64 + koff);
            acc[ct] = __builtin_amdgcn_mfma_f32_16x16x32_bf16(a, b, acc[ct], 0, 0, 0);
        }
    }
    size_t node0 = r0 + q * 4;
#pragma unroll
    for (int reg = 0; reg < 4; reg++) {
        float dv = dis[node0 + reg];
#pragma unroll
        for (int ct = 0; ct < 4; ct++)
            outb[(node0 + reg) * 64 + ct * 16 + l15] = f2b(dv * (acc[ct][reg] + w2b[ct * 16 + l15]));
    }
}

// ----------------------------------------- fully fused double LSTM (MFMA) ---
__global__ __launch_bounds__(256, 1) void k_lstm_fused(
    const bf* h1b, const bf* h2b, const bf* B1f, const bf* B2f,
    const float* bc1, const float* bc2, bf* H1out, bf* H2out)
{
    __shared__ bf h1s[2][32][72];
    __shared__ bf h2s[2][32][72];
    int tid = threadIdx.x, w = tid >> 6, lane = tid & 63;
    int q = lane >> 4, l15 = lane & 15;
    int gnode0 = blockIdx.x * 32;
    short8 B1r[6][4];
    short8 B2r[4][4];
#pragma unroll
    for (int c = 0; c < 6; c++)
#pragma unroll
        for (int g = 0; g < 4; g++)
            B1r[c][g] = *(const short8*)(B1f + (size_t)(((w + 4 * g) * 6 + c) * 64 + lane) * 8);
#pragma unroll
    for (int c = 0; c < 4; c++)
#pragma unroll
        for (int g = 0; g < 4; g++)
            B2r[c][g] = *(const short8*)(B2f + (size_t)(((w + 4 * g) * 4 + c) * 64 + lane) * 8);
    float c1[2][4] = {}, c2[2][4] = {};
    float bv1[4], bv2[4];
#pragma unroll
    for (int g = 0; g < 4; g++) {
        bv1[g] = bc1[(w + 4 * g) * 16 + l15];
        bv2[g] = bc2[(w + 4 * g) * 16 + l15];
    }
    short8 Ag[4][2], An[4][2];
#pragma unroll
    for (int c = 0; c < 4; c++) {
        const bf* sp = (c < 2) ? h1b : h2b;
        int koff = (c & 1) * 32 + q * 8;
#pragma unroll
        for (int m = 0; m < 2; m++)
            Ag[c][m] = *(const short8*)(sp + (size_t)(gnode0 + m * 16 + l15) * 64 + koff);
    }
#pragma unroll
    for (int t = 0; t < WINDOW; t++) {
        int cur = t & 1, prv = cur ^ 1;
        float4_ acc[2][4];
#pragma unroll
        for (int m = 0; m < 2; m++)
#pragma unroll
            for (int g = 0; g < 4; g++) acc[m][g] = (float4_){bv1[g], bv1[g], bv1[g], bv1[g]};
#pragma unroll
        for (int c = 0; c < 4; c++)
#pragma unroll
            for (int m = 0; m < 2; m++)
#pragma unroll
                for (int g = 0; g < 4; g++)
                    acc[m][g] = __builtin_amdgcn_mfma_f32_16x16x32_bf16(Ag[c][m], B1r[c][g], acc[m][g], 0, 0, 0);
        if (t < WINDOW - 1) {
            const size_t toff2 = (size_t)(t + 1) * N_NODES * 64;
#pragma unroll
            for (int c = 0; c < 4; c++) {
                const bf* sp = (c < 2) ? h1b + toff2 : h2b + toff2;
                int koff = (c & 1) * 32 + q * 8;
#pragma unroll
                for (int m = 0; m < 2; m++)
                    An[c][m] = *(const short8*)(sp + (size_t)(gnode0 + m * 16 + l15) * 64 + koff);
            }
        }
        if (t > 0) {
#pragma unroll
            for (int c = 4; c < 6; c++) {
                int koff = (c & 1) * 32 + q * 8;
#pragma unroll
                for (int m = 0; m < 2; m++) {
                    short8 a = *(const short8*)&h1s[prv][m * 16 + l15][koff];
#pragma unroll
                    for (int g = 0; g < 4; g++)
                        acc[m][g] = __builtin_amdgcn_mfma_f32_16x16x32_bf16(a, B1r[c][g], acc[m][g], 0, 0, 0);
                }
            }
        }
#pragma unroll
        for (int m = 0; m < 2; m++)
#pragma unroll
            for (int reg = 0; reg < 4; reg++) {
                float gi = acc[m][0][reg], gf = acc[m][1][reg];
                float gg = acc[m][2][reg], go = acc[m][3][reg];
                float co = (t == 0) ? 0.f : c1[m][reg];
                float cn = sigf(gf) * co + sigf(gi) * tanhfast(gg);
                float hn = sigf(go) * tanhfast(cn);
                c1[m][reg] = cn;
                int nl = m * 16 + q * 4 + reg;
                h1s[cur][nl][w * 16 + l15] = f2b(hn);
                if (t == WINDOW - 1)
                    H1out[(size_t)(gnode0 + nl) * 64 + w * 16 + l15] = f2b(hn);
            }
        __syncthreads();
#pragma unroll
        for (int m = 0; m < 2; m++)
#pragma unroll
            for (int g = 0; g < 4; g++) acc[m][g] = (float4_){bv2[g], bv2[g], bv2[g], bv2[g]};
#pragma unroll
        for (int c = 0; c < 2; c++) {
            int koff = (c & 1) * 32 + q * 8;
#pragma unroll
            for (int m = 0; m < 2; m++) {
                short8 a = *(const short8*)&h1s[cur][m * 16 + l15][koff];
#pragma unroll
                for (int g = 0; g < 4; g++)
                    acc[m][g] = __builtin_amdgcn_mfma_f32_16x16x32_bf16(a, B2r[c][g], acc[m][g], 0, 0, 0);
            }
        }
        if (t > 0) {
#pragma unroll
            for (int c = 2; c < 4; c++) {
                int koff = (c & 1) * 32 + q * 8;
#pragma unroll
                for (int m = 0; m < 2; m++) {
                    short8 a = *(const short8*)&h2s[prv][m * 16 + l15][koff];
#pragma unroll
                    for (int g = 0; g < 4; g++)
                        acc[m][g] = __builtin_amdgcn_mfma_f32_16x16x32_bf16(a, B2r[c][g], acc[m][g], 0, 0, 0);
                }
            }
        }
#pragma unroll
        for (int m = 0; m < 2; m++)
#pragma unroll
            for (int reg = 0; reg < 4; reg++) {
                float gi = acc[m][0][reg], gf = acc[m][1][reg];
                float gg = acc[m][2][reg], go = acc[m][3][reg];
                float co = (t == 0) ? 0.f : c2[m][reg];
                float cn = sigf(gf) * co + sigf(gi) * tanhfast(gg);
                float hn = sigf(go) * tanhfast(cn);
                c2[m][reg] = cn;
                int nl = m * 16 + q * 4 + reg;
                h2s[cur][nl][w * 16 + l15] = f2b(hn);
                if (t == WINDOW - 1)
                    H2out[(size_t)(gnode0 + nl) * 64 + w * 16 + l15] = f2b(hn);
            }
        __syncthreads();
#pragma unroll
        for (int c = 0; c < 4; c++)
#pragma unroll
            for (int m = 0; m < 2; m++) Ag[c][m] = An[c][m];
    }
}

// ------------- PQ = nodeemb @ Bpq, nodeemb built in LDS (fused) -------------
__global__ __launch_bounds__(256) void k_pq(const bf* H1, const bf* H2, const float* x,
                                            const bf* Bpqf, const float* dba, bf* PQb) {
    __shared__ bf ne[64][NER];
    int tid = threadIdx.x, w = tid >> 6, lane = tid & 63;
    int q = lane >> 4, l15 = lane & 15;
    int r0 = blockIdx.x * 64;
    for (int i = tid; i < 64 * 16; i += 256) {
        int rr = i >> 4, cc = (i & 15) * 4;
        int gr = r0 + rr;
        uint2 v1 = make_uint2(0u, 0u), v2 = make_uint2(0u, 0u);
        if (gr < N_NODES) {
            v1 = *(const uint2*)(H1 + (size_t)gr * 64 + cc);
            v2 = *(const uint2*)(H2 + (size_t)gr * 64 + cc);
        }
        *(uint2*)&ne[rr][cc] = v1;
        *(uint2*)&ne[rr][64 + cc] = v2;
    }
    for (int i = tid; i < 64 * 32; i += 256) {
        int rr = i >> 5, cc = 128 + (i & 31);
        int gr = r0 + rr;
        float v = 0.f;
        if (gr < N_NODES && cc < DHV) {
            int s = cc - 128;
            v = (s < 8) ? x[gr * IN_C + s] : x[(size_t)((s - 7) * N_NODES + gr) * IN_C + 7];
        }
        ne[rr][cc] = f2b(v);
    }
    __syncthreads();
    float4_ acc[18];
#pragma unroll
    for (int ct = 0; ct < 18; ct++) acc[ct] = (float4_){0.f, 0.f, 0.f, 0.f};
#pragma unroll
    for (int c = 0; c < 5; c++) {
        short8 a = *(const short8*)&ne[w * 16 + l15][c * 32 + q * 8];
#pragma unroll
        for (int ct = 0; ct < 18; ct++) {
            short8 b = *(const short8*)(Bpqf + (size_t)((ct * 5 + c) * 64 + lane) * 8);
            acc[ct] = __builtin_amdgcn_mfma_f32_16x16x32_bf16(a, b, acc[ct], 0, 0, 0);
        }
    }
#pragma unroll
    for (int reg = 0; reg < 4; reg++) {
        int nrow = r0 + w * 16 + q * 4 + reg;
        if (nrow < N_NODES)
#pragma unroll
            for (int ct = 0; ct < 18; ct++) {
                int col = ct * 16 + l15;
                float add = (ct < 9 && col < DHV) ? dba[col] : 0.f;
                PQb[(size_t)nrow * 288 + col] = f2b(acc[ct][reg] + add);
            }
    }
}

// decoder: 2 edges/wave, 32 lanes/edge, 8B loads; P' already has +dba
__global__ __launch_bounds__(256) void k_edge(const int* ewi, const bf* PQb,
                                              const float* dWb, const float* dbb, float* out) {
    int wv = (blockIdx.x * blockDim.x + threadIdx.x) >> 6;
    int half = (threadIdx.x >> 5) & 1, l = threadIdx.x & 31;
    int e = wv * 2 + half;
    if (e >= E_DEC) return;
    int src = ewi[e], trg = ewi[E_DEC + e];
    const bf* Pr = PQb + (size_t)src * 288;
    const bf* Qr = PQb + (size_t)trg * 288 + 144;
    float acc;
    {
        uint2 pv = *(const uint2*)(Pr + 4 * l);
        uint2 qv = *(const uint2*)(Qr + 4 * l);
        float4 wv4 = *(const float4*)(dWb + 4 * l);
        float s0 = fmaxf(bflo(pv.x) + bflo(qv.x), 0.f);
        float s1 = fmaxf(bfhi(pv.x) + bfhi(qv.x), 0.f);
        float s2 = fmaxf(bflo(pv.y) + bflo(qv.y), 0.f);
        float s3 = fmaxf(bfhi(pv.y) + bfhi(qv.y), 0.f);
        acc = s0 * wv4.x + s1 * wv4.y + s2 * wv4.z + s3 * wv4.w;
    }
    if (l < 4) {
        int u0 = 128 + 4 * l;
        uint2 pv = *(const uint2*)(Pr + u0);
        uint2 qv = *(const uint2*)(Qr + u0);
        float w0 = dWb[u0], w1 = dWb[u0 + 1], w2 = dWb[u0 + 2];
        float w3 = (u0 + 3 < DHV) ? dWb[u0 + 3] : 0.f;
        acc += fmaxf(bflo(pv.x) + bflo(qv.x), 0.f) * w0;
        acc += fmaxf(bfhi(pv.x) + bfhi(qv.x), 0.f) * w1;
        acc += fmaxf(bflo(pv.y) + bflo(qv.y), 0.f) * w2;
        acc += fmaxf(bfhi(pv.y) + bfhi(qv.y), 0.f) * w3;
    }
#pragma unroll
    for (int off = 16; off > 0; off >>= 1) acc += __shfl_xor(acc, off);
    if (l == 0) out[e] = acc + dbb[0];
}

// ---------------------------------------------------------------------------
extern "C" void kernel_launch(void* const* d_in, const int* in_sizes, int n_in,
                              void* d_out, int out_size, void* d_ws, size_t ws_size,
                              hipStream_t stream) {
    (void)in_sizes; (void)n_in; (void)out_size; (void)ws_size;
    const float* x    = (const float*)d_in[0];
    const float* ea   = (const float*)d_in[1];
    const int*   ei   = (const int*)d_in[2];
    const int*   ewi  = (const int*)d_in[3];
    const float* W1   = (const float*)d_in[4];
    const float* b1   = (const float*)d_in[5];
    const float* g1   = (const float*)d_in[6];
    const float* be1  = (const float*)d_in[7];
    const float* W2   = (const float*)d_in[8];
    const float* b2   = (const float*)d_in[9];
    const float* g2   = (const float*)d_in[10];
    const float* be2  = (const float*)d_in[11];
    const float* Wih1 = (const float*)d_in[12];
    const float* Whh1 = (const float*)d_in[13];
    const float* bih1 = (const float*)d_in[14];
    const float* bhh1 = (const float*)d_in[15];
    const float* Wih2 = (const float*)d_in[16];
    const float* Whh2 = (const float*)d_in[17];
    const float* bih2 = (const float*)d_in[18];
    const float* bhh2 = (const float*)d_in[19];
    const float* dWa  = (const float*)d_in[20];
    const float* dba  = (const float*)d_in[21];
    const float* dWb  = (const float*)d_in[22];
    const float* dbb  = (const float*)d_in[23];
    float* out = (float*)d_out;

    const size_t NSB = (size_t)N_BIG * 64;
    const size_t NS  = (size_t)N_NODES * 64;
    char* base = (char*)d_ws;
    size_t o = 0;
    float* dis  = (float*)(base + o); o += (size_t)N_BIG * 4;
    bf* PQb     = (bf*)(base + o);    o += NSB * 2;
    bf* hbufb   = (bf*)(base + o);    o += NSB * 2;
    bf* h1b     = (bf*)(base + o);    o += NSB * 2;
    bf* h2b     = (bf*)(base + o);    o += NSB * 2;
    bf* hs1     = (bf*)(base + o);    o += NS * 2;
    bf* hs2     = (bf*)(base + o);    o += NS * 2;
    bf* B1f     = (bf*)(base + o);    o += (size_t)16 * 6 * 64 * 8 * 2;
    bf* B2f     = (bf*)(base + o);    o += (size_t)16 * 4 * 64 * 8 * 2;
    bf* W2t     = (bf*)(base + o);    o += 64 * 64 * 2;
    bf* Bpqf    = (bf*)(base + o);    o += (size_t)18 * 5 * 64 * 8 * 2;
    float* bc1  = (float*)(base + o); o += 256 * 4;
    float* bc2  = (float*)(base + o); o += 256 * 4;
    float* stats= (float*)(base + o); o += 256 * 4;
    float* w2b  = (float*)(base + o); o += 64 * 4;
    float* AC   = (float*)(base + o); o += 128 * 4;
    float* bc1f = (float*)(base + o); o += 256 * 4;
    int* cnt    = (int*)(base + o);   o += (size_t)N_BIG * 4;
    int* ovfn   = (int*)(base + o);   o += 256 * 4;                // zeroed with cnt
    float4* ovf = (float4*)(base + o); o += (size_t)OVF_CAP * 16;
    unsigned int* bucket = (unsigned int*)(base + o); o += (size_t)N_BIG * CAP * 4;  // 20.5 MB
    float* part = (float*)(base + o); o += (size_t)20000 * 128 * 4;

    // ---- zero cnt+ovfn, then bucket build fused with weight prep ----
    hipMemsetAsync(cnt, 0, ((size_t)N_BIG + 256) * 4, stream);
    k_prepfill<<<6250 + 512, 256, 0, stream>>>(ei, ea, cnt, bucket, ovfn, ovf,
                                               Wih2, Whh2, bih1, bhh1, bih2, bhh2, dWa,
                                               B2f, bc1, bc2, Bpqf);
    // ---- dis + x@W1 fused ----
    k_xw1dis<<<N_BIG / 8, 256, 0, stream>>>(x, W1, cnt, bucket, ovfn, ovf, dis, hbufb);

    // ---- GCN layer 1 ----
    k_gcn_gather<<<N_BIG / 8, 256, 0, stream>>>(hbufb, dis, cnt, bucket, ovfn, ovf, b1, h1b, part);
    k_bnred<<<128, 256, 0, stream>>>(part, 20000, stats);
    k_fold1<<<1, 256, 0, stream>>>(W2, g1, be1, stats, W2t, w2b, AC);

    // ---- GCN layer 2 ----
    k_h1w2<<<2500, 256, 0, stream>>>(h1b, W2t, w2b, dis, hbufb);
    k_gcn_gather<<<N_BIG / 8, 256, 0, stream>>>(hbufb, dis, cnt, bucket, ovfn, ovf, b2, h2b, part);
    k_bnred<<<128, 256, 0, stream>>>(part, 20000, stats + 128);
    k_fold2<<<64, 256, 0, stream>>>(Wih1, Whh1, g2, be2, stats, AC, bih1, bhh1, B1f, bc1f);

    // ---- both LSTMs, all 8 steps, one launch ----
    k_lstm_fused<<<625, 256, 0, stream>>>(h1b, h2b, B1f, B2f, bc1f, bc2, hs1, hs2);

    // ---- decoder ----
    k_pq<<<313, 256, 0, stream>>>(hs1, hs2, x, Bpqf, dba, PQb);
    k_edge<<<E_DEC / 8, 256, 0, stream>>>(ewi, PQb, dWb, dbb, out);
}